// Round 15
// baseline (537.666 us; speedup 1.0000x reference)
//
#include <hip/hip_runtime.h>

typedef unsigned short u16;
typedef unsigned int u32;
typedef __attribute__((ext_vector_type(8))) __bf16 bf16x8;
typedef __attribute__((ext_vector_type(8))) _Float16 f16x8;
typedef __attribute__((ext_vector_type(4))) _Float16 f16x4;
typedef __attribute__((ext_vector_type(4))) float f32x4;

#define DEV __device__ __forceinline__

DEV u16 f2bf(float f) {
  u32 u = __float_as_uint(f);
  u += 0x7FFFu + ((u >> 16) & 1u);   // RNE
  return (u16)(u >> 16);
}
DEV float bf2f(u16 h) { return __uint_as_float(((u32)h) << 16); }
DEV void splitbf(float f, u16& hi, u16& lo) {
  u16 h = f2bf(f);
  hi = h;
  lo = f2bf(f - bf2f(h));
}
DEV void split4(float4 v, ushort4& hh, ushort4& ll) {
  splitbf(v.x, hh.x, ll.x);
  splitbf(v.y, hh.y, ll.y);
  splitbf(v.z, hh.z, ll.z);
  splitbf(v.w, hh.w, ll.w);
}
// T2 XOR swizzle for 64x64 u16 tiles (128B rows): kills the 16-way ds_read_b128 bank conflict.
DEV int SW(int r, int c) { return r * 64 + ((c) ^ ((r & 7) << 3)); }

// GEMM-tile swizzle: [*][32] u16 K-tiles, double-row (128B) units of 8x16B blocks,
// block index XORed with (row>>1)&7 -> fragment reads become 2-way (free).
DEV int SWG(int r, int c) {
  int db = ((r & 1) << 2) | ((c >> 3) & 3);
  int dbp = db ^ ((r >> 1) & 7);
  return ((r >> 1) << 6) | (dbp << 3) | (c & 7);
}
// producer-side: where logical (row, col) lives in the pre-swizzled global
DEV size_t gidx_swz(size_t row, int col, int rowlen) {
  int rr7 = (int)((row >> 1) & 7);
  int db = (int)(((row & 1) << 2) | ((col >> 3) & 3));
  int dbp = db ^ rr7;
  size_t rowp = (row & ~(size_t)1) | (size_t)(dbp >> 2);
  int colp = (col & ~31) | ((dbp & 3) << 3) | (col & 7);
  return rowp * (size_t)rowlen + colp;
}

#define MFMA16(a,b,c) __builtin_amdgcn_mfma_f32_16x16x32_bf16((a),(b),(c),0,0,0)
#define MFMAH(a,b,c)  __builtin_amdgcn_mfma_f32_16x16x32_f16((a),(b),(c),0,0,0)
#define GLDS16(g,l) __builtin_amdgcn_global_load_lds((__attribute__((address_space(1))) void*)(g), (__attribute__((address_space(3))) void*)(l), 16, 0, 0)

DEV f32x4 mm3(bf16x8 ah, bf16x8 al, bf16x8 bh, bf16x8 bl, f32x4 acc) {
  acc = MFMA16(ah, bl, acc);
  acc = MFMA16(al, bh, acc);
  acc = MFMA16(ah, bh, acc);
  return acc;
}

// ---------------- cast f32 -> f16, pre-swizzled for GEMM staging ----------------
__global__ __launch_bounds__(256) void k_cast_h(const float* __restrict__ in, _Float16* __restrict__ out, int n) {
  int idx = (blockIdx.x * 256 + threadIdx.x) * 4;
  if (idx + 3 < n) {
    float4 v = *(const float4*)(in + idx);
    f16x4 o = {(_Float16)v.x, (_Float16)v.y, (_Float16)v.z, (_Float16)v.w};
    const size_t row = (size_t)(idx >> 10);
    const int col = idx & 1023;
    *(f16x4*)(out + gidx_swz(row, col, 1024)) = o;
  }
}

// ---------------- transpose f32 [R][C] -> f16 [C][R], pre-swizzled ----------------
__global__ __launch_bounds__(256) void k_transpose_h(const float* __restrict__ in, _Float16* __restrict__ out, int R, int Cc) {
  __shared__ float tile[64][65];
  int c0 = blockIdx.x * 64, r0 = blockIdx.y * 64;
  int lr = threadIdx.x >> 6, lc = threadIdx.x & 63;
#pragma unroll
  for (int i = 0; i < 16; ++i) {
    int r = lr + i * 4;
    tile[r][lc] = in[(size_t)(r0 + r) * Cc + c0 + lc];
  }
  __syncthreads();
#pragma unroll
  for (int i = 0; i < 16; ++i) {
    int oc = lr + i * 4;
    out[gidx_swz((size_t)(c0 + oc), r0 + lc, R)] = (_Float16)tile[lc][oc];
  }
}

// ---------------- transpose f32 [R][C] -> bf16 [C][R], pre-swizzled ----------------
__global__ __launch_bounds__(256) void k_transpose(const float* __restrict__ in, u16* __restrict__ out, int R, int Cc) {
  __shared__ float tile[64][65];
  int c0 = blockIdx.x * 64, r0 = blockIdx.y * 64;
  int lr = threadIdx.x >> 6, lc = threadIdx.x & 63;
#pragma unroll
  for (int i = 0; i < 16; ++i) {
    int r = lr + i * 4;
    tile[r][lc] = in[(size_t)(r0 + r) * Cc + c0 + lc];
  }
  __syncthreads();
#pragma unroll
  for (int i = 0; i < 16; ++i) {
    int oc = lr + i * 4;
    out[gidx_swz((size_t)(c0 + oc), r0 + lc, R)] = f2bf(tile[lc][oc]);
  }
}

// ---------------- GEMM1 (f16 single): 256x256 tile, 8 waves, dbuf issue-before-compute ----------------
__global__ __launch_bounds__(512, 2) void k_gemm_h(const _Float16* __restrict__ A, const _Float16* __restrict__ Bt,
                                                   u16* __restrict__ Cq, u16* __restrict__ Cz, int M, int N, int K) {
  __shared__ __align__(16) u16 As[2][256 * 32];
  __shared__ __align__(16) u16 Bs[2][256 * 32];
  const int tid = threadIdx.x;
  const int nwg = gridDim.x * gridDim.y;
  int bid = blockIdx.y * gridDim.x + blockIdx.x;
  bid = (bid & 7) * (nwg >> 3) + (bid >> 3);      // bijective (nwg % 8 == 0)
  const int m0 = (bid / gridDim.x) * 256, n0 = (bid % gridDim.x) * 256;
  const int w = tid >> 6, l = tid & 63;
  const int wr = (w >> 1) * 64, wc = (w & 1) * 128;
  const int lrow = l & 15, lk = (l >> 4) * 8, rbase = (l >> 4) * 4;

  f32x4 acc[4][8];
#pragma unroll
  for (int i = 0; i < 4; ++i)
#pragma unroll
    for (int j = 0; j < 8; ++j) acc[i][j] = {0.f, 0.f, 0.f, 0.f};

  const _Float16* aBase = A + (size_t)m0 * K;
  const _Float16* bBase = Bt + (size_t)n0 * K;
  const int srow0 = tid >> 2, scol0 = (tid & 3) * 8;        // staging chunk 0
  const int srow1 = (tid + 512) >> 2;                       // staging chunk 1 (same scol)

  auto STAGE = [&](int buf, int k0) {
    GLDS16(aBase + (size_t)srow0 * K + k0 + scol0, &As[buf][tid * 8]);
    GLDS16(aBase + (size_t)srow1 * K + k0 + scol0, &As[buf][4096 + tid * 8]);
    GLDS16(bBase + (size_t)srow0 * K + k0 + scol0, &Bs[buf][tid * 8]);
    GLDS16(bBase + (size_t)srow1 * K + k0 + scol0, &Bs[buf][4096 + tid * 8]);
  };

  STAGE(0, 0);
  __syncthreads();
  int cur = 0;
  for (int k0 = 0; k0 < K; k0 += 32) {
    if (k0 + 32 < K) STAGE(cur ^ 1, k0 + 32);   // issue next-tile loads (fly under compute)
    f16x8 af[4], bfr[8];
#pragma unroll
    for (int i = 0; i < 4; ++i) af[i] = *(const f16x8*)&As[cur][SWG(wr + i * 16 + lrow, lk)];
#pragma unroll
    for (int j = 0; j < 8; ++j) bfr[j] = *(const f16x8*)&Bs[cur][SWG(wc + j * 16 + lrow, lk)];
#pragma unroll
    for (int i = 0; i < 4; ++i)
#pragma unroll
      for (int j = 0; j < 8; ++j) acc[i][j] = MFMAH(af[i], bfr[j], acc[i][j]);
    __syncthreads();                            // drains next-tile GLDS + this tile's ds_reads
    cur ^= 1;
  }
#pragma unroll
  for (int i = 0; i < 4; ++i)
#pragma unroll
    for (int j = 0; j < 8; ++j)
#pragma unroll
      for (int r = 0; r < 4; ++r) {
        int row = m0 + wr + i * 16 + rbase + r;
        int col = n0 + wc + j * 16 + lrow;
        if (col < 3072) Cq[(size_t)row * 3072 + col] = f2bf(acc[i][j][r]);
        else            Cz[(size_t)row * 1024 + col - 3072] = f2bf(acc[i][j][r]);
      }
}

// ---------------- GEMM2: 128x256 tile, (Ah+Al) @ Bt^T, f32 out, dbuf ----------------
__global__ __launch_bounds__(256, 2) void k_gemm2(const u16* __restrict__ Ah, const u16* __restrict__ Al,
                                               const u16* __restrict__ Bt, float* __restrict__ Cf,
                                               int M, int N, int K) {
  __shared__ __align__(16) u16 Ash[2][128 * 32];
  __shared__ __align__(16) u16 Asl[2][128 * 32];
  __shared__ __align__(16) u16 Bs[2][256 * 32];
  const int tid = threadIdx.x;
  const int nwg = gridDim.x * gridDim.y;
  int bid = blockIdx.y * gridDim.x + blockIdx.x;
  bid = (bid & 7) * (nwg >> 3) + (bid >> 3);
  const int m0 = (bid / gridDim.x) * 128, n0 = (bid % gridDim.x) * 256;
  const int w = tid >> 6, l = tid & 63;
  const int wr = (w >> 1) * 64, wc = (w & 1) * 128;
  const int lrow = l & 15, lk = (l >> 4) * 8, rbase = (l >> 4) * 4;
  const int srow = tid >> 2, scol = (tid & 3) * 8;

  f32x4 acc[4][8];
#pragma unroll
  for (int i = 0; i < 4; ++i)
#pragma unroll
    for (int j = 0; j < 8; ++j) acc[i][j] = {0.f, 0.f, 0.f, 0.f};

  const u16* ahBase = Ah + (size_t)m0 * K;
  const u16* alBase = Al + (size_t)m0 * K;
  const u16* bBase  = Bt + (size_t)n0 * K;

  auto STAGE = [&](int buf, int k0) {
    GLDS16(ahBase + (size_t)srow * K + k0 + scol,         &Ash[buf][tid * 8]);
    GLDS16(ahBase + (size_t)(srow + 64) * K + k0 + scol,  &Ash[buf][2048 + tid * 8]);
    GLDS16(alBase + (size_t)srow * K + k0 + scol,         &Asl[buf][tid * 8]);
    GLDS16(alBase + (size_t)(srow + 64) * K + k0 + scol,  &Asl[buf][2048 + tid * 8]);
    GLDS16(bBase + (size_t)srow * K + k0 + scol,          &Bs[buf][tid * 8]);
    GLDS16(bBase + (size_t)(srow + 64) * K + k0 + scol,   &Bs[buf][2048 + tid * 8]);
    GLDS16(bBase + (size_t)(srow + 128) * K + k0 + scol,  &Bs[buf][4096 + tid * 8]);
    GLDS16(bBase + (size_t)(srow + 192) * K + k0 + scol,  &Bs[buf][6144 + tid * 8]);
  };

  STAGE(0, 0);
  __syncthreads();
  int cur = 0;
  for (int k0 = 0; k0 < K; k0 += 32) {
    if (k0 + 32 < K) STAGE(cur ^ 1, k0 + 32);
    bf16x8 afh[4], afl[4], bfr[8];
#pragma unroll
    for (int i = 0; i < 4; ++i) afh[i] = *(const bf16x8*)&Ash[cur][SWG(wr + i * 16 + lrow, lk)];
#pragma unroll
    for (int i = 0; i < 4; ++i) afl[i] = *(const bf16x8*)&Asl[cur][SWG(wr + i * 16 + lrow, lk)];
#pragma unroll
    for (int j = 0; j < 8; ++j) bfr[j] = *(const bf16x8*)&Bs[cur][SWG(wc + j * 16 + lrow, lk)];
#pragma unroll
    for (int i = 0; i < 4; ++i)
#pragma unroll
      for (int j = 0; j < 8; ++j) {
        acc[i][j] = MFMA16(afl[i], bfr[j], acc[i][j]);
        acc[i][j] = MFMA16(afh[i], bfr[j], acc[i][j]);
      }
    __syncthreads();
    cur ^= 1;
  }
#pragma unroll
  for (int i = 0; i < 4; ++i)
#pragma unroll
    for (int j = 0; j < 8; ++j)
#pragma unroll
      for (int r = 0; r < 4; ++r) {
        int row = m0 + wr + i * 16 + rbase + r;
        int col = n0 + wc + j * 16 + lrow;
        Cf[(size_t)row * N + col] = acc[i][j][r];
      }
}

// ---------------- ba proj + beta/g ----------------
__global__ __launch_bounds__(256) void k_ba(const float* __restrict__ x, const float* __restrict__ Wba,
                                            const float* __restrict__ dt_bias, const float* __restrict__ A_log,
                                            float* __restrict__ betaO, float* __restrict__ gO) {
  __shared__ float xs[4][1024];
  const int wid = threadIdx.x >> 6, lane = threadIdx.x & 63;
  const int m = blockIdx.x * 4 + wid;
#pragma unroll
  for (int i = 0; i < 16; ++i) xs[wid][lane + 64 * i] = x[(size_t)m * 1024 + lane + 64 * i];
  __syncthreads();
  const int n = lane & 31, half = lane >> 5;
  float acc = 0.f;
  const float* wp = Wba + n;
  const int kk0 = half * 512;
#pragma unroll 8
  for (int kk = kk0; kk < kk0 + 512; ++kk) acc += xs[wid][kk] * wp[kk * 32];
  acc += __shfl_xor(acc, 32);
  if (lane < 32) {
    if (n < 16) {
      betaO[(size_t)m * 16 + n] = 1.f / (1.f + expf(-acc));
    } else {
      int h = n - 16;
      float xx = acc + dt_bias[h];
      float sp = (xx > 20.f) ? xx : log1pf(expf(xx));
      gO[(size_t)m * 16 + h] = -expf(fmaxf(A_log[h], -2.3f)) * sp;
    }
  }
}

// ---------------- causal depthwise conv(4) + SiLU + l2norm; outputs per-(b,h) SWIZZLED bf16 hi/lo tiles ----------------
__global__ __launch_bounds__(256) void k_conv(const u16* __restrict__ qkv3, const float* __restrict__ convw,
                                              u16* __restrict__ qhG, u16* __restrict__ qlG,
                                              u16* __restrict__ khG, u16* __restrict__ klG,
                                              u16* __restrict__ vhG, u16* __restrict__ vlG) {
  __shared__ float cs[3072];
  __shared__ float innorm[32];
  const int bt = blockIdx.x;
  const int bb = bt >> 12, tt = bt & 4095;
  const int tid = threadIdx.x;
  const size_t rb = (size_t)bb * 4096;
#pragma unroll
  for (int s = 0; s < 3; ++s) {
    const int c4 = tid * 4 + s * 1024;   // contiguous 1KB segments per step
    float cwa[4][4];
#pragma unroll
    for (int e = 0; e < 4; ++e) {
      float4 t = *(const float4*)&convw[(c4 + e) * 4];
      cwa[e][0] = t.x; cwa[e][1] = t.y; cwa[e][2] = t.z; cwa[e][3] = t.w;
    }
    float acc[4] = {0.f, 0.f, 0.f, 0.f};
#pragma unroll
    for (int j = 0; j < 4; ++j) {
      const int tau = tt - 3 + j;
      if (tau >= 0) {
        ushort4 kv = *(const ushort4*)&qkv3[(rb + tau) * 3072 + c4];
        acc[0] += bf2f(kv.x) * cwa[0][j];
        acc[1] += bf2f(kv.y) * cwa[1][j];
        acc[2] += bf2f(kv.z) * cwa[2][j];
        acc[3] += bf2f(kv.w) * cwa[3][j];
      }
    }
#pragma unroll
    for (int e = 0; e < 4; ++e) cs[c4 + e] = acc[e] / (1.f + expf(-acc[e]));
  }
  __syncthreads();
  {
    const int grp = tid >> 3, off = (tid & 7) * 8;
    const float* p = cs + grp * 64 + off;
    float s = 0.f;
#pragma unroll
    for (int i = 0; i < 8; ++i) s += p[i] * p[i];
    s += __shfl_xor(s, 1); s += __shfl_xor(s, 2); s += __shfl_xor(s, 4);
    if ((tid & 7) == 0) innorm[grp] = rsqrtf(s + 1e-6f);
  }
  __syncthreads();
  // per-(b,h) swizzled tile outputs: elem (tt, d) of tile (bh, tt>>6) -> offset SW(tt&63, d)
  const int h = tid >> 4, d4 = (tid & 15) * 4;
  const size_t ob = ((size_t)(bb * 16 + h) * 64 + (tt >> 6)) * 4096 + SW(tt & 63, d4);
  {
    const int ci = h * 64 + d4;
    const float sc = innorm[h] * 0.125f;
    float4 o = {cs[ci] * sc, cs[ci + 1] * sc, cs[ci + 2] * sc, cs[ci + 3] * sc};
    ushort4 hh, ll;
    split4(o, hh, ll);
    *(ushort4*)&qhG[ob] = hh;
    *(ushort4*)&qlG[ob] = ll;
  }
  {
    const int ci = 1024 + h * 64 + d4;
    const float sc = innorm[16 + h];
    float4 o = {cs[ci] * sc, cs[ci + 1] * sc, cs[ci + 2] * sc, cs[ci + 3] * sc};
    ushort4 hh, ll;
    split4(o, hh, ll);
    *(ushort4*)&khG[ob] = hh;
    *(ushort4*)&klG[ob] = ll;
  }
  {
    const int ci = 2048 + h * 64 + d4;
    float4 o = {cs[ci], cs[ci + 1], cs[ci + 2], cs[ci + 3]};
    ushort4 hh, ll;
    split4(o, hh, ll);
    *(ushort4*)&vhG[ob] = hh;
    *(ushort4*)&vlG[ob] = ll;
  }
}

// ---------------- k_prepmn: fused T=(I+A)^{-1} + per-chunk affine map (M,N) ----------------
// LDS: 8 tiles. Kb tiles become Tb tiles after K.K^T; Af (f32 16KB) aliases X1 tiles.
__global__ __launch_bounds__(256) void k_prepmn(const u16* __restrict__ khG, const u16* __restrict__ klG,
                                                const u16* __restrict__ vhG, const u16* __restrict__ vlG,
                                                const float* __restrict__ gG, const float* __restrict__ betaG,
                                                float* __restrict__ gcG,
                                                u16* __restrict__ Tgh, u16* __restrict__ Tgl,
                                                u16* __restrict__ Mh, u16* __restrict__ Ml,
                                                u16* __restrict__ Nh, u16* __restrict__ Nl) {
  extern __shared__ __align__(16) char smem[];
  u16* base = (u16*)smem;
  u16* Kbh  = base + 0 * 4096;   // -> Tbh after subst
  u16* Kbl  = base + 1 * 4096;   // -> Tbl
  u16* Tbh  = Kbh;
  u16* Tbl  = Kbl;
  u16* X1h  = base + 2 * 4096;   // Af region first, then X1
  u16* X1l  = base + 3 * 4096;
  u16* KdTh = base + 4 * 4096;
  u16* KdTl = base + 5 * 4096;
  u16* X2h  = base + 6 * 4096;
  u16* X2l  = base + 7 * 4096;
  float* Af = (float*)(base + 2 * 4096);   // 16KB alias over X1h/X1l
  float* gcs = (float*)(base + 8 * 4096);
  float* bs  = gcs + 64;

  const int bhc = blockIdx.x;              // b*1024 + h*64 + c
  const int c = bhc & 63, h = (bhc >> 6) & 15, bb = bhc >> 10;
  const int tid = threadIdx.x, w = tid >> 6, l = tid & 63;
  const int lrow = l & 15, lk8 = (l >> 4) * 8, rbase = (l >> 4) * 4;
  const int t0 = c * 64;
  const size_t rowbase = (size_t)bb * 4096;
  const size_t ktile = (size_t)bhc * 4096;

  // ---- stage K tiles (GLDS, pre-swizzled global -> SW-layout LDS) ----
#pragma unroll
  for (int i = 0; i < 2; ++i) {
    const int o8 = (tid + 256 * i) * 8;
    GLDS16(khG + ktile + o8, &Kbh[o8]);
    GLDS16(klG + ktile + o8, &Kbl[o8]);
  }
  if (tid < 64) {   // gc cumsum + beta (wave 0)
    float gv = gG[(rowbase + t0 + tid) * 16 + h];
    float sc = gv;
#pragma unroll
    for (int off = 1; off < 64; off <<= 1) {
      float o = __shfl_up(sc, off);
      if (tid >= off) sc += o;
    }
    gcs[tid] = sc;
    bs[tid] = betaG[(rowbase + t0 + tid) * 16 + h];
    gcG[(size_t)bhc * 64 + tid] = sc;
  }
  __syncthreads();

  // ---- K @ K^T distributed: wave w = row-quadrant i ----
  f32x4 acc[4];
#pragma unroll
  for (int j = 0; j < 4; ++j) acc[j] = {0.f, 0.f, 0.f, 0.f};
#pragma unroll
  for (int ks = 0; ks < 2; ++ks) {
    bf16x8 afh = *(const bf16x8*)&Kbh[SW(w * 16 + lrow, ks * 32 + lk8)];
    bf16x8 afl = *(const bf16x8*)&Kbl[SW(w * 16 + lrow, ks * 32 + lk8)];
#pragma unroll
    for (int j = 0; j < 4; ++j) {
      bf16x8 bfh = *(const bf16x8*)&Kbh[SW(j * 16 + lrow, ks * 32 + lk8)];
      bf16x8 bfl = *(const bf16x8*)&Kbl[SW(j * 16 + lrow, ks * 32 + lk8)];
      acc[j] = mm3(afh, afl, bfh, bfl, acc[j]);
    }
  }
  __syncthreads();   // all Kb fragment reads done (Kb stays; Af goes to X1 region)
#pragma unroll
  for (int j = 0; j < 4; ++j)
#pragma unroll
    for (int r = 0; r < 4; ++r) {
      const int t = w * 16 + rbase + r, s = j * 16 + lrow;
      Af[t * 64 + s] = (s < t) ? bs[t] * expf(gcs[t] - gcs[s]) * acc[j][r] : 0.f;
    }
  __syncthreads();   // Af ready

  const float gc63 = gcs[63];
  if (tid < 64) {
    // ---- forward substitution (wave 0; X in registers, static unroll) ----
    float x[64];
#pragma unroll
    for (int t = 0; t < 64; ++t) {
      float sum = 0.f;
#pragma unroll
      for (int s4 = 0; s4 + 4 <= t; s4 += 4) {
        float4 a4 = *(const float4*)&Af[t * 64 + s4];
        sum += a4.x * x[s4] + a4.y * x[s4 + 1] + a4.z * x[s4 + 2] + a4.w * x[s4 + 3];
      }
#pragma unroll
      for (int s = (t & ~3); s < t; ++s) sum += Af[t * 64 + s] * x[s];
      x[t] = ((t == tid) ? 1.f : 0.f) - sum;
    }
    // write T: LDS (over dead Kb tiles) + global (for scan2)
#pragma unroll
    for (int t = 0; t < 64; ++t) {
      u16 hi, lo;
      splitbf(x[t], hi, lo);
      Tbh[SW(t, tid)] = hi;
      Tbl[SW(t, tid)] = lo;
      Tgh[(size_t)bhc * 4096 + SW(t, tid)] = hi;
      Tgl[(size_t)bhc * 4096 + SW(t, tid)] = lo;
    }
  } else {
    // ---- waves 1-3: build KdT and X2 (from global K/V; independent of Af/T) ----
    for (int i2 = tid - 64; i2 < 4096; i2 += 192) {
      const int s = i2 >> 6, d = i2 & 63;
      const int sws = SW(s, d);
      const float kf = bf2f(khG[ktile + sws]) + bf2f(klG[ktile + sws]);
      u16 hh, ll;
      splitbf(expf(gc63 - gcs[s]) * kf, hh, ll);
      KdTh[SW(d, s)] = hh; KdTl[SW(d, s)] = ll;
      const float vv = bf2f(vhG[ktile + sws]) + bf2f(vlG[ktile + sws]);
      splitbf(bs[s] * vv, hh, ll);
      X2h[SW(d, s)] = hh; X2l[SW(d, s)] = ll;
    }
  }
  __syncthreads();   // T + KdT + X2 ready; Af dead

  // ---- build X1 (over Af region) ----
#pragma unroll
  for (int i = 0; i < 16; ++i) {
    const int flat = tid + 256 * i;
    const int s = flat >> 6, d = flat & 63;
    const int sws = SW(s, d);
    const float kf = bf2f(khG[ktile + sws]) + bf2f(klG[ktile + sws]);
    u16 hh, ll;
    splitbf(bs[s] * expf(gcs[s]) * kf, hh, ll);
    X1h[SW(d, s)] = hh; X1l[SW(d, s)] = ll;
  }
  __syncthreads();

  // ---- W = T @ X1, u = T @ X2 ----
  f32x4 aW[4], aU[4];
#pragma unroll
  for (int j = 0; j < 4; ++j) { aW[j] = {0.f,0.f,0.f,0.f}; aU[j] = {0.f,0.f,0.f,0.f}; }
#pragma unroll
  for (int ks = 0; ks < 2; ++ks) {
    const int ao = SW(w * 16 + lrow, ks * 32 + lk8);
    bf16x8 aTh = *(const bf16x8*)&Tbh[ao];
    bf16x8 aTl = *(const bf16x8*)&Tbl[ao];
#pragma unroll
    for (int j = 0; j < 4; ++j) {
      const int bo = SW(j * 16 + lrow, ks * 32 + lk8);
      aW[j] = mm3(aTh, aTl, *(const bf16x8*)&X1h[bo], *(const bf16x8*)&X1l[bo], aW[j]);
      aU[j] = mm3(aTh, aTl, *(const bf16x8*)&X2h[bo], *(const bf16x8*)&X2l[bo], aU[j]);
    }
  }
  __syncthreads();
#pragma unroll
  for (int j = 0; j < 4; ++j)
#pragma unroll
    for (int r = 0; r < 4; ++r) {
      const int t = w * 16 + rbase + r, dcol = j * 16 + lrow;
      u16 hh, ll;
      splitbf(aW[j][r], hh, ll);
      X1h[SW(dcol, t)] = hh; X1l[SW(dcol, t)] = ll;
      splitbf(aU[j][r], hh, ll);
      X2h[SW(dcol, t)] = hh; X2l[SW(dcol, t)] = ll;
    }
  __syncthreads();

  // ---- M = decC I - Kd^T W ; N = Kd^T u ----
  f32x4 aM[4], aN[4];
#pragma unroll
  for (int j = 0; j < 4; ++j) { aM[j] = {0.f,0.f,0.f,0.f}; aN[j] = {0.f,0.f,0.f,0.f}; }
#pragma unroll
  for (int ks = 0; ks < 2; ++ks) {
    const int ao = SW(w * 16 + lrow, ks * 32 + lk8);
    bf16x8 aKh = *(const bf16x8*)&KdTh[ao];
    bf16x8 aKl = *(const bf16x8*)&KdTl[ao];
#pragma unroll
    for (int j = 0; j < 4; ++j) {
      const int bo = SW(j * 16 + lrow, ks * 32 + lk8);
      aM[j] = mm3(aKh, aKl, *(const bf16x8*)&X1h[bo], *(const bf16x8*)&X1l[bo], aM[j]);
      aN[j] = mm3(aKh, aKl, *(const bf16x8*)&X2h[bo], *(const bf16x8*)&X2l[bo], aN[j]);
    }
  }
  __syncthreads();
  const float decC = expf(gc63);
#pragma unroll
  for (int j = 0; j < 4; ++j)
#pragma unroll
    for (int r = 0; r < 4; ++r) {
      const int d = w * 16 + rbase + r, d2 = j * 16 + lrow;
      u16 hh, ll;
      splitbf(((d == d2) ? decC : 0.f) - aM[j][r], hh, ll);
      X1h[SW(d, d2)] = hh; X1l[SW(d, d2)] = ll;
      splitbf(aN[j][r], hh, ll);
      X2h[SW(d, d2)] = hh; X2l[SW(d, d2)] = ll;
    }
  __syncthreads();
#pragma unroll
  for (int i = 0; i < 2; ++i) {   // linear copy out -> globals hold swizzled tiles
    const int idx = tid + 256 * i;
    const int off = idx * 8;
    *(float4*)&Mh[(size_t)bhc * 4096 + off] = *(const float4*)&X1h[off];
    *(float4*)&Ml[(size_t)bhc * 4096 + off] = *(const float4*)&X1l[off];
    *(float4*)&Nh[(size_t)bhc * 4096 + off] = *(const float4*)&X2h[off];
    *(float4*)&Nl[(size_t)bhc * 4096 + off] = *(const float4*)&X2l[off];
  }
}

// ---------------- k_seg: compose 8 chunks (swizzled tiles throughout) ----------------
__global__ __launch_bounds__(256) void k_seg(const u16* __restrict__ Mh, const u16* __restrict__ Ml,
                                             const u16* __restrict__ Nh, const u16* __restrict__ Nl,
                                             u16* __restrict__ Msegh, u16* __restrict__ Msegl,
                                             u16* __restrict__ Nsegh, u16* __restrict__ Nsegl) {
  extern __shared__ __align__(16) char smem[];
  u16* base = (u16*)smem;
  u16* MaTh = base + 0 * 4096;
  u16* MaTl = base + 1 * 4096;
  u16* NaTh = base + 2 * 4096;
  u16* NaTl = base + 3 * 4096;
  u16* sMh  = base + 4 * 4096;
  u16* sMl  = base + 5 * 4096;
  u16* sNh  = base + 6 * 4096;
  u16* sNl  = base + 7 * 4096;

  const int blk = blockIdx.x;                       // bh*8 + seg
  const size_t cbase = (size_t)(blk >> 3) * 64 + (blk & 7) * 8;
  const int tid = threadIdx.x, w = tid >> 6, l = tid & 63;
  const int lrow = l & 15, lk8 = (l >> 4) * 8, rbase = (l >> 4) * 4;

#pragma unroll
  for (int i = 0; i < 2; ++i) {
    const int off = (tid + 256 * i) * 8;
    *(float4*)&sMh[off] = *(const float4*)&Mh[cbase * 4096 + off];
    *(float4*)&sMl[off] = *(const float4*)&Ml[cbase * 4096 + off];
    *(float4*)&sNh[off] = *(const float4*)&Nh[cbase * 4096 + off];
    *(float4*)&sNl[off] = *(const float4*)&Nl[cbase * 4096 + off];
  }
  __syncthreads();
#pragma unroll
  for (int i = 0; i < 16; ++i) {       // transpose into accumulators
    const int flat = tid + 256 * i;
    const int a = flat >> 6, b = flat & 63;
    MaTh[SW(a, b)] = sMh[SW(b, a)];
    MaTl[SW(a, b)] = sMl[SW(b, a)];
    NaTh[SW(a, b)] = sNh[SW(b, a)];
    NaTl[SW(a, b)] = sNl[SW(b, a)];
  }
  __syncthreads();

  for (int j = 1; j < 8; ++j) {
#pragma unroll
    for (int i = 0; i < 2; ++i) {
      const int off = (tid + 256 * i) * 8;
      *(float4*)&sMh[off] = *(const float4*)&Mh[(cbase + j) * 4096 + off];
      *(float4*)&sMl[off] = *(const float4*)&Ml[(cbase + j) * 4096 + off];
      *(float4*)&sNh[off] = *(const float4*)&Nh[(cbase + j) * 4096 + off];
      *(float4*)&sNl[off] = *(const float4*)&Nl[(cbase + j) * 4096 + off];
    }
    __syncthreads();
    f32x4 aM2[4], aN2[4];
#pragma unroll
    for (int jj = 0; jj < 4; ++jj) { aM2[jj] = {0.f,0.f,0.f,0.f}; aN2[jj] = {0.f,0.f,0.f,0.f}; }
#pragma unroll
    for (int ks = 0; ks < 2; ++ks) {
      const int ao = SW(w * 16 + lrow, ks * 32 + lk8);
      bf16x8 aCh = *(const bf16x8*)&sMh[ao];
      bf16x8 aCl = *(const bf16x8*)&sMl[ao];
#pragma unroll
      for (int jj = 0; jj < 4; ++jj) {
        const int bo = SW(jj * 16 + lrow, ks * 32 + lk8);
        aM2[jj] = mm3(aCh, aCl, *(const bf16x8*)&MaTh[bo], *(const bf16x8*)&MaTl[bo], aM2[jj]);
        aN2[jj] = mm3(aCh, aCl, *(const bf16x8*)&NaTh[bo], *(const bf16x8*)&NaTl[bo], aN2[jj]);
      }
    }
    __syncthreads();
#pragma unroll
    for (int jj = 0; jj < 4; ++jj)
#pragma unroll
      for (int r = 0; r < 4; ++r) {
        const int t = w * 16 + rbase + r, col = jj * 16 + lrow;
        u16 hh, ll;
        splitbf(aM2[jj][r], hh, ll);
        MaTh[SW(col, t)] = hh; MaTl[SW(col, t)] = ll;
        const float nv = aN2[jj][r] + bf2f(sNh[SW(t, col)]) + bf2f(sNl[SW(t, col)]);
        splitbf(nv, hh, ll);
        NaTh[SW(col, t)] = hh; NaTl[SW(col, t)] = ll;
      }
    __syncthreads();
  }
#pragma unroll
  for (int i = 0; i < 16; ++i) {       // un-transpose; globals swizzled
    const int flat = tid + 256 * i;
    const int t = flat >> 6, s = flat & 63;
    Msegh[(size_t)blk * 4096 + SW(t, s)] = MaTh[SW(s, t)];
    Msegl[(size_t)blk * 4096 + SW(t, s)] = MaTl[SW(s, t)];
    Nsegh[(size_t)blk * 4096 + SW(t, s)] = NaTh[SW(s, t)];
    Nsegl[(size_t)blk * 4096 + SW(t, s)] = NaTl[SW(s, t)];
  }
}

// ---------------- k_bound: sequential 8-step prefix (S^T tiles, swizzled; Sseg global swizzled) ----------------
__global__ __launch_bounds__(256) void k_bound(const u16* __restrict__ Msegh, const u16* __restrict__ Msegl,
                                               const u16* __restrict__ Nsegh, const u16* __restrict__ Nsegl,
                                               u16* __restrict__ Ssegh, u16* __restrict__ Ssegl) {
  __shared__ __align__(16) u16 STh[4096], STl[4096];
  __shared__ __align__(16) u16 sMh[4096], sMl[4096], sNh[4096], sNl[4096];
  const int bh = blockIdx.x;
  const int tid = threadIdx.x, w = tid >> 6, l = tid & 63;
  const int lrow = l & 15, lk8 = (l >> 4) * 8, rbase = (l >> 4) * 4;
  for (int i = tid; i < 4096; i += 256) { STh[i] = (u16)0; STl[i] = (u16)0; }
  __syncthreads();
  for (int j = 0; j < 8; ++j) {
    const size_t sb = (size_t)(bh * 8 + j) * 4096;
#pragma unroll
    for (int i = 0; i < 2; ++i) {
      const int off = (tid + 256 * i) * 8;
      *(float4*)&Ssegh[sb + off] = *(const float4*)&STh[off];   // linear copies (all swizzled)
      *(float4*)&Ssegl[sb + off] = *(const float4*)&STl[off];
      *(float4*)&sMh[off] = *(const float4*)&Msegh[sb + off];
      *(float4*)&sMl[off] = *(const float4*)&Msegl[sb + off];
      *(float4*)&sNh[off] = *(const float4*)&Nsegh[sb + off];
      *(float4*)&sNl[off] = *(const float4*)&Nsegl[sb + off];
    }
    __syncthreads();
    f32x4 acc[4];
#pragma unroll
    for (int jj = 0; jj < 4; ++jj) acc[jj] = {0.f, 0.f, 0.f, 0.f};
#pragma unroll
    for (int ks = 0; ks < 2; ++ks) {
      const int ao = SW(w * 16 + lrow, ks * 32 + lk8);
      bf16x8 aSh = *(const bf16x8*)&STh[ao];
      bf16x8 aSl = *(const bf16x8*)&STl[ao];
#pragma unroll
      for (int jj = 0; jj < 4; ++jj) {
        const int bo = SW(jj * 16 + lrow, ks * 32 + lk8);
        acc[jj] = mm3(aSh, aSl, *(const bf16x8*)&sMh[bo], *(const bf16x8*)&sMl[bo], acc[jj]);
      }
    }
    __syncthreads();
#pragma unroll
    for (int jj = 0; jj < 4; ++jj)
#pragma unroll
      for (int r = 0; r < 4; ++r) {
        const int v = w * 16 + rbase + r, t = jj * 16 + lrow;
        const float sv = acc[jj][r] + bf2f(sNh[SW(t, v)]) + bf2f(sNl[SW(t, v)]);
        u16 hh, ll;
        splitbf(sv, hh, ll);
        STh[SW(v, t)] = hh; STl[SW(v, t)] = ll;
      }
    __syncthreads();
  }
}

// ---------------- k_scan2: 8-chunk scan per (bh,seg); 8 waves, GLDS pipeline, hoisted exps ----------------
__global__ __launch_bounds__(512, 2) void k_scan2(const u16* __restrict__ qhG, const u16* __restrict__ qlG,
                                               const u16* __restrict__ khG, const u16* __restrict__ klG,
                                               const u16* __restrict__ vhG, const u16* __restrict__ vlG,
                                               const u16* __restrict__ zb,
                                               const u16* __restrict__ Tgh, const u16* __restrict__ Tgl,
                                               const float* __restrict__ gcG,
                                               const float* __restrict__ betaG, const float* __restrict__ norm_w,
                                               const u16* __restrict__ Ssegh, const u16* __restrict__ Ssegl,
                                               u16* __restrict__ Yhi, u16* __restrict__ Ylo) {
  extern __shared__ __align__(16) char smem[];
  u16* base = (u16*)smem;
  u16* Kbh  = base + 0 * 4096;
  u16* Kbl  = base + 1 * 4096;
  u16* Qbh  = base + 2 * 4096;
  u16* Qbl  = base + 3 * 4096;
  u16* Vbh  = base + 4 * 4096;
  u16* Vbl  = base + 5 * 4096;
  u16* Zb   = base + 6 * 4096;
  u16* Tbh  = base + 7 * 4096;
  u16* Tbl  = base + 8 * 4096;
  u16* SbTh = base + 9 * 4096;
  u16* SbTl = base + 10 * 4096;
  u16* Mqh  = base + 11 * 4096;
  u16* Mql  = base + 12 * 4096;
  u16* KdTh = base + 13 * 4096;
  u16* KdTl = base + 14 * 4096;
  u16* RTh  = base + 15 * 4096;
  u16* RTl  = base + 16 * 4096;
  u16* UTh  = base + 17 * 4096;
  u16* UTl  = base + 18 * 4096;
  u16* Ybh  = RTh;   // RT dead after phase B
  u16* Ybl  = RTl;
  float* gcs = (float*)(base + 19 * 4096);
  float* bs  = gcs + 64;
  float* nws = gcs + 128;
  float* esF = gcs + 192;   // exp(gc63 - gcs[s])
  float* etF = gcs + 256;   // exp(gcs[t])
  float* ssP = gcs + 320;   // [2][64] RMS partials

  const int blk = blockIdx.x;             // bh*8 + seg
  const int bh = blk >> 3, seg = blk & 7;
  const int bb = bh >> 4, h = bh & 15;
  const int tid = threadIdx.x, w = tid >> 6, l = tid & 63;
  const int wrow = w >> 1, jh = w & 1;            // row quadrant, j-half
  const int lrow = l & 15, lk8 = (l >> 4) * 8, rbase = (l >> 4) * 4;
  const size_t rowbase = (size_t)bb * 4096;
  const size_t bhTile = (size_t)bh * 64;
  const int o8 = tid * 8;
  const int zr = tid >> 3, zc8 = (tid & 7) << 3;  // 512-thread float4 tile mapping

  // ---- prologue: GLDS stage everything for chunk seg*8 ----
  {
    const int c = seg * 8, t0 = c * 64;
    const size_t gt = (bhTile + c) * 4096;
    GLDS16(qhG + gt + o8, &Qbh[o8]);
    GLDS16(qlG + gt + o8, &Qbl[o8]);
    GLDS16(khG + gt + o8, &Kbh[o8]);
    GLDS16(klG + gt + o8, &Kbl[o8]);
    GLDS16(vhG + gt + o8, &Vbh[o8]);
    GLDS16(vlG + gt + o8, &Vbl[o8]);
    GLDS16(Tgh + (size_t)(bh * 64 + c) * 4096 + o8, &Tbh[o8]);
    GLDS16(Tgl + (size_t)(bh * 64 + c) * 4096 + o8, &Tbl[o8]);
    GLDS16(Ssegh + (size_t)blk * 4096 + o8, &SbTh[o8]);
    GLDS16(Ssegl + (size_t)blk * 4096 + o8, &SbTl[o8]);
    *(float4*)&Zb[SW(zr, zc8)] = *(const float4*)&zb[(rowbase + t0 + zr) * 1024 + h * 64 + zc8];
    if (tid < 64) {
      nws[tid] = norm_w[tid];
      float g0 = gcG[((size_t)bh * 64 + c) * 64 + tid];
      float b0 = betaG[(rowbase + t0 + tid) * 16 + h];
      float g63 = __shfl(g0, 63);
      gcs[tid] = g0; bs[tid] = b0;
      esF[tid] = expf(g63 - g0);
      etF[tid] = expf(g0);
    }
  }
  __syncthreads();

  for (int cc = 0; cc < 8; ++cc) {
    const int c = seg * 8 + cc;
    const int t0 = c * 64;
    const bool pf = (cc < 7);
    const size_t gt1 = (bhTile + c + 1) * 4096;

    // ---- tiny register prefetch: z, gc, bs for chunk c+1 ----
    float4 pz;
    float pgc = 0.f, pbs = 0.f;
    if (pf) {
      const int t1 = t0 + 64;
      pz = *(const float4*)&zb[(rowbase + t1 + zr) * 1024 + h * 64 + zc8];
      if (tid < 64) {
        pgc = gcG[((size_t)bh * 64 + (c + 1)) * 64 + tid];
        pbs = betaG[(rowbase + t1 + tid) * 16 + h];
      }
    }

    // ---- phase A: KdT build (no expf: esF) ----
#pragma unroll
    for (int i = 0; i < 8; ++i) {
      const int flat = tid * 8 + i;
      const int d = flat >> 6, s = flat & 63;
      const float kv = bf2f(Kbh[SW(s, d)]) + bf2f(Kbl[SW(s, d)]);
      u16 hh, ll;
      splitbf(esF[s] * kv, hh, ll);
      KdTh[SW(d, s)] = hh;
      KdTl[SW(d, s)] = ll;
    }
    f32x4 aqk[2], ap[2], aqs[2];
#pragma unroll
    for (int j = 0; j < 2; ++j) { aqk[j] = {0.f,0.f,0.f,0.f}; ap[j] = {0.f,0.f,0.f,0.f}; aqs[j] = {0.f,0.f,0.f,0.f}; }
#pragma unroll
    for (int ks = 0; ks < 2; ++ks) {
      const int ao = SW(wrow * 16 + lrow, ks * 32 + lk8);
      bf16x8 aKh = *(const bf16x8*)&Kbh[ao];
      bf16x8 aKl = *(const bf16x8*)&Kbl[ao];
      bf16x8 aQh = *(const bf16x8*)&Qbh[ao];
      bf16x8 aQl = *(const bf16x8*)&Qbl[ao];
#pragma unroll
      for (int j = 0; j < 2; ++j) {
        const int jj = jh * 2 + j;
        const int bo = SW(jj * 16 + lrow, ks * 32 + lk8);
        bf16x8 bKh = *(const bf16x8*)&Kbh[bo];
        bf16x8 bKl = *(const bf16x8*)&Kbl[bo];
        bf16x8 bSh = *(const bf16x8*)&SbTh[bo];
        bf16x8 bSl = *(const bf16x8*)&SbTl[bo];
        aqk[j] = mm3(aQh, aQl, bKh, bKl, aqk[j]);
        ap[j]  = mm3(aKh, aKl, bSh, bSl, ap[j]);
        aqs[j] = mm3(aQh, aQl, bSh, bSl, aqs[j]);
      }
    }
#pragma unroll
    for (int j = 0; j < 2; ++j)
#pragma unroll
      for (int r = 0; r < 4; ++r) {
        const int t = wrow * 16 + rbase + r;
        const int s = (jh * 2 + j) * 16 + lrow;
        u16 mh, ml;
        splitbf((s <= t) ? expf(gcs[t] - gcs[s]) * aqk[j][r] : 0.f, mh, ml);
        Mqh[SW(t, s)] = mh;
        Mql[SW(t, s)] = ml;
        const float vv = bf2f(Vbh[SW(t, s)]) + bf2f(Vbl[SW(t, s)]);
        const float rhs = bs[t] * (vv - etF[t] * ap[j][r]);
        u16 rh, rl;
        splitbf(rhs, rh, rl);
        RTh[SW(s, t)] = rh;
        RTl[SW(s, t)] = rl;
      }
    __syncthreads();                        // barrier A

    // ---- Q/K/V dead: async GLDS chunk c+1 Q/K/V (drains at barrier B) ----
    if (pf) {
      GLDS16(qhG + gt1 + o8, &Qbh[o8]);
      GLDS16(qlG + gt1 + o8, &Qbl[o8]);
      GLDS16(khG + gt1 + o8, &Kbh[o8]);
      GLDS16(klG + gt1 + o8, &Kbl[o8]);
      GLDS16(vhG + gt1 + o8, &Vbh[o8]);
      GLDS16(vlG + gt1 + o8, &Vbl[o8]);
    }

    // ---- phase B: U = T @ RHS ----
    f32x4 au[2];
#pragma unroll
    for (int j = 0; j < 2; ++j) au[j] = {0.f, 0.f, 0.f, 0.f};
#pragma unroll
    for (int ks = 0; ks < 2; ++ks) {
      const int ao = SW(wrow * 16 + lrow, ks * 32 + lk8);
      bf16x8 aTh = *(const bf16x8*)&Tbh[ao];
      bf16x8 aTl = *(const bf16x8*)&Tbl[ao];
#pragma unroll
      for (int j = 0; j < 2; ++j) {
        const int bo = SW((jh * 2 + j) * 16 + lrow, ks * 32 + lk8);
        au[j] = mm3(aTh, aTl, *(const bf16x8*)&RTh[bo], *(const bf16x8*)&RTl[bo], au[j]);
      }
    }
#pragma unroll
    for (int j = 0; j < 2; ++j)
#pragma unroll
      for (int r = 0; r < 4; ++r) {
        u16 uh, ul;
        splitbf(au[j][r], uh, ul);
        const int o = SW((jh * 2 + j) * 16 + lrow, wrow * 16 + rbase + r);
        UTh[o] = uh;
        UTl[o] = ul;
      }
    __syncthreads();                        // barrier B (drains Q/K/V GLDS)

    // ---- T dead: async GLDS chunk c+1 T (drains at barrier C) ----
    if (pf) {
      GLDS16(Tgh + (size_t)(bh * 64 + (c + 1)) * 4096 + o8, &Tbh[o8]);
      GLDS16(Tgl + (size_t)(bh * 64 + (c + 1)) * 4096 + o8, &Tbl[o8]);
    }

    // ---- phase C ----
    f32x4 amu[2], as_[2];
#pragma unroll
    for (int j = 0; j < 2; ++j) { amu[j] = {0.f,0.f,0.f,0.f}; as_[j] = {0.f,0.f,0.f,0.f}; }
#pragma unroll
    for (int ks = 0; ks < 2; ++ks) {
      const int ao = SW(wrow * 16 + lrow, ks * 32 + lk8);
      bf16x8 aMh = *(const bf16x8*)&Mqh[ao];
      bf16x8 aMl = *(const bf16x8*)&Mql[ao];
      bf16x8 aKdh = *(const bf16x8*)&KdTh[ao];
      bf16x8 aKdl = *(const bf16x8*)&KdTl[ao];
#pragma unroll
      for (int j = 0; j < 2; ++j) {
        const int bo = SW((jh * 2 + j) * 16 + lrow, ks * 32 + lk8);
        bf16x8 bUh = *(const bf16x8*)&UTh[bo];
        bf16x8 bUl = *(const bf16x8*)&UTl[bo];
        amu[j] = mm3(aMh, aMl, bUh, bUl, amu[j]);
        as_[j] = mm3(aKdh, aKdl, bUh, bUl, as_[j]);
      }
    }
    // y values + cross-wave RMS partials
    float yv_[4][2];
#pragma unroll
    for (int r = 0; r < 4; ++r) {
      const int t = wrow * 16 + rbase + r;
      const float gt = etF[t];
      float ss = 0.f;
#pragma unroll
      for (int j = 0; j < 2; ++j) {
        yv_[r][j] = gt * aqs[j][r] + amu[j][r];
        ss += yv_[r][j] * yv_[r][j];
      }
      ss += __shfl_xor(ss, 1); ss += __shfl_xor(ss, 2); ss += __shfl_xor(ss, 4); ss += __shfl_xor(ss, 8);
      if (lrow == 0) ssP[jh * 64 + t] = ss;
    }
    __syncthreads();                        // publish RMS partials
#pragma unroll
    for (int r = 0; r < 4; ++r) {
      const int t = wrow * 16 + rbase + r;
      const float rstd = rsqrtf((ssP[t] + ssP[64 + t]) * (1.f / 64.f) + 1e-6f);
#pragma unroll
      for (int j = 0; j < 2; ++j) {
        const int col = (jh * 2 + j) * 16 + lrow;
        const float zz = bf2f(Zb[SW(t, col)]);
        const float yv = yv_[r][j] * rstd * nws[col] * (zz / (1.f + expf(-zz)));
        u16 yh, yl;
        splitbf(yv, yh, yl);
        Ybh[SW(t, col)] = yh;
        Ybl[SW(t, col)] = yl;
      }
    }
    {
      const float decC = etF[63];
#pragma unroll
      for (int j = 0; j < 2; ++j)
#pragma unroll
        for (int r = 0; r < 4; ++r) {
          const int d = wrow * 16 + rbase + r, col = (jh * 2 + j) * 16 + lrow;
          const int o = SW(col, d);
          const float s0 = bf2f(SbTh[o]) + bf2f(SbTl[o]);
          const float sv = decC * s0 + as_[j][r];
          u16 sh, sl;
          splitbf(sv, sh, sl);
          SbTh[o] = sh;
          SbTl[o] = sl;
        }
    }
    __syncthreads();                        // barrier C (drains T GLDS)

    // ---- store Y (pre-swizzled for GEMM2); write prefetched z; update gcs/bs/esF/etF ----
    {
      const size_t gsw = gidx_swz(rowbase + t0 + zr, h * 64 + zc8, 1024);
      *(float4*)&Yhi[gsw] = *(const float4*)&Ybh[SW(zr, zc8)];
      *(float4*)&Ylo[gsw] = *(const float4*)&Ybl[SW(zr, zc8)];
    }
    if (pf) {
      *(float4*)&Zb[SW(zr, zc8)] = pz;
      if (tid < 64) {
        float g63 = __shfl(pgc, 63);
        gcs[tid] = pgc; bs[tid] = pbs;
        esF[tid] = expf(g63 - pgc);
        etF[tid] = expf(pgc);
      }
    }
    __syncthreads();                        // barrier D
  }
}

extern "C" void kernel_launch(void* const* d_in, const int* in_sizes, int n_in,
                              void* d_out, int out_size, void* d_ws, size_t ws_size,
                              hipStream_t stream) {
  (void)in_sizes; (void)n_in; (void)out_size; (void)ws_size;
  const float* x       = (const float*)d_in[0];
  const float* W_in    = (const float*)d_in[1];
  const float* W_ba    = (const float*)d_in[2];
  const float* conv_w  = (const float*)d_in[3];
  const float* dt_bias = (const float*)d_in[4];
  const float* A_log   = (const float*)d_in[5];
  const float* norm_w  = (const float*)d_in[6];
  const float* W_o     = (const float*)d_in[7];
  float* out = (float*)d_out;
  char* ws = (char*)d_ws;
  const size_t MB = 1048576;

  _Float16* xh = (_Float16*)(ws + 0);     // 16 MB f16 x (pre-swizzled) -> Mh -> Yhi
  u16* MhB   = (u16*)(ws + 0);
  u16* YhiB  = (u16*)(ws + 0);
  u16* MlB   = (u16*)(ws + 16 * MB);      // 16 MB Ml -> Ylo
  u16* YloB  = (u16*)(ws + 16 * MB);
  _Float16* WinT = (_Float16*)(ws + 32 * MB);  // 8 MB f16 (pre-swizzled, dead post-GEMM1)
  float* gB  = (float*)(ws + 32 * MB);             // 0.5 MB (post-GEMM1)
  float* bB  = (float*)(ws + 32 * MB + 524288);    // 0.5 MB
  float* gcB = (float*)(ws + 33 * MB);             // 0.5 MB
  u16* Ssegh = (u16*)(ws + 34 * MB);      // 2 MB
  u16* Ssegl = (u16*)(ws + 36 * MB);      // 2 MB
  u16* Msegh = (u16*)(ws + 38 * MB);      // 2 MB
  u16* Msegl = (u16*)(ws + 40 * MB);      // 2 MB
  u16* Nsegh = (u16*)(ws + 42 * MB);      // 2 MB
  u16* Nsegl = (u16*)(ws + 44 * MB);      // 2 MB
  u16* WoT   = (u16*)(ws + 48 * MB);      // 2 MB (pre-swizzled)
  u16* qkv3  = (u16*)(ws + 50 * MB);      // 48 MB (dead post-conv)
  u16* NhB   = (u16*)(ws + 50 * MB);      // 16 MB
  u16* NlB   = (u16*)(ws + 66 * MB);      // 16 MB
  u16* zbB   = (u16*)(ws + 98 * MB);      // 16 MB (GEMM-major)
  u16* qhG   = (u16*)(ws + 114 * MB);     // 16 MB (per-(b,h) swizzled tiles)
  u16* qlG   = (u16*)(ws + 130 * MB);     // 16 MB
  u16* khG   = (u16*)(ws + 146 * MB);     // 16 MB
  u16* klG   = (u16*)(ws + 162 * MB);     // 16 MB
  u16* vhG   = (u16*)(ws + 178 * MB);     // 16 MB
  u16* vlG   = (u16*)(ws + 194 * MB);     // 16 MB
  u16* TghB  = (u16*)(ws + 210 * MB);     // 16 MB
  u16* TglB  = (u16*)(ws + 226 * MB);     // 16 MB  (end 242 MB)

  const int SCAN_LDS = 19 * 8192 + 448 * 4;   // 157440 B
  const int PMN_LDS  = 8 * 8192 + 512;        // 66048 B
  const int SEG_LDS  = 8 * 8192;              // 65536 B

  k_cast_h<<<8192, 256, 0, stream>>>(x, xh, 8388608);
  k_transpose_h<<<dim3(64, 16), 256, 0, stream>>>(W_in, WinT, 1024, 4096);
  k_transpose<<<dim3(16, 16), 256, 0, stream>>>(W_o, WoT, 1024, 1024);
  k_gemm_h<<<dim3(16, 32), 512, 0, stream>>>(xh, WinT, qkv3, zbB, 8192, 4096, 1024);
  k_ba<<<2048, 256, 0, stream>>>(x, W_ba, dt_bias, A_log, bB, gB);
  k_conv<<<8192, 256, 0, stream>>>(qkv3, conv_w, qhG, qlG, khG, klG, vhG, vlG);
  hipFuncSetAttribute((const void*)k_prepmn, hipFuncAttributeMaxDynamicSharedMemorySize, PMN_LDS);
  k_prepmn<<<2048, 256, PMN_LDS, stream>>>(khG, klG, vhG, vlG, gB, bB, gcB, TghB, TglB,
                                           MhB, MlB, NhB, NlB);
  hipFuncSetAttribute((const void*)k_seg, hipFuncAttributeMaxDynamicSharedMemorySize, SEG_LDS);
  k_seg<<<256, 256, SEG_LDS, stream>>>(MhB, MlB, NhB, NlB, Msegh, Msegl, Nsegh, Nsegl);
  k_bound<<<32, 256, 0, stream>>>(Msegh, Msegl, Nsegh, Nsegl, Ssegh, Ssegl);
  hipFuncSetAttribute((const void*)k_scan2, hipFuncAttributeMaxDynamicSharedMemorySize, SCAN_LDS);
  k_scan2<<<256, 512, SCAN_LDS, stream>>>(qhG, qlG, khG, klG, vhG, vlG, zbB, TghB, TglB, gcB, bB, norm_w,
                                          Ssegh, Ssegl, YhiB, YloB);
  k_gemm2<<<dim3(4, 64), 256, 0, stream>>>(YhiB, YloB, WoT, out, 8192, 1024, 1024);
}

// Round 16
// 524.764 us; speedup vs baseline: 1.0246x; 1.0246x over previous
//
#include <hip/hip_runtime.h>

typedef unsigned short u16;
typedef unsigned int u32;
typedef __attribute__((ext_vector_type(8))) __bf16 bf16x8;
typedef __attribute__((ext_vector_type(8))) _Float16 f16x8;
typedef __attribute__((ext_vector_type(4))) _Float16 f16x4;
typedef __attribute__((ext_vector_type(4))) float f32x4;

#define DEV __device__ __forceinline__

DEV u16 f2bf(float f) {
  u32 u = __float_as_uint(f);
  u += 0x7FFFu + ((u >> 16) & 1u);   // RNE
  return (u16)(u >> 16);
}
DEV float bf2f(u16 h) { return __uint_as_float(((u32)h) << 16); }
DEV void splitbf(float f, u16& hi, u16& lo) {
  u16 h = f2bf(f);
  hi = h;
  lo = f2bf(f - bf2f(h));
}
DEV void split4(float4 v, ushort4& hh, ushort4& ll) {
  splitbf(v.x, hh.x, ll.x);
  splitbf(v.y, hh.y, ll.y);
  splitbf(v.z, hh.z, ll.z);
  splitbf(v.w, hh.w, ll.w);
}
// T2 XOR swizzle for 64x64 u16 tiles (128B rows): kills the 16-way ds_read_b128 bank conflict.
DEV int SW(int r, int c) { return r * 64 + ((c) ^ ((r & 7) << 3)); }

// GEMM-tile swizzle: [*][32] u16 K-tiles, double-row (128B) units of 8x16B blocks,
// block index XORed with (row>>1)&7 -> fragment reads become 2-way (free).
DEV int SWG(int r, int c) {
  int db = ((r & 1) << 2) | ((c >> 3) & 3);
  int dbp = db ^ ((r >> 1) & 7);
  return ((r >> 1) << 6) | (dbp << 3) | (c & 7);
}
// producer-side: where logical (row, col) lives in the pre-swizzled global
DEV size_t gidx_swz(size_t row, int col, int rowlen) {
  int rr7 = (int)((row >> 1) & 7);
  int db = (int)(((row & 1) << 2) | ((col >> 3) & 3));
  int dbp = db ^ rr7;
  size_t rowp = (row & ~(size_t)1) | (size_t)(dbp >> 2);
  int colp = (col & ~31) | ((dbp & 3) << 3) | (col & 7);
  return rowp * (size_t)rowlen + colp;
}

#define MFMA16(a,b,c) __builtin_amdgcn_mfma_f32_16x16x32_bf16((a),(b),(c),0,0,0)
#define MFMAH(a,b,c)  __builtin_amdgcn_mfma_f32_16x16x32_f16((a),(b),(c),0,0,0)
#define GLDS16(g,l) __builtin_amdgcn_global_load_lds((__attribute__((address_space(1))) void*)(g), (__attribute__((address_space(3))) void*)(l), 16, 0, 0)

DEV f32x4 mm3(bf16x8 ah, bf16x8 al, bf16x8 bh, bf16x8 bl, f32x4 acc) {
  acc = MFMA16(ah, bl, acc);
  acc = MFMA16(al, bh, acc);
  acc = MFMA16(ah, bh, acc);
  return acc;
}

// ---------------- cast f32 -> f16, pre-swizzled for GEMM staging ----------------
__global__ __launch_bounds__(256) void k_cast_h(const float* __restrict__ in, _Float16* __restrict__ out, int n) {
  int idx = (blockIdx.x * 256 + threadIdx.x) * 4;
  if (idx + 3 < n) {
    float4 v = *(const float4*)(in + idx);
    f16x4 o = {(_Float16)v.x, (_Float16)v.y, (_Float16)v.z, (_Float16)v.w};
    const size_t row = (size_t)(idx >> 10);
    const int col = idx & 1023;
    *(f16x4*)(out + gidx_swz(row, col, 1024)) = o;
  }
}

// ---------------- transpose f32 [R][C] -> f16 [C][R], pre-swizzled ----------------
__global__ __launch_bounds__(256) void k_transpose_h(const float* __restrict__ in, _Float16* __restrict__ out, int R, int Cc) {
  __shared__ float tile[64][65];
  int c0 = blockIdx.x * 64, r0 = blockIdx.y * 64;
  int lr = threadIdx.x >> 6, lc = threadIdx.x & 63;
#pragma unroll
  for (int i = 0; i < 16; ++i) {
    int r = lr + i * 4;
    tile[r][lc] = in[(size_t)(r0 + r) * Cc + c0 + lc];
  }
  __syncthreads();
#pragma unroll
  for (int i = 0; i < 16; ++i) {
    int oc = lr + i * 4;
    out[gidx_swz((size_t)(c0 + oc), r0 + lc, R)] = (_Float16)tile[lc][oc];
  }
}

// ---------------- transpose f32 [R][C] -> bf16 [C][R], pre-swizzled ----------------
__global__ __launch_bounds__(256) void k_transpose(const float* __restrict__ in, u16* __restrict__ out, int R, int Cc) {
  __shared__ float tile[64][65];
  int c0 = blockIdx.x * 64, r0 = blockIdx.y * 64;
  int lr = threadIdx.x >> 6, lc = threadIdx.x & 63;
#pragma unroll
  for (int i = 0; i < 16; ++i) {
    int r = lr + i * 4;
    tile[r][lc] = in[(size_t)(r0 + r) * Cc + c0 + lc];
  }
  __syncthreads();
#pragma unroll
  for (int i = 0; i < 16; ++i) {
    int oc = lr + i * 4;
    out[gidx_swz((size_t)(c0 + oc), r0 + lc, R)] = f2bf(tile[lc][oc]);
  }
}

// ---------------- GEMM1 (f16 single): 256x256 tile, 8 waves, dbuf issue-before-compute ----------------
__global__ __launch_bounds__(512, 2) void k_gemm_h(const _Float16* __restrict__ A, const _Float16* __restrict__ Bt,
                                                   u16* __restrict__ Cq, u16* __restrict__ Cz, int M, int N, int K) {
  __shared__ __align__(16) u16 As[2][256 * 32];
  __shared__ __align__(16) u16 Bs[2][256 * 32];
  const int tid = threadIdx.x;
  const int nwg = gridDim.x * gridDim.y;
  int bid = blockIdx.y * gridDim.x + blockIdx.x;
  bid = (bid & 7) * (nwg >> 3) + (bid >> 3);      // bijective (nwg % 8 == 0)
  const int m0 = (bid / gridDim.x) * 256, n0 = (bid % gridDim.x) * 256;
  const int w = tid >> 6, l = tid & 63;
  const int wr = (w >> 1) * 64, wc = (w & 1) * 128;
  const int lrow = l & 15, lk = (l >> 4) * 8, rbase = (l >> 4) * 4;

  f32x4 acc[4][8];
#pragma unroll
  for (int i = 0; i < 4; ++i)
#pragma unroll
    for (int j = 0; j < 8; ++j) acc[i][j] = {0.f, 0.f, 0.f, 0.f};

  const _Float16* aBase = A + (size_t)m0 * K;
  const _Float16* bBase = Bt + (size_t)n0 * K;
  const int srow0 = tid >> 2, scol0 = (tid & 3) * 8;        // staging chunk 0
  const int srow1 = (tid + 512) >> 2;                       // staging chunk 1 (same scol)

  auto STAGE = [&](int buf, int k0) {
    GLDS16(aBase + (size_t)srow0 * K + k0 + scol0, &As[buf][tid * 8]);
    GLDS16(aBase + (size_t)srow1 * K + k0 + scol0, &As[buf][4096 + tid * 8]);
    GLDS16(bBase + (size_t)srow0 * K + k0 + scol0, &Bs[buf][tid * 8]);
    GLDS16(bBase + (size_t)srow1 * K + k0 + scol0, &Bs[buf][4096 + tid * 8]);
  };

  STAGE(0, 0);
  __syncthreads();
  int cur = 0;
  for (int k0 = 0; k0 < K; k0 += 32) {
    if (k0 + 32 < K) STAGE(cur ^ 1, k0 + 32);   // issue next-tile loads (fly under compute)
    f16x8 af[4], bfr[8];
#pragma unroll
    for (int i = 0; i < 4; ++i) af[i] = *(const f16x8*)&As[cur][SWG(wr + i * 16 + lrow, lk)];
#pragma unroll
    for (int j = 0; j < 8; ++j) bfr[j] = *(const f16x8*)&Bs[cur][SWG(wc + j * 16 + lrow, lk)];
#pragma unroll
    for (int i = 0; i < 4; ++i)
#pragma unroll
      for (int j = 0; j < 8; ++j) acc[i][j] = MFMAH(af[i], bfr[j], acc[i][j]);
    __syncthreads();                            // drains next-tile GLDS + this tile's ds_reads
    cur ^= 1;
  }
#pragma unroll
  for (int i = 0; i < 4; ++i)
#pragma unroll
    for (int j = 0; j < 8; ++j)
#pragma unroll
      for (int r = 0; r < 4; ++r) {
        int row = m0 + wr + i * 16 + rbase + r;
        int col = n0 + wc + j * 16 + lrow;
        if (col < 3072) Cq[(size_t)row * 3072 + col] = f2bf(acc[i][j][r]);
        else            Cz[(size_t)row * 1024 + col - 3072] = f2bf(acc[i][j][r]);
      }
}

// ---------------- GEMM2: 128x256 tile, (Ah+Al) @ Bt^T, f32 out, dbuf ----------------
__global__ __launch_bounds__(256, 2) void k_gemm2(const u16* __restrict__ Ah, const u16* __restrict__ Al,
                                               const u16* __restrict__ Bt, float* __restrict__ Cf,
                                               int M, int N, int K) {
  __shared__ __align__(16) u16 Ash[2][128 * 32];
  __shared__ __align__(16) u16 Asl[2][128 * 32];
  __shared__ __align__(16) u16 Bs[2][256 * 32];
  const int tid = threadIdx.x;
  const int nwg = gridDim.x * gridDim.y;
  int bid = blockIdx.y * gridDim.x + blockIdx.x;
  bid = (bid & 7) * (nwg >> 3) + (bid >> 3);
  const int m0 = (bid / gridDim.x) * 128, n0 = (bid % gridDim.x) * 256;
  const int w = tid >> 6, l = tid & 63;
  const int wr = (w >> 1) * 64, wc = (w & 1) * 128;
  const int lrow = l & 15, lk = (l >> 4) * 8, rbase = (l >> 4) * 4;
  const int srow = tid >> 2, scol = (tid & 3) * 8;

  f32x4 acc[4][8];
#pragma unroll
  for (int i = 0; i < 4; ++i)
#pragma unroll
    for (int j = 0; j < 8; ++j) acc[i][j] = {0.f, 0.f, 0.f, 0.f};

  const u16* ahBase = Ah + (size_t)m0 * K;
  const u16* alBase = Al + (size_t)m0 * K;
  const u16* bBase  = Bt + (size_t)n0 * K;

  auto STAGE = [&](int buf, int k0) {
    GLDS16(ahBase + (size_t)srow * K + k0 + scol,         &Ash[buf][tid * 8]);
    GLDS16(ahBase + (size_t)(srow + 64) * K + k0 + scol,  &Ash[buf][2048 + tid * 8]);
    GLDS16(alBase + (size_t)srow * K + k0 + scol,         &Asl[buf][tid * 8]);
    GLDS16(alBase + (size_t)(srow + 64) * K + k0 + scol,  &Asl[buf][2048 + tid * 8]);
    GLDS16(bBase + (size_t)srow * K + k0 + scol,          &Bs[buf][tid * 8]);
    GLDS16(bBase + (size_t)(srow + 64) * K + k0 + scol,   &Bs[buf][2048 + tid * 8]);
    GLDS16(bBase + (size_t)(srow + 128) * K + k0 + scol,  &Bs[buf][4096 + tid * 8]);
    GLDS16(bBase + (size_t)(srow + 192) * K + k0 + scol,  &Bs[buf][6144 + tid * 8]);
  };

  STAGE(0, 0);
  __syncthreads();
  int cur = 0;
  for (int k0 = 0; k0 < K; k0 += 32) {
    if (k0 + 32 < K) STAGE(cur ^ 1, k0 + 32);
    bf16x8 afh[4], afl[4], bfr[8];
#pragma unroll
    for (int i = 0; i < 4; ++i) afh[i] = *(const bf16x8*)&Ash[cur][SWG(wr + i * 16 + lrow, lk)];
#pragma unroll
    for (int i = 0; i < 4; ++i) afl[i] = *(const bf16x8*)&Asl[cur][SWG(wr + i * 16 + lrow, lk)];
#pragma unroll
    for (int j = 0; j < 8; ++j) bfr[j] = *(const bf16x8*)&Bs[cur][SWG(wc + j * 16 + lrow, lk)];
#pragma unroll
    for (int i = 0; i < 4; ++i)
#pragma unroll
      for (int j = 0; j < 8; ++j) {
        acc[i][j] = MFMA16(afl[i], bfr[j], acc[i][j]);
        acc[i][j] = MFMA16(afh[i], bfr[j], acc[i][j]);
      }
    __syncthreads();
    cur ^= 1;
  }
#pragma unroll
  for (int i = 0; i < 4; ++i)
#pragma unroll
    for (int j = 0; j < 8; ++j)
#pragma unroll
      for (int r = 0; r < 4; ++r) {
        int row = m0 + wr + i * 16 + rbase + r;
        int col = n0 + wc + j * 16 + lrow;
        Cf[(size_t)row * N + col] = acc[i][j][r];
      }
}

// ---------------- ba proj + beta/g ----------------
__global__ __launch_bounds__(256) void k_ba(const float* __restrict__ x, const float* __restrict__ Wba,
                                            const float* __restrict__ dt_bias, const float* __restrict__ A_log,
                                            float* __restrict__ betaO, float* __restrict__ gO) {
  __shared__ float xs[4][1024];
  const int wid = threadIdx.x >> 6, lane = threadIdx.x & 63;
  const int m = blockIdx.x * 4 + wid;
#pragma unroll
  for (int i = 0; i < 16; ++i) xs[wid][lane + 64 * i] = x[(size_t)m * 1024 + lane + 64 * i];
  __syncthreads();
  const int n = lane & 31, half = lane >> 5;
  float acc = 0.f;
  const float* wp = Wba + n;
  const int kk0 = half * 512;
#pragma unroll 8
  for (int kk = kk0; kk < kk0 + 512; ++kk) acc += xs[wid][kk] * wp[kk * 32];
  acc += __shfl_xor(acc, 32);
  if (lane < 32) {
    if (n < 16) {
      betaO[(size_t)m * 16 + n] = 1.f / (1.f + expf(-acc));
    } else {
      int h = n - 16;
      float xx = acc + dt_bias[h];
      float sp = (xx > 20.f) ? xx : log1pf(expf(xx));
      gO[(size_t)m * 16 + h] = -expf(fmaxf(A_log[h], -2.3f)) * sp;
    }
  }
}

// ---------------- causal depthwise conv(4) + SiLU + l2norm; outputs per-(b,h) SWIZZLED bf16 hi/lo tiles ----------------
__global__ __launch_bounds__(256) void k_conv(const u16* __restrict__ qkv3, const float* __restrict__ convw,
                                              u16* __restrict__ qhG, u16* __restrict__ qlG,
                                              u16* __restrict__ khG, u16* __restrict__ klG,
                                              u16* __restrict__ vhG, u16* __restrict__ vlG) {
  __shared__ float cs[3072];
  __shared__ float innorm[32];
  const int bt = blockIdx.x;
  const int bb = bt >> 12, tt = bt & 4095;
  const int tid = threadIdx.x;
  const size_t rb = (size_t)bb * 4096;
#pragma unroll
  for (int s = 0; s < 3; ++s) {
    const int c4 = tid * 4 + s * 1024;   // contiguous 1KB segments per step
    float cwa[4][4];
#pragma unroll
    for (int e = 0; e < 4; ++e) {
      float4 t = *(const float4*)&convw[(c4 + e) * 4];
      cwa[e][0] = t.x; cwa[e][1] = t.y; cwa[e][2] = t.z; cwa[e][3] = t.w;
    }
    float acc[4] = {0.f, 0.f, 0.f, 0.f};
#pragma unroll
    for (int j = 0; j < 4; ++j) {
      const int tau = tt - 3 + j;
      if (tau >= 0) {
        ushort4 kv = *(const ushort4*)&qkv3[(rb + tau) * 3072 + c4];
        acc[0] += bf2f(kv.x) * cwa[0][j];
        acc[1] += bf2f(kv.y) * cwa[1][j];
        acc[2] += bf2f(kv.z) * cwa[2][j];
        acc[3] += bf2f(kv.w) * cwa[3][j];
      }
    }
#pragma unroll
    for (int e = 0; e < 4; ++e) cs[c4 + e] = acc[e] / (1.f + expf(-acc[e]));
  }
  __syncthreads();
  {
    const int grp = tid >> 3, off = (tid & 7) * 8;
    const float* p = cs + grp * 64 + off;
    float s = 0.f;
#pragma unroll
    for (int i = 0; i < 8; ++i) s += p[i] * p[i];
    s += __shfl_xor(s, 1); s += __shfl_xor(s, 2); s += __shfl_xor(s, 4);
    if ((tid & 7) == 0) innorm[grp] = rsqrtf(s + 1e-6f);
  }
  __syncthreads();
  // per-(b,h) swizzled tile outputs: elem (tt, d) of tile (bh, tt>>6) -> offset SW(tt&63, d)
  const int h = tid >> 4, d4 = (tid & 15) * 4;
  const size_t ob = ((size_t)(bb * 16 + h) * 64 + (tt >> 6)) * 4096 + SW(tt & 63, d4);
  {
    const int ci = h * 64 + d4;
    const float sc = innorm[h] * 0.125f;
    float4 o = {cs[ci] * sc, cs[ci + 1] * sc, cs[ci + 2] * sc, cs[ci + 3] * sc};
    ushort4 hh, ll;
    split4(o, hh, ll);
    *(ushort4*)&qhG[ob] = hh;
    *(ushort4*)&qlG[ob] = ll;
  }
  {
    const int ci = 1024 + h * 64 + d4;
    const float sc = innorm[16 + h];
    float4 o = {cs[ci] * sc, cs[ci + 1] * sc, cs[ci + 2] * sc, cs[ci + 3] * sc};
    ushort4 hh, ll;
    split4(o, hh, ll);
    *(ushort4*)&khG[ob] = hh;
    *(ushort4*)&klG[ob] = ll;
  }
  {
    const int ci = 2048 + h * 64 + d4;
    float4 o = {cs[ci], cs[ci + 1], cs[ci + 2], cs[ci + 3]};
    ushort4 hh, ll;
    split4(o, hh, ll);
    *(ushort4*)&vhG[ob] = hh;
    *(ushort4*)&vlG[ob] = ll;
  }
}

// ---------------- per-chunk precompute: gc cumsum + T=(I+A)^{-1} ----------------
__global__ __launch_bounds__(64) void k_prep(const u16* __restrict__ khG, const u16* __restrict__ klG,
                                             const float* __restrict__ gG, const float* __restrict__ betaG,
                                             float* __restrict__ gcG, u16* __restrict__ Tgh, u16* __restrict__ Tgl) {
  __shared__ __align__(16) char pmem[16384];
  u16* Kbh = (u16*)pmem;                 // 8KB
  u16* Kbl = (u16*)(pmem + 8192);        // 8KB
  float* Af = (float*)pmem;              // 16KB, aliases Kb after MFMA phase
  __shared__ float gcs[64], bs[64];
  const int bhc = blockIdx.x;              // b*1024 + h*64 + c
  const int c = bhc & 63, h = (bhc >> 6) & 15, bb = bhc >> 10;
  const int lane = threadIdx.x;
  const int t0 = c * 64;
  const size_t rowbase = (size_t)bb * 4096;
  const size_t ktile = (size_t)bhc * 4096;   // swizzled tile in global
#pragma unroll
  for (int i = 0; i < 8; ++i) {
    const int idx = lane + 64 * i;
    GLDS16(khG + ktile + idx * 8, &Kbh[idx * 8]);
    GLDS16(klG + ktile + idx * 8, &Kbl[idx * 8]);
  }
  {
    float gv = gG[(rowbase + t0 + lane) * 16 + h];
    float sc = gv;
#pragma unroll
    for (int off = 1; off < 64; off <<= 1) {
      float o = __shfl_up(sc, off);
      if (lane >= off) sc += o;
    }
    gcs[lane] = sc;
    bs[lane] = betaG[(rowbase + t0 + lane) * 16 + h];
    gcG[(size_t)bhc * 64 + lane] = sc;
  }
  __syncthreads();
  const int lrow = lane & 15, lk8 = (lane >> 4) * 8, rbase = (lane >> 4) * 4;
  f32x4 acc[4][4];
#pragma unroll
  for (int i = 0; i < 4; ++i)
#pragma unroll
    for (int j = 0; j < 4; ++j) acc[i][j] = {0.f, 0.f, 0.f, 0.f};
#pragma unroll
  for (int ks = 0; ks < 2; ++ks) {
    bf16x8 afh[4], afl[4], bfh[4], bfl[4];
#pragma unroll
    for (int i = 0; i < 4; ++i) {
      afh[i] = *(const bf16x8*)&Kbh[SW(i * 16 + lrow, ks * 32 + lk8)];
      afl[i] = *(const bf16x8*)&Kbl[SW(i * 16 + lrow, ks * 32 + lk8)];
    }
#pragma unroll
    for (int j = 0; j < 4; ++j) {
      bfh[j] = *(const bf16x8*)&Kbh[SW(j * 16 + lrow, ks * 32 + lk8)];
      bfl[j] = *(const bf16x8*)&Kbl[SW(j * 16 + lrow, ks * 32 + lk8)];
    }
#pragma unroll
    for (int i = 0; i < 4; ++i)
#pragma unroll
      for (int j = 0; j < 4; ++j) acc[i][j] = mm3(afh[i], afl[i], bfh[j], bfl[j], acc[i][j]);
  }
  __syncthreads();   // Kb reads complete before Af overwrites same LDS
#pragma unroll
  for (int i = 0; i < 4; ++i)
#pragma unroll
    for (int j = 0; j < 4; ++j)
#pragma unroll
      for (int r = 0; r < 4; ++r) {
        int t = i * 16 + rbase + r, s = j * 16 + lrow;
        Af[t * 64 + s] = (s < t) ? bs[t] * expf(gcs[t] - gcs[s]) * acc[i][j][r] : 0.f;
      }
  __syncthreads();
  // forward substitution: lane = column; X fully in registers (static unroll)
  float x[64];
#pragma unroll
  for (int t = 0; t < 64; ++t) {
    float sum = 0.f;
#pragma unroll
    for (int s4 = 0; s4 + 4 <= t; s4 += 4) {
      float4 a4 = *(const float4*)&Af[t * 64 + s4];
      sum += a4.x * x[s4] + a4.y * x[s4 + 1] + a4.z * x[s4 + 2] + a4.w * x[s4 + 3];
    }
#pragma unroll
    for (int s = (t & ~3); s < t; ++s) sum += Af[t * 64 + s] * x[s];
    x[t] = ((t == lane) ? 1.f : 0.f) - sum;
  }
#pragma unroll
  for (int t = 0; t < 64; ++t) {
    u16 hi, lo;
    splitbf(x[t], hi, lo);
    Tgh[(size_t)bhc * 4096 + SW(t, lane)] = hi;   // global T stored swizzled
    Tgl[(size_t)bhc * 4096 + SW(t, lane)] = lo;
  }
}

// ---------------- k_mn: per-chunk affine map (swizzled tiles; M,N global swizzled) ----------------
__global__ __launch_bounds__(256) void k_mn(const u16* __restrict__ khG, const u16* __restrict__ klG,
                                            const u16* __restrict__ vhG, const u16* __restrict__ vlG,
                                            const u16* __restrict__ Tgh, const u16* __restrict__ Tgl,
                                            const float* __restrict__ gcG, const float* __restrict__ betaG,
                                            u16* __restrict__ Mh, u16* __restrict__ Ml,
                                            u16* __restrict__ Nh, u16* __restrict__ Nl) {
  extern __shared__ __align__(16) char smem[];
  u16* base = (u16*)smem;
  u16* Tbh  = base + 0 * 4096;
  u16* Tbl  = base + 1 * 4096;
  u16* X1h  = base + 2 * 4096;
  u16* X1l  = base + 3 * 4096;
  u16* KdTh = base + 4 * 4096;
  u16* KdTl = base + 5 * 4096;
  u16* X2h  = base + 6 * 4096;
  u16* X2l  = base + 7 * 4096;
  float* gcs = (float*)(base + 8 * 4096);
  float* bs  = gcs + 64;

  const int bhc = blockIdx.x;
  const int c = bhc & 63, h = (bhc >> 6) & 15, bb = bhc >> 10;
  const int tid = threadIdx.x, w = tid >> 6, l = tid & 63;
  const int lrow = l & 15, lk8 = (l >> 4) * 8, rbase = (l >> 4) * 4;
  const int t0 = c * 64;
  const size_t rowbase = (size_t)bb * 4096;
  const size_t ktile = (size_t)bhc * 4096;

  if (tid < 64) {
    gcs[tid] = gcG[(size_t)bhc * 64 + tid];
    bs[tid] = betaG[(rowbase + t0 + tid) * 16 + h];
  }
#pragma unroll
  for (int i = 0; i < 2; ++i) {   // T global is swizzled: linear copy keeps tile swizzled
    const int idx = tid + 256 * i;
    const int off = idx * 8;
    *(float4*)&Tbh[off] = *(const float4*)&Tgh[(size_t)bhc * 4096 + off];
    *(float4*)&Tbl[off] = *(const float4*)&Tgl[(size_t)bhc * 4096 + off];
  }
  __syncthreads();
  const float gc63 = gcs[63];
#pragma unroll
  for (int i = 0; i < 16; ++i) {
    const int flat = tid + 256 * i;
    const int s = flat >> 6, d = flat & 63;
    const int sws = SW(s, d);
    const float kf = bf2f(khG[ktile + sws]) + bf2f(klG[ktile + sws]);
    const float gv = gcs[s], bv = bs[s];
    u16 hh, ll;
    splitbf(bv * expf(gv) * kf, hh, ll);
    X1h[SW(d, s)] = hh; X1l[SW(d, s)] = ll;
    splitbf(expf(gc63 - gv) * kf, hh, ll);
    KdTh[SW(d, s)] = hh; KdTl[SW(d, s)] = ll;
    const float vv = bf2f(vhG[ktile + sws]) + bf2f(vlG[ktile + sws]);
    splitbf(bv * vv, hh, ll);
    X2h[SW(d, s)] = hh; X2l[SW(d, s)] = ll;
  }
  __syncthreads();

  f32x4 aW[4], aU[4];
#pragma unroll
  for (int j = 0; j < 4; ++j) { aW[j] = {0.f,0.f,0.f,0.f}; aU[j] = {0.f,0.f,0.f,0.f}; }
#pragma unroll
  for (int ks = 0; ks < 2; ++ks) {
    const int ao = SW(w * 16 + lrow, ks * 32 + lk8);
    bf16x8 aTh = *(const bf16x8*)&Tbh[ao];
    bf16x8 aTl = *(const bf16x8*)&Tbl[ao];
#pragma unroll
    for (int j = 0; j < 4; ++j) {
      const int bo = SW(j * 16 + lrow, ks * 32 + lk8);
      aW[j] = mm3(aTh, aTl, *(const bf16x8*)&X1h[bo], *(const bf16x8*)&X1l[bo], aW[j]);
      aU[j] = mm3(aTh, aTl, *(const bf16x8*)&X2h[bo], *(const bf16x8*)&X2l[bo], aU[j]);
    }
  }
  __syncthreads();
#pragma unroll
  for (int j = 0; j < 4; ++j)
#pragma unroll
    for (int r = 0; r < 4; ++r) {
      const int t = w * 16 + rbase + r, dcol = j * 16 + lrow;
      u16 hh, ll;
      splitbf(aW[j][r], hh, ll);
      X1h[SW(dcol, t)] = hh; X1l[SW(dcol, t)] = ll;
      splitbf(aU[j][r], hh, ll);
      X2h[SW(dcol, t)] = hh; X2l[SW(dcol, t)] = ll;
    }
  __syncthreads();

  f32x4 aM[4], aN[4];
#pragma unroll
  for (int j = 0; j < 4; ++j) { aM[j] = {0.f,0.f,0.f,0.f}; aN[j] = {0.f,0.f,0.f,0.f}; }
#pragma unroll
  for (int ks = 0; ks < 2; ++ks) {
    const int ao = SW(w * 16 + lrow, ks * 32 + lk8);
    bf16x8 aKh = *(const bf16x8*)&KdTh[ao];
    bf16x8 aKl = *(const bf16x8*)&KdTl[ao];
#pragma unroll
    for (int j = 0; j < 4; ++j) {
      const int bo = SW(j * 16 + lrow, ks * 32 + lk8);
      aM[j] = mm3(aKh, aKl, *(const bf16x8*)&X1h[bo], *(const bf16x8*)&X1l[bo], aM[j]);
      aN[j] = mm3(aKh, aKl, *(const bf16x8*)&X2h[bo], *(const bf16x8*)&X2l[bo], aN[j]);
    }
  }
  __syncthreads();
  const float decC = expf(gc63);
#pragma unroll
  for (int j = 0; j < 4; ++j)
#pragma unroll
    for (int r = 0; r < 4; ++r) {
      const int d = w * 16 + rbase + r, d2 = j * 16 + lrow;
      u16 hh, ll;
      splitbf(((d == d2) ? decC : 0.f) - aM[j][r], hh, ll);
      X1h[SW(d, d2)] = hh; X1l[SW(d, d2)] = ll;
      splitbf(aN[j][r], hh, ll);
      X2h[SW(d, d2)] = hh; X2l[SW(d, d2)] = ll;
    }
  __syncthreads();
#pragma unroll
  for (int i = 0; i < 2; ++i) {   // linear copy out -> globals hold swizzled tiles
    const int idx = tid + 256 * i;
    const int off = idx * 8;
    *(float4*)&Mh[(size_t)bhc * 4096 + off] = *(const float4*)&X1h[off];
    *(float4*)&Ml[(size_t)bhc * 4096 + off] = *(const float4*)&X1l[off];
    *(float4*)&Nh[(size_t)bhc * 4096 + off] = *(const float4*)&X2h[off];
    *(float4*)&Nl[(size_t)bhc * 4096 + off] = *(const float4*)&X2l[off];
  }
}

// ---------------- k_seg: compose 8 chunks (swizzled tiles throughout) ----------------
__global__ __launch_bounds__(256) void k_seg(const u16* __restrict__ Mh, const u16* __restrict__ Ml,
                                             const u16* __restrict__ Nh, const u16* __restrict__ Nl,
                                             u16* __restrict__ Msegh, u16* __restrict__ Msegl,
                                             u16* __restrict__ Nsegh, u16* __restrict__ Nsegl) {
  extern __shared__ __align__(16) char smem[];
  u16* base = (u16*)smem;
  u16* MaTh = base + 0 * 4096;
  u16* MaTl = base + 1 * 4096;
  u16* NaTh = base + 2 * 4096;
  u16* NaTl = base + 3 * 4096;
  u16* sMh  = base + 4 * 4096;
  u16* sMl  = base + 5 * 4096;
  u16* sNh  = base + 6 * 4096;
  u16* sNl  = base + 7 * 4096;

  const int blk = blockIdx.x;                       // bh*8 + seg
  const size_t cbase = (size_t)(blk >> 3) * 64 + (blk & 7) * 8;
  const int tid = threadIdx.x, w = tid >> 6, l = tid & 63;
  const int lrow = l & 15, lk8 = (l >> 4) * 8, rbase = (l >> 4) * 4;

#pragma unroll
  for (int i = 0; i < 2; ++i) {
    const int off = (tid + 256 * i) * 8;
    *(float4*)&sMh[off] = *(const float4*)&Mh[cbase * 4096 + off];
    *(float4*)&sMl[off] = *(const float4*)&Ml[cbase * 4096 + off];
    *(float4*)&sNh[off] = *(const float4*)&Nh[cbase * 4096 + off];
    *(float4*)&sNl[off] = *(const float4*)&Nl[cbase * 4096 + off];
  }
  __syncthreads();
#pragma unroll
  for (int i = 0; i < 16; ++i) {       // transpose into accumulators
    const int flat = tid + 256 * i;
    const int a = flat >> 6, b = flat & 63;
    MaTh[SW(a, b)] = sMh[SW(b, a)];
    MaTl[SW(a, b)] = sMl[SW(b, a)];
    NaTh[SW(a, b)] = sNh[SW(b, a)];
    NaTl[SW(a, b)] = sNl[SW(b, a)];
  }
  __syncthreads();

  for (int j = 1; j < 8; ++j) {
#pragma unroll
    for (int i = 0; i < 2; ++i) {
      const int off = (tid + 256 * i) * 8;
      *(float4*)&sMh[off] = *(const float4*)&Mh[(cbase + j) * 4096 + off];
      *(float4*)&sMl[off] = *(const float4*)&Ml[(cbase + j) * 4096 + off];
      *(float4*)&sNh[off] = *(const float4*)&Nh[(cbase + j) * 4096 + off];
      *(float4*)&sNl[off] = *(const float4*)&Nl[(cbase + j) * 4096 + off];
    }
    __syncthreads();
    f32x4 aM2[4], aN2[4];
#pragma unroll
    for (int jj = 0; jj < 4; ++jj) { aM2[jj] = {0.f,0.f,0.f,0.f}; aN2[jj] = {0.f,0.f,0.f,0.f}; }
#pragma unroll
    for (int ks = 0; ks < 2; ++ks) {
      const int ao = SW(w * 16 + lrow, ks * 32 + lk8);
      bf16x8 aCh = *(const bf16x8*)&sMh[ao];
      bf16x8 aCl = *(const bf16x8*)&sMl[ao];
#pragma unroll
      for (int jj = 0; jj < 4; ++jj) {
        const int bo = SW(jj * 16 + lrow, ks * 32 + lk8);
        aM2[jj] = mm3(aCh, aCl, *(const bf16x8*)&MaTh[bo], *(const bf16x8*)&MaTl[bo], aM2[jj]);
        aN2[jj] = mm3(aCh, aCl, *(const bf16x8*)&NaTh[bo], *(const bf16x8*)&NaTl[bo], aN2[jj]);
      }
    }
    __syncthreads();
#pragma unroll
    for (int jj = 0; jj < 4; ++jj)
#pragma unroll
      for (int r = 0; r < 4; ++r) {
        const int t = w * 16 + rbase + r, col = jj * 16 + lrow;
        u16 hh, ll;
        splitbf(aM2[jj][r], hh, ll);
        MaTh[SW(col, t)] = hh; MaTl[SW(col, t)] = ll;
        const float nv = aN2[jj][r] + bf2f(sNh[SW(t, col)]) + bf2f(sNl[SW(t, col)]);
        splitbf(nv, hh, ll);
        NaTh[SW(col, t)] = hh; NaTl[SW(col, t)] = ll;
      }
    __syncthreads();
  }
#pragma unroll
  for (int i = 0; i < 16; ++i) {       // un-transpose; globals swizzled
    const int flat = tid + 256 * i;
    const int t = flat >> 6, s = flat & 63;
    Msegh[(size_t)blk * 4096 + SW(t, s)] = MaTh[SW(s, t)];
    Msegl[(size_t)blk * 4096 + SW(t, s)] = MaTl[SW(s, t)];
    Nsegh[(size_t)blk * 4096 + SW(t, s)] = NaTh[SW(s, t)];
    Nsegl[(size_t)blk * 4096 + SW(t, s)] = NaTl[SW(s, t)];
  }
}

// ---------------- k_bound: sequential 8-step prefix (S^T tiles, swizzled; Sseg global swizzled) ----------------
__global__ __launch_bounds__(256) void k_bound(const u16* __restrict__ Msegh, const u16* __restrict__ Msegl,
                                               const u16* __restrict__ Nsegh, const u16* __restrict__ Nsegl,
                                               u16* __restrict__ Ssegh, u16* __restrict__ Ssegl) {
  __shared__ __align__(16) u16 STh[4096], STl[4096];
  __shared__ __align__(16) u16 sMh[4096], sMl[4096], sNh[4096], sNl[4096];
  const int bh = blockIdx.x;
  const int tid = threadIdx.x, w = tid >> 6, l = tid & 63;
  const int lrow = l & 15, lk8 = (l >> 4) * 8, rbase = (l >> 4) * 4;
  for (int i = tid; i < 4096; i += 256) { STh[i] = (u16)0; STl[i] = (u16)0; }
  __syncthreads();
  for (int j = 0; j < 8; ++j) {
    const size_t sb = (size_t)(bh * 8 + j) * 4096;
#pragma unroll
    for (int i = 0; i < 2; ++i) {
      const int off = (tid + 256 * i) * 8;
      *(float4*)&Ssegh[sb + off] = *(const float4*)&STh[off];   // linear copies (all swizzled)
      *(float4*)&Ssegl[sb + off] = *(const float4*)&STl[off];
      *(float4*)&sMh[off] = *(const float4*)&Msegh[sb + off];
      *(float4*)&sMl[off] = *(const float4*)&Msegl[sb + off];
      *(float4*)&sNh[off] = *(const float4*)&Nsegh[sb + off];
      *(float4*)&sNl[off] = *(const float4*)&Nsegl[sb + off];
    }
    __syncthreads();
    f32x4 acc[4];
#pragma unroll
    for (int jj = 0; jj < 4; ++jj) acc[jj] = {0.f, 0.f, 0.f, 0.f};
#pragma unroll
    for (int ks = 0; ks < 2; ++ks) {
      const int ao = SW(w * 16 + lrow, ks * 32 + lk8);
      bf16x8 aSh = *(const bf16x8*)&STh[ao];
      bf16x8 aSl = *(const bf16x8*)&STl[ao];
#pragma unroll
      for (int jj = 0; jj < 4; ++jj) {
        const int bo = SW(jj * 16 + lrow, ks * 32 + lk8);
        acc[jj] = mm3(aSh, aSl, *(const bf16x8*)&sMh[bo], *(const bf16x8*)&sMl[bo], acc[jj]);
      }
    }
    __syncthreads();
#pragma unroll
    for (int jj = 0; jj < 4; ++jj)
#pragma unroll
      for (int r = 0; r < 4; ++r) {
        const int v = w * 16 + rbase + r, t = jj * 16 + lrow;
        const float sv = acc[jj][r] + bf2f(sNh[SW(t, v)]) + bf2f(sNl[SW(t, v)]);
        u16 hh, ll;
        splitbf(sv, hh, ll);
        STh[SW(v, t)] = hh; STl[SW(v, t)] = ll;
      }
    __syncthreads();
  }
}

// ---------------- k_scan2: 8-chunk scan per (bh,seg); 8 waves, GLDS pipeline, hoisted exps ----------------
__global__ __launch_bounds__(512, 2) void k_scan2(const u16* __restrict__ qhG, const u16* __restrict__ qlG,
                                               const u16* __restrict__ khG, const u16* __restrict__ klG,
                                               const u16* __restrict__ vhG, const u16* __restrict__ vlG,
                                               const u16* __restrict__ zb,
                                               const u16* __restrict__ Tgh, const u16* __restrict__ Tgl,
                                               const float* __restrict__ gcG,
                                               const float* __restrict__ betaG, const float* __restrict__ norm_w,
                                               const u16* __restrict__ Ssegh, const u16* __restrict__ Ssegl,
                                               u16* __restrict__ Yhi, u16* __restrict__ Ylo) {
  extern __shared__ __align__(16) char smem[];
  u16* base = (u16*)smem;
  u16* Kbh  = base + 0 * 4096;
  u16* Kbl  = base + 1 * 4096;
  u16* Qbh  = base + 2 * 4096;
  u16* Qbl  = base + 3 * 4096;
  u16* Vbh  = base + 4 * 4096;
  u16* Vbl  = base + 5 * 4096;
  u16* Zb   = base + 6 * 4096;
  u16* Tbh  = base + 7 * 4096;
  u16* Tbl  = base + 8 * 4096;
  u16* SbTh = base + 9 * 4096;
  u16* SbTl = base + 10 * 4096;
  u16* Mqh  = base + 11 * 4096;
  u16* Mql  = base + 12 * 4096;
  u16* KdTh = base + 13 * 4096;
  u16* KdTl = base + 14 * 4096;
  u16* RTh  = base + 15 * 4096;
  u16* RTl  = base + 16 * 4096;
  u16* UTh  = base + 17 * 4096;
  u16* UTl  = base + 18 * 4096;
  u16* Ybh  = RTh;   // RT dead after phase B
  u16* Ybl  = RTl;
  float* gcs = (float*)(base + 19 * 4096);
  float* bs  = gcs + 64;
  float* nws = gcs + 128;
  float* esF = gcs + 192;   // exp(gc63 - gcs[s])
  float* etF = gcs + 256;   // exp(gcs[t])
  float* ssP = gcs + 320;   // [2][64] RMS partials

  const int blk = blockIdx.x;             // bh*8 + seg
  const int bh = blk >> 3, seg = blk & 7;
  const int bb = bh >> 4, h = bh & 15;
  const int tid = threadIdx.x, w = tid >> 6, l = tid & 63;
  const int wrow = w >> 1, jh = w & 1;            // row quadrant, j-half
  const int lrow = l & 15, lk8 = (l >> 4) * 8, rbase = (l >> 4) * 4;
  const size_t rowbase = (size_t)bb * 4096;
  const size_t bhTile = (size_t)bh * 64;
  const int o8 = tid * 8;
  const int zr = tid >> 3, zc8 = (tid & 7) << 3;  // 512-thread float4 tile mapping

  // ---- prologue: GLDS stage everything for chunk seg*8 ----
  {
    const int c = seg * 8, t0 = c * 64;
    const size_t gt = (bhTile + c) * 4096;
    GLDS16(qhG + gt + o8, &Qbh[o8]);
    GLDS16(qlG + gt + o8, &Qbl[o8]);
    GLDS16(khG + gt + o8, &Kbh[o8]);
    GLDS16(klG + gt + o8, &Kbl[o8]);
    GLDS16(vhG + gt + o8, &Vbh[o8]);
    GLDS16(vlG + gt + o8, &Vbl[o8]);
    GLDS16(Tgh + (size_t)(bh * 64 + c) * 4096 + o8, &Tbh[o8]);
    GLDS16(Tgl + (size_t)(bh * 64 + c) * 4096 + o8, &Tbl[o8]);
    GLDS16(Ssegh + (size_t)blk * 4096 + o8, &SbTh[o8]);
    GLDS16(Ssegl + (size_t)blk * 4096 + o8, &SbTl[o8]);
    *(float4*)&Zb[SW(zr, zc8)] = *(const float4*)&zb[(rowbase + t0 + zr) * 1024 + h * 64 + zc8];
    if (tid < 64) {
      nws[tid] = norm_w[tid];
      float g0 = gcG[((size_t)bh * 64 + c) * 64 + tid];
      float b0 = betaG[(rowbase + t0 + tid) * 16 + h];
      float g63 = __shfl(g0, 63);
      gcs[tid] = g0; bs[tid] = b0;
      esF[tid] = expf(g63 - g0);
      etF[tid] = expf(g0);
    }
  }
  __syncthreads();

  for (int cc = 0; cc < 8; ++cc) {
    const int c = seg * 8 + cc;
    const int t0 = c * 64;
    const bool pf = (cc < 7);
    const size_t gt1 = (bhTile + c + 1) * 4096;

    // ---- tiny register prefetch: z, gc, bs for chunk c+1 ----
    float4 pz;
    float pgc = 0.f, pbs = 0.f;
    if (pf) {
      const int t1 = t0 + 64;
      pz = *(const float4*)&zb[(rowbase + t1 + zr) * 1024 + h * 64 + zc8];
      if (tid < 64) {
        pgc = gcG[((size_t)bh * 64 + (c + 1)) * 64 + tid];
        pbs = betaG[(rowbase + t1 + tid) * 16 + h];
      }
    }

    // ---- phase A: KdT build (no expf: esF) ----
#pragma unroll
    for (int i = 0; i < 8; ++i) {
      const int flat = tid * 8 + i;
      const int d = flat >> 6, s = flat & 63;
      const float kv = bf2f(Kbh[SW(s, d)]) + bf2f(Kbl[SW(s, d)]);
      u16 hh, ll;
      splitbf(esF[s] * kv, hh, ll);
      KdTh[SW(d, s)] = hh;
      KdTl[SW(d, s)] = ll;
    }
    f32x4 aqk[2], ap[2], aqs[2];
#pragma unroll
    for (int j = 0; j < 2; ++j) { aqk[j] = {0.f,0.f,0.f,0.f}; ap[j] = {0.f,0.f,0.f,0.f}; aqs[j] = {0.f,0.f,0.f,0.f}; }
#pragma unroll
    for (int ks = 0; ks < 2; ++ks) {
      const int ao = SW(wrow * 16 + lrow, ks * 32 + lk8);
      bf16x8 aKh = *(const bf16x8*)&Kbh[ao];
      bf16x8 aKl = *(const bf16x8*)&Kbl[ao];
      bf16x8 aQh = *(const bf16x8*)&Qbh[ao];
      bf16x8 aQl = *(const bf16x8*)&Qbl[ao];
#pragma unroll
      for (int j = 0; j < 2; ++j) {
        const int jj = jh * 2 + j;
        const int bo = SW(jj * 16 + lrow, ks * 32 + lk8);
        bf16x8 bKh = *(const bf16x8*)&Kbh[bo];
        bf16x8 bKl = *(const bf16x8*)&Kbl[bo];
        bf16x8 bSh = *(const bf16x8*)&SbTh[bo];
        bf16x8 bSl = *(const bf16x8*)&SbTl[bo];
        aqk[j] = mm3(aQh, aQl, bKh, bKl, aqk[j]);
        ap[j]  = mm3(aKh, aKl, bSh, bSl, ap[j]);
        aqs[j] = mm3(aQh, aQl, bSh, bSl, aqs[j]);
      }
    }
#pragma unroll
    for (int j = 0; j < 2; ++j)
#pragma unroll
      for (int r = 0; r < 4; ++r) {
        const int t = wrow * 16 + rbase + r;
        const int s = (jh * 2 + j) * 16 + lrow;
        u16 mh, ml;
        splitbf((s <= t) ? expf(gcs[t] - gcs[s]) * aqk[j][r] : 0.f, mh, ml);
        Mqh[SW(t, s)] = mh;
        Mql[SW(t, s)] = ml;
        const float vv = bf2f(Vbh[SW(t, s)]) + bf2f(Vbl[SW(t, s)]);
        const float rhs = bs[t] * (vv - etF[t] * ap[j][r]);
        u16 rh, rl;
        splitbf(rhs, rh, rl);
        RTh[SW(s, t)] = rh;
        RTl[SW(s, t)] = rl;
      }
    __syncthreads();                        // barrier A

    // ---- Q/K/V dead: async GLDS chunk c+1 Q/K/V (drains at barrier B) ----
    if (pf) {
      GLDS16(qhG + gt1 + o8, &Qbh[o8]);
      GLDS16(qlG + gt1 + o8, &Qbl[o8]);
      GLDS16(khG + gt1 + o8, &Kbh[o8]);
      GLDS16(klG + gt1 + o8, &Kbl[o8]);
      GLDS16(vhG + gt1 + o8, &Vbh[o8]);
      GLDS16(vlG + gt1 + o8, &Vbl[o8]);
    }

    // ---- phase B: U = T @ RHS ----
    f32x4 au[2];
#pragma unroll
    for (int j = 0; j < 2; ++j) au[j] = {0.f, 0.f, 0.f, 0.f};
#pragma unroll
    for (int ks = 0; ks < 2; ++ks) {
      const int ao = SW(wrow * 16 + lrow, ks * 32 + lk8);
      bf16x8 aTh = *(const bf16x8*)&Tbh[ao];
      bf16x8 aTl = *(const bf16x8*)&Tbl[ao];
#pragma unroll
      for (int j = 0; j < 2; ++j) {
        const int bo = SW((jh * 2 + j) * 16 + lrow, ks * 32 + lk8);
        au[j] = mm3(aTh, aTl, *(const bf16x8*)&RTh[bo], *(const bf16x8*)&RTl[bo], au[j]);
      }
    }
#pragma unroll
    for (int j = 0; j < 2; ++j)
#pragma unroll
      for (int r = 0; r < 4; ++r) {
        u16 uh, ul;
        splitbf(au[j][r], uh, ul);
        const int o = SW((jh * 2 + j) * 16 + lrow, wrow * 16 + rbase + r);
        UTh[o] = uh;
        UTl[o] = ul;
      }
    __syncthreads();                        // barrier B (drains Q/K/V GLDS)

    // ---- T dead: async GLDS chunk c+1 T (drains at barrier C) ----
    if (pf) {
      GLDS16(Tgh + (size_t)(bh * 64 + (c + 1)) * 4096 + o8, &Tbh[o8]);
      GLDS16(Tgl + (size_t)(bh * 64 + (c + 1)) * 4096 + o8, &Tbl[o8]);
    }

    // ---- phase C ----
    f32x4 amu[2], as_[2];
#pragma unroll
    for (int j = 0; j < 2; ++j) { amu[j] = {0.f,0.f,0.f,0.f}; as_[j] = {0.f,0.f,0.f,0.f}; }
#pragma unroll
    for (int ks = 0; ks < 2; ++ks) {
      const int ao = SW(wrow * 16 + lrow, ks * 32 + lk8);
      bf16x8 aMh = *(const bf16x8*)&Mqh[ao];
      bf16x8 aMl = *(const bf16x8*)&Mql[ao];
      bf16x8 aKdh = *(const bf16x8*)&KdTh[ao];
      bf16x8 aKdl = *(const bf16x8*)&KdTl[ao];
#pragma unroll
      for (int j = 0; j < 2; ++j) {
        const int bo = SW((jh * 2 + j) * 16 + lrow, ks * 32 + lk8);
        bf16x8 bUh = *(const bf16x8*)&UTh[bo];
        bf16x8 bUl = *(const bf16x8*)&UTl[bo];
        amu[j] = mm3(aMh, aMl, bUh, bUl, amu[j]);
        as_[j] = mm3(aKdh, aKdl, bUh, bUl, as_[j]);
      }
    }
    // y values + cross-wave RMS partials
    float yv_[4][2];
#pragma unroll
    for (int r = 0; r < 4; ++r) {
      const int t = wrow * 16 + rbase + r;
      const float gt = etF[t];
      float ss = 0.f;
#pragma unroll
      for (int j = 0; j < 2; ++j) {
        yv_[r][j] = gt * aqs[j][r] + amu[j][r];
        ss += yv_[r][j] * yv_[r][j];
      }
      ss += __shfl_xor(ss, 1); ss += __shfl_xor(ss, 2); ss += __shfl_xor(ss, 4); ss += __shfl_xor(ss, 8);
      if (lrow == 0) ssP[jh * 64 + t] = ss;
    }
    __syncthreads();                        // publish RMS partials
#pragma unroll
    for (int r = 0; r < 4; ++r) {
      const int t = wrow * 16 + rbase + r;
      const float rstd = rsqrtf((ssP[t] + ssP[64 + t]) * (1.f / 64.f) + 1e-6f);
#pragma unroll
      for (int j = 0; j < 2; ++j) {
        const int col = (jh * 2 + j) * 16 + lrow;
        const float zz = bf2f(Zb[SW(t, col)]);
        const float yv = yv_[r][j] * rstd * nws[col] * (zz / (1.f + expf(-zz)));
        u16 yh, yl;
        splitbf(yv, yh, yl);
        Ybh[SW(t, col)] = yh;
        Ybl[SW(t, col)] = yl;
      }
    }
    {
      const float decC = etF[63];
#pragma unroll
      for (int j = 0; j < 2; ++j)
#pragma unroll
        for (int r = 0; r < 4; ++r) {
          const int d = wrow * 16 + rbase + r, col = (jh * 2 + j) * 16 + lrow;
          const int o = SW(col, d);
          const float s0 = bf2f(SbTh[o]) + bf2f(SbTl[o]);
          const float sv = decC * s0 + as_[j][r];
          u16 sh, sl;
          splitbf(sv, sh, sl);
          SbTh[o] = sh;
          SbTl[o] = sl;
        }
    }
    __syncthreads();                        // barrier C (drains T GLDS)

    // ---- store Y (pre-swizzled for GEMM2); write prefetched z; update gcs/bs/esF/etF ----
    {
      const size_t gsw = gidx_swz(rowbase + t0 + zr, h * 64 + zc8, 1024);
      *(float4*)&Yhi[gsw] = *(const float4*)&Ybh[SW(zr, zc8)];
      *(float4*)&Ylo[gsw] = *(const float4*)&Ybl[SW(zr, zc8)];
    }
    if (pf) {
      *(float4*)&Zb[SW(zr, zc8)] = pz;
      if (tid < 64) {
        float g63 = __shfl(pgc, 63);
        gcs[tid] = pgc; bs[tid] = pbs;
        esF[tid] = expf(g63 - pgc);
        etF[tid] = expf(pgc);
      }
    }
    __syncthreads();                        // barrier D
  }
}

extern "C" void kernel_launch(void* const* d_in, const int* in_sizes, int n_in,
                              void* d_out, int out_size, void* d_ws, size_t ws_size,
                              hipStream_t stream) {
  (void)in_sizes; (void)n_in; (void)out_size; (void)ws_size;
  const float* x       = (const float*)d_in[0];
  const float* W_in    = (const float*)d_in[1];
  const float* W_ba    = (const float*)d_in[2];
  const float* conv_w  = (const float*)d_in[3];
  const float* dt_bias = (const float*)d_in[4];
  const float* A_log   = (const float*)d_in[5];
  const float* norm_w  = (const float*)d_in[6];
  const float* W_o     = (const float*)d_in[7];
  float* out = (float*)d_out;
  char* ws = (char*)d_ws;
  const size_t MB = 1048576;

  _Float16* xh = (_Float16*)(ws + 0);     // 16 MB f16 x (pre-swizzled) -> Mh -> Yhi
  u16* MhB   = (u16*)(ws + 0);
  u16* YhiB  = (u16*)(ws + 0);
  u16* MlB   = (u16*)(ws + 16 * MB);      // 16 MB Ml -> Ylo
  u16* YloB  = (u16*)(ws + 16 * MB);
  _Float16* WinT = (_Float16*)(ws + 32 * MB);  // 8 MB f16 (pre-swizzled, dead post-GEMM1)
  float* gB  = (float*)(ws + 32 * MB);             // 0.5 MB (post-GEMM1)
  float* bB  = (float*)(ws + 32 * MB + 524288);    // 0.5 MB
  float* gcB = (float*)(ws + 33 * MB);             // 0.5 MB
  u16* Ssegh = (u16*)(ws + 34 * MB);      // 2 MB
  u16* Ssegl = (u16*)(ws + 36 * MB);      // 2 MB
  u16* Msegh = (u16*)(ws + 38 * MB);      // 2 MB
  u16* Msegl = (u16*)(ws + 40 * MB);      // 2 MB
  u16* Nsegh = (u16*)(ws + 42 * MB);      // 2 MB
  u16* Nsegl = (u16*)(ws + 44 * MB);      // 2 MB
  u16* WoT   = (u16*)(ws + 48 * MB);      // 2 MB (pre-swizzled)
  u16* qkv3  = (u16*)(ws + 50 * MB);      // 48 MB (dead post-conv)
  u16* NhB   = (u16*)(ws + 50 * MB);      // 16 MB
  u16* NlB   = (u16*)(ws + 66 * MB);      // 16 MB
  u16* zbB   = (u16*)(ws + 98 * MB);      // 16 MB (GEMM-major)
  u16* qhG   = (u16*)(ws + 114 * MB);     // 16 MB (per-(b,h) swizzled tiles)
  u16* qlG   = (u16*)(ws + 130 * MB);     // 16 MB
  u16* khG   = (u16*)(ws + 146 * MB);     // 16 MB
  u16* klG   = (u16*)(ws + 162 * MB);     // 16 MB
  u16* vhG   = (u16*)(ws + 178 * MB);     // 16 MB
  u16* vlG   = (u16*)(ws + 194 * MB);     // 16 MB
  u16* TghB  = (u16*)(ws + 210 * MB);     // 16 MB
  u16* TglB  = (u16*)(ws + 226 * MB);     // 16 MB  (end 242 MB)

  const int SCAN_LDS = 19 * 8192 + 448 * 4;   // 157440 B
  const int MN_LDS   = 8 * 8192 + 512;        // 66048 B
  const int SEG_LDS  = 8 * 8192;              // 65536 B

  k_cast_h<<<8192, 256, 0, stream>>>(x, xh, 8388608);
  k_transpose_h<<<dim3(64, 16), 256, 0, stream>>>(W_in, WinT, 1024, 4096);
  k_transpose<<<dim3(16, 16), 256, 0, stream>>>(W_o, WoT, 1024, 1024);
  k_gemm_h<<<dim3(16, 32), 512, 0, stream>>>(xh, WinT, qkv3, zbB, 8192, 4096, 1024);
  k_ba<<<2048, 256, 0, stream>>>(x, W_ba, dt_bias, A_log, bB, gB);
  k_conv<<<8192, 256, 0, stream>>>(qkv3, conv_w, qhG, qlG, khG, klG, vhG, vlG);
  k_prep<<<2048, 64, 0, stream>>>(khG, klG, gB, bB, gcB, TghB, TglB);
  hipFuncSetAttribute((const void*)k_mn, hipFuncAttributeMaxDynamicSharedMemorySize, MN_LDS);
  k_mn<<<2048, 256, MN_LDS, stream>>>(khG, klG, vhG, vlG, TghB, TglB, gcB, bB, MhB, MlB, NhB, NlB);
  hipFuncSetAttribute((const void*)k_seg, hipFuncAttributeMaxDynamicSharedMemorySize, SEG_LDS);
  k_seg<<<256, 256, SEG_LDS, stream>>>(MhB, MlB, NhB, NlB, Msegh, Msegl, Nsegh, Nsegl);
  k_bound<<<32, 256, 0, stream>>>(Msegh, Msegl, Nsegh, Nsegl, Ssegh, Ssegl);
  hipFuncSetAttribute((const void*)k_scan2, hipFuncAttributeMaxDynamicSharedMemorySize, SCAN_LDS);
  k_scan2<<<256, 512, SCAN_LDS, stream>>>(qhG, qlG, khG, klG, vhG, vlG, zbB, TghB, TglB, gcB, bB, norm_w,
                                          Ssegh, Ssegl, YhiB, YloB);
  k_gemm2<<<dim3(4, 64), 256, 0, stream>>>(YhiB, YloB, WoT, out, 8192, 1024, 1024);
}

// Round 17
// 512.478 us; speedup vs baseline: 1.0491x; 1.0240x over previous
//
#include <hip/hip_runtime.h>

typedef unsigned short u16;
typedef unsigned int u32;
typedef __attribute__((ext_vector_type(8))) __bf16 bf16x8;
typedef __attribute__((ext_vector_type(8))) _Float16 f16x8;
typedef __attribute__((ext_vector_type(4))) _Float16 f16x4;
typedef __attribute__((ext_vector_type(4))) float f32x4;

#define DEV __device__ __forceinline__

DEV u16 f2bf(float f) {
  u32 u = __float_as_uint(f);
  u += 0x7FFFu + ((u >> 16) & 1u);   // RNE
  return (u16)(u >> 16);
}
DEV float bf2f(u16 h) { return __uint_as_float(((u32)h) << 16); }
DEV void splitbf(float f, u16& hi, u16& lo) {
  u16 h = f2bf(f);
  hi = h;
  lo = f2bf(f - bf2f(h));
}
DEV void split4(float4 v, ushort4& hh, ushort4& ll) {
  splitbf(v.x, hh.x, ll.x);
  splitbf(v.y, hh.y, ll.y);
  splitbf(v.z, hh.z, ll.z);
  splitbf(v.w, hh.w, ll.w);
}
// T2 XOR swizzle for 64x64 u16 tiles (128B rows): kills the 16-way ds_read_b128 bank conflict.
DEV int SW(int r, int c) { return r * 64 + ((c) ^ ((r & 7) << 3)); }

// GEMM-tile swizzle: [*][32] u16 K-tiles, double-row (128B) units of 8x16B blocks,
// block index XORed with (row>>1)&7 -> fragment reads become 2-way (free).
DEV int SWG(int r, int c) {
  int db = ((r & 1) << 2) | ((c >> 3) & 3);
  int dbp = db ^ ((r >> 1) & 7);
  return ((r >> 1) << 6) | (dbp << 3) | (c & 7);
}
// producer-side: where logical (row, col) lives in the pre-swizzled global
DEV size_t gidx_swz(size_t row, int col, int rowlen) {
  int rr7 = (int)((row >> 1) & 7);
  int db = (int)(((row & 1) << 2) | ((col >> 3) & 3));
  int dbp = db ^ rr7;
  size_t rowp = (row & ~(size_t)1) | (size_t)(dbp >> 2);
  int colp = (col & ~31) | ((dbp & 3) << 3) | (col & 7);
  return rowp * (size_t)rowlen + colp;
}

#define MFMA16(a,b,c) __builtin_amdgcn_mfma_f32_16x16x32_bf16((a),(b),(c),0,0,0)
#define MFMAH(a,b,c)  __builtin_amdgcn_mfma_f32_16x16x32_f16((a),(b),(c),0,0,0)
#define GLDS16(g,l) __builtin_amdgcn_global_load_lds((__attribute__((address_space(1))) void*)(g), (__attribute__((address_space(3))) void*)(l), 16, 0, 0)

DEV f32x4 mm3(bf16x8 ah, bf16x8 al, bf16x8 bh, bf16x8 bl, f32x4 acc) {
  acc = MFMA16(ah, bl, acc);
  acc = MFMA16(al, bh, acc);
  acc = MFMA16(ah, bh, acc);
  return acc;
}

// ---------------- cast f32 -> f16, pre-swizzled for GEMM staging ----------------
__global__ __launch_bounds__(256) void k_cast_h(const float* __restrict__ in, _Float16* __restrict__ out, int n) {
  int idx = (blockIdx.x * 256 + threadIdx.x) * 4;
  if (idx + 3 < n) {
    float4 v = *(const float4*)(in + idx);
    f16x4 o = {(_Float16)v.x, (_Float16)v.y, (_Float16)v.z, (_Float16)v.w};
    const size_t row = (size_t)(idx >> 10);
    const int col = idx & 1023;
    *(f16x4*)(out + gidx_swz(row, col, 1024)) = o;
  }
}

// ---------------- transpose f32 [R][C] -> f16 [C][R], pre-swizzled ----------------
__global__ __launch_bounds__(256) void k_transpose_h(const float* __restrict__ in, _Float16* __restrict__ out, int R, int Cc) {
  __shared__ float tile[64][65];
  int c0 = blockIdx.x * 64, r0 = blockIdx.y * 64;
  int lr = threadIdx.x >> 6, lc = threadIdx.x & 63;
#pragma unroll
  for (int i = 0; i < 16; ++i) {
    int r = lr + i * 4;
    tile[r][lc] = in[(size_t)(r0 + r) * Cc + c0 + lc];
  }
  __syncthreads();
#pragma unroll
  for (int i = 0; i < 16; ++i) {
    int oc = lr + i * 4;
    out[gidx_swz((size_t)(c0 + oc), r0 + lc, R)] = (_Float16)tile[lc][oc];
  }
}

// ---------------- transpose f32 [R][C] -> bf16 [C][R], pre-swizzled ----------------
__global__ __launch_bounds__(256) void k_transpose(const float* __restrict__ in, u16* __restrict__ out, int R, int Cc) {
  __shared__ float tile[64][65];
  int c0 = blockIdx.x * 64, r0 = blockIdx.y * 64;
  int lr = threadIdx.x >> 6, lc = threadIdx.x & 63;
#pragma unroll
  for (int i = 0; i < 16; ++i) {
    int r = lr + i * 4;
    tile[r][lc] = in[(size_t)(r0 + r) * Cc + c0 + lc];
  }
  __syncthreads();
#pragma unroll
  for (int i = 0; i < 16; ++i) {
    int oc = lr + i * 4;
    out[gidx_swz((size_t)(c0 + oc), r0 + lc, R)] = f2bf(tile[lc][oc]);
  }
}

// ---------------- GEMM1 (f16 single): 256x256 tile, 8 waves, dbuf issue-before-compute ----------------
__global__ __launch_bounds__(512, 2) void k_gemm_h(const _Float16* __restrict__ A, const _Float16* __restrict__ Bt,
                                                   u16* __restrict__ Cq, u16* __restrict__ Cz, int M, int N, int K) {
  __shared__ __align__(16) u16 As[2][256 * 32];
  __shared__ __align__(16) u16 Bs[2][256 * 32];
  const int tid = threadIdx.x;
  const int nwg = gridDim.x * gridDim.y;
  int bid = blockIdx.y * gridDim.x + blockIdx.x;
  bid = (bid & 7) * (nwg >> 3) + (bid >> 3);      // bijective (nwg % 8 == 0)
  const int m0 = (bid / gridDim.x) * 256, n0 = (bid % gridDim.x) * 256;
  const int w = tid >> 6, l = tid & 63;
  const int wr = (w >> 1) * 64, wc = (w & 1) * 128;
  const int lrow = l & 15, lk = (l >> 4) * 8, rbase = (l >> 4) * 4;

  f32x4 acc[4][8];
#pragma unroll
  for (int i = 0; i < 4; ++i)
#pragma unroll
    for (int j = 0; j < 8; ++j) acc[i][j] = {0.f, 0.f, 0.f, 0.f};

  const _Float16* aBase = A + (size_t)m0 * K;
  const _Float16* bBase = Bt + (size_t)n0 * K;
  const int srow0 = tid >> 2, scol0 = (tid & 3) * 8;        // staging chunk 0
  const int srow1 = (tid + 512) >> 2;                       // staging chunk 1 (same scol)

  auto STAGE = [&](int buf, int k0) {
    GLDS16(aBase + (size_t)srow0 * K + k0 + scol0, &As[buf][tid * 8]);
    GLDS16(aBase + (size_t)srow1 * K + k0 + scol0, &As[buf][4096 + tid * 8]);
    GLDS16(bBase + (size_t)srow0 * K + k0 + scol0, &Bs[buf][tid * 8]);
    GLDS16(bBase + (size_t)srow1 * K + k0 + scol0, &Bs[buf][4096 + tid * 8]);
  };

  STAGE(0, 0);
  __syncthreads();
  int cur = 0;
  for (int k0 = 0; k0 < K; k0 += 32) {
    if (k0 + 32 < K) STAGE(cur ^ 1, k0 + 32);   // issue next-tile loads (fly under compute)
    f16x8 af[4], bfr[8];
#pragma unroll
    for (int i = 0; i < 4; ++i) af[i] = *(const f16x8*)&As[cur][SWG(wr + i * 16 + lrow, lk)];
#pragma unroll
    for (int j = 0; j < 8; ++j) bfr[j] = *(const f16x8*)&Bs[cur][SWG(wc + j * 16 + lrow, lk)];
#pragma unroll
    for (int i = 0; i < 4; ++i)
#pragma unroll
      for (int j = 0; j < 8; ++j) acc[i][j] = MFMAH(af[i], bfr[j], acc[i][j]);
    __syncthreads();                            // drains next-tile GLDS + this tile's ds_reads
    cur ^= 1;
  }
#pragma unroll
  for (int i = 0; i < 4; ++i)
#pragma unroll
    for (int j = 0; j < 8; ++j)
#pragma unroll
      for (int r = 0; r < 4; ++r) {
        int row = m0 + wr + i * 16 + rbase + r;
        int col = n0 + wc + j * 16 + lrow;
        if (col < 3072) Cq[(size_t)row * 3072 + col] = f2bf(acc[i][j][r]);
        else            Cz[(size_t)row * 1024 + col - 3072] = f2bf(acc[i][j][r]);
      }
}

// ---------------- GEMM2: (Ah+Al) @ Bt^T, f32 out, dbuf issue-before-compute ----------------
__global__ __launch_bounds__(256, 2) void k_gemm2(const u16* __restrict__ Ah, const u16* __restrict__ Al,
                                               const u16* __restrict__ Bt, float* __restrict__ Cf,
                                               int M, int N, int K) {
  __shared__ __align__(16) u16 Ash[2][128 * 32];
  __shared__ __align__(16) u16 Asl[2][128 * 32];
  __shared__ __align__(16) u16 Bs[2][128 * 32];
  const int tid = threadIdx.x;
  const int nwg = gridDim.x * gridDim.y;
  int bid = blockIdx.y * gridDim.x + blockIdx.x;
  bid = (bid & 7) * (nwg >> 3) + (bid >> 3);
  const int m0 = (bid / gridDim.x) * 128, n0 = (bid % gridDim.x) * 128;
  const int w = tid >> 6, l = tid & 63;
  const int wr = (w >> 1) * 64, wc = (w & 1) * 64;
  const int lrow = l & 15, lk = (l >> 4) * 8, rbase = (l >> 4) * 4;
  const int srow = tid >> 2, scol = (tid & 3) * 8;

  f32x4 acc[4][4];
#pragma unroll
  for (int i = 0; i < 4; ++i)
#pragma unroll
    for (int j = 0; j < 4; ++j) acc[i][j] = {0.f, 0.f, 0.f, 0.f};

  const u16* ahBase = Ah + (size_t)m0 * K;
  const u16* alBase = Al + (size_t)m0 * K;
  const u16* bBase  = Bt + (size_t)n0 * K;

  auto STAGE = [&](int buf, int k0) {
    GLDS16(ahBase + (size_t)srow * K + k0 + scol,        &Ash[buf][tid * 8]);
    GLDS16(ahBase + (size_t)(srow + 64) * K + k0 + scol, &Ash[buf][2048 + tid * 8]);
    GLDS16(alBase + (size_t)srow * K + k0 + scol,        &Asl[buf][tid * 8]);
    GLDS16(alBase + (size_t)(srow + 64) * K + k0 + scol, &Asl[buf][2048 + tid * 8]);
    GLDS16(bBase + (size_t)srow * K + k0 + scol,         &Bs[buf][tid * 8]);
    GLDS16(bBase + (size_t)(srow + 64) * K + k0 + scol,  &Bs[buf][2048 + tid * 8]);
  };

  STAGE(0, 0);
  __syncthreads();
  int cur = 0;
  for (int k0 = 0; k0 < K; k0 += 32) {
    if (k0 + 32 < K) STAGE(cur ^ 1, k0 + 32);
    bf16x8 afh[4], afl[4], bfr[4];
#pragma unroll
    for (int i = 0; i < 4; ++i) afh[i] = *(const bf16x8*)&Ash[cur][SWG(wr + i * 16 + lrow, lk)];
#pragma unroll
    for (int i = 0; i < 4; ++i) afl[i] = *(const bf16x8*)&Asl[cur][SWG(wr + i * 16 + lrow, lk)];
#pragma unroll
    for (int j = 0; j < 4; ++j) bfr[j] = *(const bf16x8*)&Bs[cur][SWG(wc + j * 16 + lrow, lk)];
#pragma unroll
    for (int i = 0; i < 4; ++i)
#pragma unroll
      for (int j = 0; j < 4; ++j) {
        acc[i][j] = MFMA16(afl[i], bfr[j], acc[i][j]);
        acc[i][j] = MFMA16(afh[i], bfr[j], acc[i][j]);
      }
    __syncthreads();
    cur ^= 1;
  }
#pragma unroll
  for (int i = 0; i < 4; ++i)
#pragma unroll
    for (int j = 0; j < 4; ++j)
#pragma unroll
      for (int r = 0; r < 4; ++r) {
        int row = m0 + wr + i * 16 + rbase + r;
        int col = n0 + wc + j * 16 + lrow;
        Cf[(size_t)row * N + col] = acc[i][j][r];
      }
}

// ---------------- ba proj + beta/g ----------------
__global__ __launch_bounds__(256) void k_ba(const float* __restrict__ x, const float* __restrict__ Wba,
                                            const float* __restrict__ dt_bias, const float* __restrict__ A_log,
                                            float* __restrict__ betaO, float* __restrict__ gO) {
  __shared__ float xs[4][1024];
  const int wid = threadIdx.x >> 6, lane = threadIdx.x & 63;
  const int m = blockIdx.x * 4 + wid;
#pragma unroll
  for (int i = 0; i < 16; ++i) xs[wid][lane + 64 * i] = x[(size_t)m * 1024 + lane + 64 * i];
  __syncthreads();
  const int n = lane & 31, half = lane >> 5;
  float acc = 0.f;
  const float* wp = Wba + n;
  const int kk0 = half * 512;
#pragma unroll 8
  for (int kk = kk0; kk < kk0 + 512; ++kk) acc += xs[wid][kk] * wp[kk * 32];
  acc += __shfl_xor(acc, 32);
  if (lane < 32) {
    if (n < 16) {
      betaO[(size_t)m * 16 + n] = 1.f / (1.f + expf(-acc));
    } else {
      int h = n - 16;
      float xx = acc + dt_bias[h];
      float sp = (xx > 20.f) ? xx : log1pf(expf(xx));
      gO[(size_t)m * 16 + h] = -expf(fmaxf(A_log[h], -2.3f)) * sp;
    }
  }
}

// ---------------- causal depthwise conv(4) + SiLU + l2norm; outputs per-(b,h) SWIZZLED bf16 hi/lo tiles ----------------
__global__ __launch_bounds__(256) void k_conv(const u16* __restrict__ qkv3, const float* __restrict__ convw,
                                              u16* __restrict__ qhG, u16* __restrict__ qlG,
                                              u16* __restrict__ khG, u16* __restrict__ klG,
                                              u16* __restrict__ vhG, u16* __restrict__ vlG) {
  __shared__ float cs[3072];
  __shared__ float innorm[32];
  const int bt = blockIdx.x;
  const int bb = bt >> 12, tt = bt & 4095;
  const int tid = threadIdx.x;
  const size_t rb = (size_t)bb * 4096;
#pragma unroll
  for (int s = 0; s < 3; ++s) {
    const int c4 = tid * 4 + s * 1024;   // contiguous 1KB segments per step
    float cwa[4][4];
#pragma unroll
    for (int e = 0; e < 4; ++e) {
      float4 t = *(const float4*)&convw[(c4 + e) * 4];
      cwa[e][0] = t.x; cwa[e][1] = t.y; cwa[e][2] = t.z; cwa[e][3] = t.w;
    }
    float acc[4] = {0.f, 0.f, 0.f, 0.f};
#pragma unroll
    for (int j = 0; j < 4; ++j) {
      const int tau = tt - 3 + j;
      if (tau >= 0) {
        ushort4 kv = *(const ushort4*)&qkv3[(rb + tau) * 3072 + c4];
        acc[0] += bf2f(kv.x) * cwa[0][j];
        acc[1] += bf2f(kv.y) * cwa[1][j];
        acc[2] += bf2f(kv.z) * cwa[2][j];
        acc[3] += bf2f(kv.w) * cwa[3][j];
      }
    }
#pragma unroll
    for (int e = 0; e < 4; ++e) cs[c4 + e] = acc[e] / (1.f + expf(-acc[e]));
  }
  __syncthreads();
  {
    const int grp = tid >> 3, off = (tid & 7) * 8;
    const float* p = cs + grp * 64 + off;
    float s = 0.f;
#pragma unroll
    for (int i = 0; i < 8; ++i) s += p[i] * p[i];
    s += __shfl_xor(s, 1); s += __shfl_xor(s, 2); s += __shfl_xor(s, 4);
    if ((tid & 7) == 0) innorm[grp] = rsqrtf(s + 1e-6f);
  }
  __syncthreads();
  // per-(b,h) swizzled tile outputs: elem (tt, d) of tile (bh, tt>>6) -> offset SW(tt&63, d)
  const int h = tid >> 4, d4 = (tid & 15) * 4;
  const size_t ob = ((size_t)(bb * 16 + h) * 64 + (tt >> 6)) * 4096 + SW(tt & 63, d4);
  {
    const int ci = h * 64 + d4;
    const float sc = innorm[h] * 0.125f;
    float4 o = {cs[ci] * sc, cs[ci + 1] * sc, cs[ci + 2] * sc, cs[ci + 3] * sc};
    ushort4 hh, ll;
    split4(o, hh, ll);
    *(ushort4*)&qhG[ob] = hh;
    *(ushort4*)&qlG[ob] = ll;
  }
  {
    const int ci = 1024 + h * 64 + d4;
    const float sc = innorm[16 + h];
    float4 o = {cs[ci] * sc, cs[ci + 1] * sc, cs[ci + 2] * sc, cs[ci + 3] * sc};
    ushort4 hh, ll;
    split4(o, hh, ll);
    *(ushort4*)&khG[ob] = hh;
    *(ushort4*)&klG[ob] = ll;
  }
  {
    const int ci = 2048 + h * 64 + d4;
    float4 o = {cs[ci], cs[ci + 1], cs[ci + 2], cs[ci + 3]};
    ushort4 hh, ll;
    split4(o, hh, ll);
    *(ushort4*)&vhG[ob] = hh;
    *(ushort4*)&vlG[ob] = ll;
  }
}

// ---------------- per-chunk precompute: gc cumsum + T=(I+A)^{-1} ----------------
__global__ __launch_bounds__(64) void k_prep(const u16* __restrict__ khG, const u16* __restrict__ klG,
                                             const float* __restrict__ gG, const float* __restrict__ betaG,
                                             float* __restrict__ gcG, u16* __restrict__ Tgh, u16* __restrict__ Tgl) {
  __shared__ __align__(16) char pmem[16384];
  u16* Kbh = (u16*)pmem;                 // 8KB
  u16* Kbl = (u16*)(pmem + 8192);        // 8KB
  float* Af = (float*)pmem;              // 16KB, aliases Kb after MFMA phase
  __shared__ float gcs[64], bs[64];
  const int bhc = blockIdx.x;              // b*1024 + h*64 + c
  const int c = bhc & 63, h = (bhc >> 6) & 15, bb = bhc >> 10;
  const int lane = threadIdx.x;
  const int t0 = c * 64;
  const size_t rowbase = (size_t)bb * 4096;
  const size_t ktile = (size_t)bhc * 4096;   // swizzled tile in global
#pragma unroll
  for (int i = 0; i < 8; ++i) {
    const int idx = lane + 64 * i;
    GLDS16(khG + ktile + idx * 8, &Kbh[idx * 8]);
    GLDS16(klG + ktile + idx * 8, &Kbl[idx * 8]);
  }
  {
    float gv = gG[(rowbase + t0 + lane) * 16 + h];
    float sc = gv;
#pragma unroll
    for (int off = 1; off < 64; off <<= 1) {
      float o = __shfl_up(sc, off);
      if (lane >= off) sc += o;
    }
    gcs[lane] = sc;
    bs[lane] = betaG[(rowbase + t0 + lane) * 16 + h];
    gcG[(size_t)bhc * 64 + lane] = sc;
  }
  __syncthreads();
  const int lrow = lane & 15, lk8 = (lane >> 4) * 8, rbase = (lane >> 4) * 4;
  f32x4 acc[4][4];
#pragma unroll
  for (int i = 0; i < 4; ++i)
#pragma unroll
    for (int j = 0; j < 4; ++j) acc[i][j] = {0.f, 0.f, 0.f, 0.f};
#pragma unroll
  for (int ks = 0; ks < 2; ++ks) {
    bf16x8 afh[4], afl[4], bfh[4], bfl[4];
#pragma unroll
    for (int i = 0; i < 4; ++i) {
      afh[i] = *(const bf16x8*)&Kbh[SW(i * 16 + lrow, ks * 32 + lk8)];
      afl[i] = *(const bf16x8*)&Kbl[SW(i * 16 + lrow, ks * 32 + lk8)];
    }
#pragma unroll
    for (int j = 0; j < 4; ++j) {
      bfh[j] = *(const bf16x8*)&Kbh[SW(j * 16 + lrow, ks * 32 + lk8)];
      bfl[j] = *(const bf16x8*)&Kbl[SW(j * 16 + lrow, ks * 32 + lk8)];
    }
#pragma unroll
    for (int i = 0; i < 4; ++i)
#pragma unroll
      for (int j = 0; j < 4; ++j) acc[i][j] = mm3(afh[i], afl[i], bfh[j], bfl[j], acc[i][j]);
  }
  __syncthreads();   // Kb reads complete before Af overwrites same LDS
#pragma unroll
  for (int i = 0; i < 4; ++i)
#pragma unroll
    for (int j = 0; j < 4; ++j)
#pragma unroll
      for (int r = 0; r < 4; ++r) {
        int t = i * 16 + rbase + r, s = j * 16 + lrow;
        Af[t * 64 + s] = (s < t) ? bs[t] * expf(gcs[t] - gcs[s]) * acc[i][j][r] : 0.f;
      }
  __syncthreads();
  // forward substitution: lane = column; X fully in registers (static unroll)
  float x[64];
#pragma unroll
  for (int t = 0; t < 64; ++t) {
    float sum = 0.f;
#pragma unroll
    for (int s4 = 0; s4 + 4 <= t; s4 += 4) {
      float4 a4 = *(const float4*)&Af[t * 64 + s4];
      sum += a4.x * x[s4] + a4.y * x[s4 + 1] + a4.z * x[s4 + 2] + a4.w * x[s4 + 3];
    }
#pragma unroll
    for (int s = (t & ~3); s < t; ++s) sum += Af[t * 64 + s] * x[s];
    x[t] = ((t == lane) ? 1.f : 0.f) - sum;
  }
#pragma unroll
  for (int t = 0; t < 64; ++t) {
    u16 hi, lo;
    splitbf(x[t], hi, lo);
    Tgh[(size_t)bhc * 4096 + SW(t, lane)] = hi;   // global T stored swizzled
    Tgl[(size_t)bhc * 4096 + SW(t, lane)] = lo;
  }
}

// ---------------- k_mn: per-chunk affine map (swizzled tiles; M,N global swizzled) ----------------
__global__ __launch_bounds__(256) void k_mn(const u16* __restrict__ khG, const u16* __restrict__ klG,
                                            const u16* __restrict__ vhG, const u16* __restrict__ vlG,
                                            const u16* __restrict__ Tgh, const u16* __restrict__ Tgl,
                                            const float* __restrict__ gcG, const float* __restrict__ betaG,
                                            u16* __restrict__ Mh, u16* __restrict__ Ml,
                                            u16* __restrict__ Nh, u16* __restrict__ Nl) {
  extern __shared__ __align__(16) char smem[];
  u16* base = (u16*)smem;
  u16* Tbh  = base + 0 * 4096;
  u16* Tbl  = base + 1 * 4096;
  u16* X1h  = base + 2 * 4096;
  u16* X1l  = base + 3 * 4096;
  u16* KdTh = base + 4 * 4096;
  u16* KdTl = base + 5 * 4096;
  u16* X2h  = base + 6 * 4096;
  u16* X2l  = base + 7 * 4096;
  float* gcs = (float*)(base + 8 * 4096);
  float* bs  = gcs + 64;

  const int bhc = blockIdx.x;
  const int c = bhc & 63, h = (bhc >> 6) & 15, bb = bhc >> 10;
  const int tid = threadIdx.x, w = tid >> 6, l = tid & 63;
  const int lrow = l & 15, lk8 = (l >> 4) * 8, rbase = (l >> 4) * 4;
  const int t0 = c * 64;
  const size_t rowbase = (size_t)bb * 4096;
  const size_t ktile = (size_t)bhc * 4096;

  if (tid < 64) {
    gcs[tid] = gcG[(size_t)bhc * 64 + tid];
    bs[tid] = betaG[(rowbase + t0 + tid) * 16 + h];
  }
#pragma unroll
  for (int i = 0; i < 2; ++i) {   // T global is swizzled: linear copy keeps tile swizzled
    const int idx = tid + 256 * i;
    const int off = idx * 8;
    *(float4*)&Tbh[off] = *(const float4*)&Tgh[(size_t)bhc * 4096 + off];
    *(float4*)&Tbl[off] = *(const float4*)&Tgl[(size_t)bhc * 4096 + off];
  }
  __syncthreads();
  const float gc63 = gcs[63];
#pragma unroll
  for (int i = 0; i < 16; ++i) {
    const int flat = tid + 256 * i;
    const int s = flat >> 6, d = flat & 63;
    const int sws = SW(s, d);
    const float kf = bf2f(khG[ktile + sws]) + bf2f(klG[ktile + sws]);
    const float gv = gcs[s], bv = bs[s];
    u16 hh, ll;
    splitbf(bv * expf(gv) * kf, hh, ll);
    X1h[SW(d, s)] = hh; X1l[SW(d, s)] = ll;
    splitbf(expf(gc63 - gv) * kf, hh, ll);
    KdTh[SW(d, s)] = hh; KdTl[SW(d, s)] = ll;
    const float vv = bf2f(vhG[ktile + sws]) + bf2f(vlG[ktile + sws]);
    splitbf(bv * vv, hh, ll);
    X2h[SW(d, s)] = hh; X2l[SW(d, s)] = ll;
  }
  __syncthreads();

  f32x4 aW[4], aU[4];
#pragma unroll
  for (int j = 0; j < 4; ++j) { aW[j] = {0.f,0.f,0.f,0.f}; aU[j] = {0.f,0.f,0.f,0.f}; }
#pragma unroll
  for (int ks = 0; ks < 2; ++ks) {
    const int ao = SW(w * 16 + lrow, ks * 32 + lk8);
    bf16x8 aTh = *(const bf16x8*)&Tbh[ao];
    bf16x8 aTl = *(const bf16x8*)&Tbl[ao];
#pragma unroll
    for (int j = 0; j < 4; ++j) {
      const int bo = SW(j * 16 + lrow, ks * 32 + lk8);
      aW[j] = mm3(aTh, aTl, *(const bf16x8*)&X1h[bo], *(const bf16x8*)&X1l[bo], aW[j]);
      aU[j] = mm3(aTh, aTl, *(const bf16x8*)&X2h[bo], *(const bf16x8*)&X2l[bo], aU[j]);
    }
  }
  __syncthreads();
#pragma unroll
  for (int j = 0; j < 4; ++j)
#pragma unroll
    for (int r = 0; r < 4; ++r) {
      const int t = w * 16 + rbase + r, dcol = j * 16 + lrow;
      u16 hh, ll;
      splitbf(aW[j][r], hh, ll);
      X1h[SW(dcol, t)] = hh; X1l[SW(dcol, t)] = ll;
      splitbf(aU[j][r], hh, ll);
      X2h[SW(dcol, t)] = hh; X2l[SW(dcol, t)] = ll;
    }
  __syncthreads();

  f32x4 aM[4], aN[4];
#pragma unroll
  for (int j = 0; j < 4; ++j) { aM[j] = {0.f,0.f,0.f,0.f}; aN[j] = {0.f,0.f,0.f,0.f}; }
#pragma unroll
  for (int ks = 0; ks < 2; ++ks) {
    const int ao = SW(w * 16 + lrow, ks * 32 + lk8);
    bf16x8 aKh = *(const bf16x8*)&KdTh[ao];
    bf16x8 aKl = *(const bf16x8*)&KdTl[ao];
#pragma unroll
    for (int j = 0; j < 4; ++j) {
      const int bo = SW(j * 16 + lrow, ks * 32 + lk8);
      aM[j] = mm3(aKh, aKl, *(const bf16x8*)&X1h[bo], *(const bf16x8*)&X1l[bo], aM[j]);
      aN[j] = mm3(aKh, aKl, *(const bf16x8*)&X2h[bo], *(const bf16x8*)&X2l[bo], aN[j]);
    }
  }
  __syncthreads();
  const float decC = expf(gc63);
#pragma unroll
  for (int j = 0; j < 4; ++j)
#pragma unroll
    for (int r = 0; r < 4; ++r) {
      const int d = w * 16 + rbase + r, d2 = j * 16 + lrow;
      u16 hh, ll;
      splitbf(((d == d2) ? decC : 0.f) - aM[j][r], hh, ll);
      X1h[SW(d, d2)] = hh; X1l[SW(d, d2)] = ll;
      splitbf(aN[j][r], hh, ll);
      X2h[SW(d, d2)] = hh; X2l[SW(d, d2)] = ll;
    }
  __syncthreads();
#pragma unroll
  for (int i = 0; i < 2; ++i) {   // linear copy out -> globals hold swizzled tiles
    const int idx = tid + 256 * i;
    const int off = idx * 8;
    *(float4*)&Mh[(size_t)bhc * 4096 + off] = *(const float4*)&X1h[off];
    *(float4*)&Ml[(size_t)bhc * 4096 + off] = *(const float4*)&X1l[off];
    *(float4*)&Nh[(size_t)bhc * 4096 + off] = *(const float4*)&X2h[off];
    *(float4*)&Nl[(size_t)bhc * 4096 + off] = *(const float4*)&X2l[off];
  }
}

// ---------------- k_seg: compose 8 chunks (swizzled tiles throughout) ----------------
__global__ __launch_bounds__(256) void k_seg(const u16* __restrict__ Mh, const u16* __restrict__ Ml,
                                             const u16* __restrict__ Nh, const u16* __restrict__ Nl,
                                             u16* __restrict__ Msegh, u16* __restrict__ Msegl,
                                             u16* __restrict__ Nsegh, u16* __restrict__ Nsegl) {
  extern __shared__ __align__(16) char smem[];
  u16* base = (u16*)smem;
  u16* MaTh = base + 0 * 4096;
  u16* MaTl = base + 1 * 4096;
  u16* NaTh = base + 2 * 4096;
  u16* NaTl = base + 3 * 4096;
  u16* sMh  = base + 4 * 4096;
  u16* sMl  = base + 5 * 4096;
  u16* sNh  = base + 6 * 4096;
  u16* sNl  = base + 7 * 4096;

  const int blk = blockIdx.x;                       // bh*8 + seg
  const size_t cbase = (size_t)(blk >> 3) * 64 + (blk & 7) * 8;
  const int tid = threadIdx.x, w = tid >> 6, l = tid & 63;
  const int lrow = l & 15, lk8 = (l >> 4) * 8, rbase = (l >> 4) * 4;

#pragma unroll
  for (int i = 0; i < 2; ++i) {
    const int off = (tid + 256 * i) * 8;
    *(float4*)&sMh[off] = *(const float4*)&Mh[cbase * 4096 + off];
    *(float4*)&sMl[off] = *(const float4*)&Ml[cbase * 4096 + off];
    *(float4*)&sNh[off] = *(const float4*)&Nh[cbase * 4096 + off];
    *(float4*)&sNl[off] = *(const float4*)&Nl[cbase * 4096 + off];
  }
  __syncthreads();
#pragma unroll
  for (int i = 0; i < 16; ++i) {       // transpose into accumulators
    const int flat = tid + 256 * i;
    const int a = flat >> 6, b = flat & 63;
    MaTh[SW(a, b)] = sMh[SW(b, a)];
    MaTl[SW(a, b)] = sMl[SW(b, a)];
    NaTh[SW(a, b)] = sNh[SW(b, a)];
    NaTl[SW(a, b)] = sNl[SW(b, a)];
  }
  __syncthreads();

  for (int j = 1; j < 8; ++j) {
#pragma unroll
    for (int i = 0; i < 2; ++i) {
      const int off = (tid + 256 * i) * 8;
      *(float4*)&sMh[off] = *(const float4*)&Mh[(cbase + j) * 4096 + off];
      *(float4*)&sMl[off] = *(const float4*)&Ml[(cbase + j) * 4096 + off];
      *(float4*)&sNh[off] = *(const float4*)&Nh[(cbase + j) * 4096 + off];
      *(float4*)&sNl[off] = *(const float4*)&Nl[(cbase + j) * 4096 + off];
    }
    __syncthreads();
    f32x4 aM2[4], aN2[4];
#pragma unroll
    for (int jj = 0; jj < 4; ++jj) { aM2[jj] = {0.f,0.f,0.f,0.f}; aN2[jj] = {0.f,0.f,0.f,0.f}; }
#pragma unroll
    for (int ks = 0; ks < 2; ++ks) {
      const int ao = SW(w * 16 + lrow, ks * 32 + lk8);
      bf16x8 aCh = *(const bf16x8*)&sMh[ao];
      bf16x8 aCl = *(const bf16x8*)&sMl[ao];
#pragma unroll
      for (int jj = 0; jj < 4; ++jj) {
        const int bo = SW(jj * 16 + lrow, ks * 32 + lk8);
        aM2[jj] = mm3(aCh, aCl, *(const bf16x8*)&MaTh[bo], *(const bf16x8*)&MaTl[bo], aM2[jj]);
        aN2[jj] = mm3(aCh, aCl, *(const bf16x8*)&NaTh[bo], *(const bf16x8*)&NaTl[bo], aN2[jj]);
      }
    }
    __syncthreads();
#pragma unroll
    for (int jj = 0; jj < 4; ++jj)
#pragma unroll
      for (int r = 0; r < 4; ++r) {
        const int t = w * 16 + rbase + r, col = jj * 16 + lrow;
        u16 hh, ll;
        splitbf(aM2[jj][r], hh, ll);
        MaTh[SW(col, t)] = hh; MaTl[SW(col, t)] = ll;
        const float nv = aN2[jj][r] + bf2f(sNh[SW(t, col)]) + bf2f(sNl[SW(t, col)]);
        splitbf(nv, hh, ll);
        NaTh[SW(col, t)] = hh; NaTl[SW(col, t)] = ll;
      }
    __syncthreads();
  }
#pragma unroll
  for (int i = 0; i < 16; ++i) {       // un-transpose; globals swizzled
    const int flat = tid + 256 * i;
    const int t = flat >> 6, s = flat & 63;
    Msegh[(size_t)blk * 4096 + SW(t, s)] = MaTh[SW(s, t)];
    Msegl[(size_t)blk * 4096 + SW(t, s)] = MaTl[SW(s, t)];
    Nsegh[(size_t)blk * 4096 + SW(t, s)] = NaTh[SW(s, t)];
    Nsegl[(size_t)blk * 4096 + SW(t, s)] = NaTl[SW(s, t)];
  }
}

// ---------------- k_bound: sequential 8-step prefix (S^T tiles, swizzled; Sseg global swizzled) ----------------
__global__ __launch_bounds__(256) void k_bound(const u16* __restrict__ Msegh, const u16* __restrict__ Msegl,
                                               const u16* __restrict__ Nsegh, const u16* __restrict__ Nsegl,
                                               u16* __restrict__ Ssegh, u16* __restrict__ Ssegl) {
  __shared__ __align__(16) u16 STh[4096], STl[4096];
  __shared__ __align__(16) u16 sMh[4096], sMl[4096], sNh[4096], sNl[4096];
  const int bh = blockIdx.x;
  const int tid = threadIdx.x, w = tid >> 6, l = tid & 63;
  const int lrow = l & 15, lk8 = (l >> 4) * 8, rbase = (l >> 4) * 4;
  for (int i = tid; i < 4096; i += 256) { STh[i] = (u16)0; STl[i] = (u16)0; }
  __syncthreads();
  for (int j = 0; j < 8; ++j) {
    const size_t sb = (size_t)(bh * 8 + j) * 4096;
#pragma unroll
    for (int i = 0; i < 2; ++i) {
      const int off = (tid + 256 * i) * 8;
      *(float4*)&Ssegh[sb + off] = *(const float4*)&STh[off];   // linear copies (all swizzled)
      *(float4*)&Ssegl[sb + off] = *(const float4*)&STl[off];
      *(float4*)&sMh[off] = *(const float4*)&Msegh[sb + off];
      *(float4*)&sMl[off] = *(const float4*)&Msegl[sb + off];
      *(float4*)&sNh[off] = *(const float4*)&Nsegh[sb + off];
      *(float4*)&sNl[off] = *(const float4*)&Nsegl[sb + off];
    }
    __syncthreads();
    f32x4 acc[4];
#pragma unroll
    for (int jj = 0; jj < 4; ++jj) acc[jj] = {0.f, 0.f, 0.f, 0.f};
#pragma unroll
    for (int ks = 0; ks < 2; ++ks) {
      const int ao = SW(w * 16 + lrow, ks * 32 + lk8);
      bf16x8 aSh = *(const bf16x8*)&STh[ao];
      bf16x8 aSl = *(const bf16x8*)&STl[ao];
#pragma unroll
      for (int jj = 0; jj < 4; ++jj) {
        const int bo = SW(jj * 16 + lrow, ks * 32 + lk8);
        acc[jj] = mm3(aSh, aSl, *(const bf16x8*)&sMh[bo], *(const bf16x8*)&sMl[bo], acc[jj]);
      }
    }
    __syncthreads();
#pragma unroll
    for (int jj = 0; jj < 4; ++jj)
#pragma unroll
      for (int r = 0; r < 4; ++r) {
        const int v = w * 16 + rbase + r, t = jj * 16 + lrow;
        const float sv = acc[jj][r] + bf2f(sNh[SW(t, v)]) + bf2f(sNl[SW(t, v)]);
        u16 hh, ll;
        splitbf(sv, hh, ll);
        STh[SW(v, t)] = hh; STl[SW(v, t)] = ll;
      }
    __syncthreads();
  }
}

// ---------------- k_scan2: 8-chunk scan per (bh,seg); 8 waves, GLDS pipeline, hoisted exps ----------------
__global__ __launch_bounds__(512, 2) void k_scan2(const u16* __restrict__ qhG, const u16* __restrict__ qlG,
                                               const u16* __restrict__ khG, const u16* __restrict__ klG,
                                               const u16* __restrict__ vhG, const u16* __restrict__ vlG,
                                               const u16* __restrict__ zb,
                                               const u16* __restrict__ Tgh, const u16* __restrict__ Tgl,
                                               const float* __restrict__ gcG,
                                               const float* __restrict__ betaG, const float* __restrict__ norm_w,
                                               const u16* __restrict__ Ssegh, const u16* __restrict__ Ssegl,
                                               u16* __restrict__ Yhi, u16* __restrict__ Ylo) {
  extern __shared__ __align__(16) char smem[];
  u16* base = (u16*)smem;
  u16* Kbh  = base + 0 * 4096;
  u16* Kbl  = base + 1 * 4096;
  u16* Qbh  = base + 2 * 4096;
  u16* Qbl  = base + 3 * 4096;
  u16* Vbh  = base + 4 * 4096;
  u16* Vbl  = base + 5 * 4096;
  u16* Zb   = base + 6 * 4096;
  u16* Tbh  = base + 7 * 4096;
  u16* Tbl  = base + 8 * 4096;
  u16* SbTh = base + 9 * 4096;
  u16* SbTl = base + 10 * 4096;
  u16* Mqh  = base + 11 * 4096;
  u16* Mql  = base + 12 * 4096;
  u16* KdTh = base + 13 * 4096;
  u16* KdTl = base + 14 * 4096;
  u16* RTh  = base + 15 * 4096;
  u16* RTl  = base + 16 * 4096;
  u16* UTh  = base + 17 * 4096;
  u16* UTl  = base + 18 * 4096;
  u16* Ybh  = RTh;   // RT dead after phase B
  u16* Ybl  = RTl;
  float* gcs = (float*)(base + 19 * 4096);
  float* bs  = gcs + 64;
  float* nws = gcs + 128;
  float* esF = gcs + 192;   // exp(gc63 - gcs[s])
  float* etF = gcs + 256;   // exp(gcs[t])
  float* ssP = gcs + 320;   // [2][64] RMS partials

  const int blk = blockIdx.x;             // bh*8 + seg
  const int bh = blk >> 3, seg = blk & 7;
  const int bb = bh >> 4, h = bh & 15;
  const int tid = threadIdx.x, w = tid >> 6, l = tid & 63;
  const int wrow = w >> 1, jh = w & 1;            // row quadrant, j-half
  const int lrow = l & 15, lk8 = (l >> 4) * 8, rbase = (l >> 4) * 4;
  const size_t rowbase = (size_t)bb * 4096;
  const size_t bhTile = (size_t)bh * 64;
  const int o8 = tid * 8;
  const int zr = tid >> 3, zc8 = (tid & 7) << 3;  // 512-thread float4 tile mapping

  // ---- prologue: GLDS stage everything for chunk seg*8 ----
  {
    const int c = seg * 8, t0 = c * 64;
    const size_t gt = (bhTile + c) * 4096;
    GLDS16(qhG + gt + o8, &Qbh[o8]);
    GLDS16(qlG + gt + o8, &Qbl[o8]);
    GLDS16(khG + gt + o8, &Kbh[o8]);
    GLDS16(klG + gt + o8, &Kbl[o8]);
    GLDS16(vhG + gt + o8, &Vbh[o8]);
    GLDS16(vlG + gt + o8, &Vbl[o8]);
    GLDS16(Tgh + (size_t)(bh * 64 + c) * 4096 + o8, &Tbh[o8]);
    GLDS16(Tgl + (size_t)(bh * 64 + c) * 4096 + o8, &Tbl[o8]);
    GLDS16(Ssegh + (size_t)blk * 4096 + o8, &SbTh[o8]);
    GLDS16(Ssegl + (size_t)blk * 4096 + o8, &SbTl[o8]);
    *(float4*)&Zb[SW(zr, zc8)] = *(const float4*)&zb[(rowbase + t0 + zr) * 1024 + h * 64 + zc8];
    if (tid < 64) {
      nws[tid] = norm_w[tid];
      float g0 = gcG[((size_t)bh * 64 + c) * 64 + tid];
      float b0 = betaG[(rowbase + t0 + tid) * 16 + h];
      float g63 = __shfl(g0, 63);
      gcs[tid] = g0; bs[tid] = b0;
      esF[tid] = expf(g63 - g0);
      etF[tid] = expf(g0);
    }
  }
  __syncthreads();

  for (int cc = 0; cc < 8; ++cc) {
    const int c = seg * 8 + cc;
    const int t0 = c * 64;
    const bool pf = (cc < 7);
    const size_t gt1 = (bhTile + c + 1) * 4096;

    // ---- tiny register prefetch: z, gc, bs for chunk c+1 ----
    float4 pz;
    float pgc = 0.f, pbs = 0.f;
    if (pf) {
      const int t1 = t0 + 64;
      pz = *(const float4*)&zb[(rowbase + t1 + zr) * 1024 + h * 64 + zc8];
      if (tid < 64) {
        pgc = gcG[((size_t)bh * 64 + (c + 1)) * 64 + tid];
        pbs = betaG[(rowbase + t1 + tid) * 16 + h];
      }
    }

    // ---- phase A: KdT build (no expf: esF) ----
#pragma unroll
    for (int i = 0; i < 8; ++i) {
      const int flat = tid * 8 + i;
      const int d = flat >> 6, s = flat & 63;
      const float kv = bf2f(Kbh[SW(s, d)]) + bf2f(Kbl[SW(s, d)]);
      u16 hh, ll;
      splitbf(esF[s] * kv, hh, ll);
      KdTh[SW(d, s)] = hh;
      KdTl[SW(d, s)] = ll;
    }
    f32x4 aqk[2], ap[2], aqs[2];
#pragma unroll
    for (int j = 0; j < 2; ++j) { aqk[j] = {0.f,0.f,0.f,0.f}; ap[j] = {0.f,0.f,0.f,0.f}; aqs[j] = {0.f,0.f,0.f,0.f}; }
#pragma unroll
    for (int ks = 0; ks < 2; ++ks) {
      const int ao = SW(wrow * 16 + lrow, ks * 32 + lk8);
      bf16x8 aKh = *(const bf16x8*)&Kbh[ao];
      bf16x8 aKl = *(const bf16x8*)&Kbl[ao];
      bf16x8 aQh = *(const bf16x8*)&Qbh[ao];
      bf16x8 aQl = *(const bf16x8*)&Qbl[ao];
#pragma unroll
      for (int j = 0; j < 2; ++j) {
        const int jj = jh * 2 + j;
        const int bo = SW(jj * 16 + lrow, ks * 32 + lk8);
        bf16x8 bKh = *(const bf16x8*)&Kbh[bo];
        bf16x8 bKl = *(const bf16x8*)&Kbl[bo];
        bf16x8 bSh = *(const bf16x8*)&SbTh[bo];
        bf16x8 bSl = *(const bf16x8*)&SbTl[bo];
        aqk[j] = mm3(aQh, aQl, bKh, bKl, aqk[j]);
        ap[j]  = mm3(aKh, aKl, bSh, bSl, ap[j]);
        aqs[j] = mm3(aQh, aQl, bSh, bSl, aqs[j]);
      }
    }
#pragma unroll
    for (int j = 0; j < 2; ++j)
#pragma unroll
      for (int r = 0; r < 4; ++r) {
        const int t = wrow * 16 + rbase + r;
        const int s = (jh * 2 + j) * 16 + lrow;
        u16 mh, ml;
        splitbf((s <= t) ? expf(gcs[t] - gcs[s]) * aqk[j][r] : 0.f, mh, ml);
        Mqh[SW(t, s)] = mh;
        Mql[SW(t, s)] = ml;
        const float vv = bf2f(Vbh[SW(t, s)]) + bf2f(Vbl[SW(t, s)]);
        const float rhs = bs[t] * (vv - etF[t] * ap[j][r]);
        u16 rh, rl;
        splitbf(rhs, rh, rl);
        RTh[SW(s, t)] = rh;
        RTl[SW(s, t)] = rl;
      }
    __syncthreads();                        // barrier A

    // ---- Q/K/V dead: async GLDS chunk c+1 Q/K/V (drains at barrier B) ----
    if (pf) {
      GLDS16(qhG + gt1 + o8, &Qbh[o8]);
      GLDS16(qlG + gt1 + o8, &Qbl[o8]);
      GLDS16(khG + gt1 + o8, &Kbh[o8]);
      GLDS16(klG + gt1 + o8, &Kbl[o8]);
      GLDS16(vhG + gt1 + o8, &Vbh[o8]);
      GLDS16(vlG + gt1 + o8, &Vbl[o8]);
    }

    // ---- phase B: U = T @ RHS ----
    f32x4 au[2];
#pragma unroll
    for (int j = 0; j < 2; ++j) au[j] = {0.f, 0.f, 0.f, 0.f};
#pragma unroll
    for (int ks = 0; ks < 2; ++ks) {
      const int ao = SW(wrow * 16 + lrow, ks * 32 + lk8);
      bf16x8 aTh = *(const bf16x8*)&Tbh[ao];
      bf16x8 aTl = *(const bf16x8*)&Tbl[ao];
#pragma unroll
      for (int j = 0; j < 2; ++j) {
        const int bo = SW((jh * 2 + j) * 16 + lrow, ks * 32 + lk8);
        au[j] = mm3(aTh, aTl, *(const bf16x8*)&RTh[bo], *(const bf16x8*)&RTl[bo], au[j]);
      }
    }
#pragma unroll
    for (int j = 0; j < 2; ++j)
#pragma unroll
      for (int r = 0; r < 4; ++r) {
        u16 uh, ul;
        splitbf(au[j][r], uh, ul);
        const int o = SW((jh * 2 + j) * 16 + lrow, wrow * 16 + rbase + r);
        UTh[o] = uh;
        UTl[o] = ul;
      }
    __syncthreads();                        // barrier B (drains Q/K/V GLDS)

    // ---- T dead: async GLDS chunk c+1 T (drains at barrier C) ----
    if (pf) {
      GLDS16(Tgh + (size_t)(bh * 64 + (c + 1)) * 4096 + o8, &Tbh[o8]);
      GLDS16(Tgl + (size_t)(bh * 64 + (c + 1)) * 4096 + o8, &Tbl[o8]);
    }

    // ---- phase C ----
    f32x4 amu[2], as_[2];
#pragma unroll
    for (int j = 0; j < 2; ++j) { amu[j] = {0.f,0.f,0.f,0.f}; as_[j] = {0.f,0.f,0.f,0.f}; }
#pragma unroll
    for (int ks = 0; ks < 2; ++ks) {
      const int ao = SW(wrow * 16 + lrow, ks * 32 + lk8);
      bf16x8 aMh = *(const bf16x8*)&Mqh[ao];
      bf16x8 aMl = *(const bf16x8*)&Mql[ao];
      bf16x8 aKdh = *(const bf16x8*)&KdTh[ao];
      bf16x8 aKdl = *(const bf16x8*)&KdTl[ao];
#pragma unroll
      for (int j = 0; j < 2; ++j) {
        const int bo = SW((jh * 2 + j) * 16 + lrow, ks * 32 + lk8);
        bf16x8 bUh = *(const bf16x8*)&UTh[bo];
        bf16x8 bUl = *(const bf16x8*)&UTl[bo];
        amu[j] = mm3(aMh, aMl, bUh, bUl, amu[j]);
        as_[j] = mm3(aKdh, aKdl, bUh, bUl, as_[j]);
      }
    }
    // y values + cross-wave RMS partials
    float yv_[4][2];
#pragma unroll
    for (int r = 0; r < 4; ++r) {
      const int t = wrow * 16 + rbase + r;
      const float gt = etF[t];
      float ss = 0.f;
#pragma unroll
      for (int j = 0; j < 2; ++j) {
        yv_[r][j] = gt * aqs[j][r] + amu[j][r];
        ss += yv_[r][j] * yv_[r][j];
      }
      ss += __shfl_xor(ss, 1); ss += __shfl_xor(ss, 2); ss += __shfl_xor(ss, 4); ss += __shfl_xor(ss, 8);
      if (lrow == 0) ssP[jh * 64 + t] = ss;
    }
    __syncthreads();                        // publish RMS partials
#pragma unroll
    for (int r = 0; r < 4; ++r) {
      const int t = wrow * 16 + rbase + r;
      const float rstd = rsqrtf((ssP[t] + ssP[64 + t]) * (1.f / 64.f) + 1e-6f);
#pragma unroll
      for (int j = 0; j < 2; ++j) {
        const int col = (jh * 2 + j) * 16 + lrow;
        const float zz = bf2f(Zb[SW(t, col)]);
        const float yv = yv_[r][j] * rstd * nws[col] * (zz / (1.f + expf(-zz)));
        u16 yh, yl;
        splitbf(yv, yh, yl);
        Ybh[SW(t, col)] = yh;
        Ybl[SW(t, col)] = yl;
      }
    }
    {
      const float decC = etF[63];
#pragma unroll
      for (int j = 0; j < 2; ++j)
#pragma unroll
        for (int r = 0; r < 4; ++r) {
          const int d = wrow * 16 + rbase + r, col = (jh * 2 + j) * 16 + lrow;
          const int o = SW(col, d);
          const float s0 = bf2f(SbTh[o]) + bf2f(SbTl[o]);
          const float sv = decC * s0 + as_[j][r];
          u16 sh, sl;
          splitbf(sv, sh, sl);
          SbTh[o] = sh;
          SbTl[o] = sl;
        }
    }
    __syncthreads();                        // barrier C (drains T GLDS)

    // ---- store Y (pre-swizzled for GEMM2); write prefetched z; update gcs/bs/esF/etF ----
    {
      const size_t gsw = gidx_swz(rowbase + t0 + zr, h * 64 + zc8, 1024);
      *(float4*)&Yhi[gsw] = *(const float4*)&Ybh[SW(zr, zc8)];
      *(float4*)&Ylo[gsw] = *(const float4*)&Ybl[SW(zr, zc8)];
    }
    if (pf) {
      *(float4*)&Zb[SW(zr, zc8)] = pz;
      if (tid < 64) {
        float g63 = __shfl(pgc, 63);
        gcs[tid] = pgc; bs[tid] = pbs;
        esF[tid] = expf(g63 - pgc);
        etF[tid] = expf(pgc);
      }
    }
    __syncthreads();                        // barrier D
  }
}

extern "C" void kernel_launch(void* const* d_in, const int* in_sizes, int n_in,
                              void* d_out, int out_size, void* d_ws, size_t ws_size,
                              hipStream_t stream) {
  (void)in_sizes; (void)n_in; (void)out_size; (void)ws_size;
  const float* x       = (const float*)d_in[0];
  const float* W_in    = (const float*)d_in[1];
  const float* W_ba    = (const float*)d_in[2];
  const float* conv_w  = (const float*)d_in[3];
  const float* dt_bias = (const float*)d_in[4];
  const float* A_log   = (const float*)d_in[5];
  const float* norm_w  = (const float*)d_in[6];
  const float* W_o     = (const float*)d_in[7];
  float* out = (float*)d_out;
  char* ws = (char*)d_ws;
  const size_t MB = 1048576;

  _Float16* xh = (_Float16*)(ws + 0);     // 16 MB f16 x (pre-swizzled) -> Mh -> Yhi
  u16* MhB   = (u16*)(ws + 0);
  u16* YhiB  = (u16*)(ws + 0);
  u16* MlB   = (u16*)(ws + 16 * MB);      // 16 MB Ml -> Ylo
  u16* YloB  = (u16*)(ws + 16 * MB);
  _Float16* WinT = (_Float16*)(ws + 32 * MB);  // 8 MB f16 (pre-swizzled, dead post-GEMM1)
  float* gB  = (float*)(ws + 32 * MB);             // 0.5 MB (post-GEMM1)
  float* bB  = (float*)(ws + 32 * MB + 524288);    // 0.5 MB
  float* gcB = (float*)(ws + 33 * MB);             // 0.5 MB
  u16* Ssegh = (u16*)(ws + 34 * MB);      // 2 MB
  u16* Ssegl = (u16*)(ws + 36 * MB);      // 2 MB
  u16* Msegh = (u16*)(ws + 38 * MB);      // 2 MB
  u16* Msegl = (u16*)(ws + 40 * MB);      // 2 MB
  u16* Nsegh = (u16*)(ws + 42 * MB);      // 2 MB
  u16* Nsegl = (u16*)(ws + 44 * MB);      // 2 MB
  u16* WoT   = (u16*)(ws + 48 * MB);      // 2 MB (pre-swizzled)
  u16* qkv3  = (u16*)(ws + 50 * MB);      // 48 MB (dead post-conv)
  u16* NhB   = (u16*)(ws + 50 * MB);      // 16 MB
  u16* NlB   = (u16*)(ws + 66 * MB);      // 16 MB
  u16* zbB   = (u16*)(ws + 98 * MB);      // 16 MB (GEMM-major)
  u16* qhG   = (u16*)(ws + 114 * MB);     // 16 MB (per-(b,h) swizzled tiles)
  u16* qlG   = (u16*)(ws + 130 * MB);     // 16 MB
  u16* khG   = (u16*)(ws + 146 * MB);     // 16 MB
  u16* klG   = (u16*)(ws + 162 * MB);     // 16 MB
  u16* vhG   = (u16*)(ws + 178 * MB);     // 16 MB
  u16* vlG   = (u16*)(ws + 194 * MB);     // 16 MB
  u16* TghB  = (u16*)(ws + 210 * MB);     // 16 MB
  u16* TglB  = (u16*)(ws + 226 * MB);     // 16 MB  (end 242 MB)

  const int SCAN_LDS = 19 * 8192 + 448 * 4;   // 157440 B
  const int MN_LDS   = 8 * 8192 + 512;        // 66048 B
  const int SEG_LDS  = 8 * 8192;              // 65536 B

  k_cast_h<<<8192, 256, 0, stream>>>(x, xh, 8388608);
  k_transpose_h<<<dim3(64, 16), 256, 0, stream>>>(W_in, WinT, 1024, 4096);
  k_transpose<<<dim3(16, 16), 256, 0, stream>>>(W_o, WoT, 1024, 1024);
  k_gemm_h<<<dim3(16, 32), 512, 0, stream>>>(xh, WinT, qkv3, zbB, 8192, 4096, 1024);
  k_ba<<<2048, 256, 0, stream>>>(x, W_ba, dt_bias, A_log, bB, gB);
  k_conv<<<8192, 256, 0, stream>>>(qkv3, conv_w, qhG, qlG, khG, klG, vhG, vlG);
  k_prep<<<2048, 64, 0, stream>>>(khG, klG, gB, bB, gcB, TghB, TglB);
  hipFuncSetAttribute((const void*)k_mn, hipFuncAttributeMaxDynamicSharedMemorySize, MN_LDS);
  k_mn<<<2048, 256, MN_LDS, stream>>>(khG, klG, vhG, vlG, TghB, TglB, gcB, bB, MhB, MlB, NhB, NlB);
  hipFuncSetAttribute((const void*)k_seg, hipFuncAttributeMaxDynamicSharedMemorySize, SEG_LDS);
  k_seg<<<256, 256, SEG_LDS, stream>>>(MhB, MlB, NhB, NlB, Msegh, Msegl, Nsegh, Nsegl);
  k_bound<<<32, 256, 0, stream>>>(Msegh, Msegl, Nsegh, Nsegl, Ssegh, Ssegl);
  hipFuncSetAttribute((const void*)k_scan2, hipFuncAttributeMaxDynamicSharedMemorySize, SCAN_LDS);
  k_scan2<<<256, 512, SCAN_LDS, stream>>>(qhG, qlG, khG, klG, vhG, vlG, zbB, TghB, TglB, gcB, bB, norm_w,
                                          Ssegh, Ssegl, YhiB, YloB);
  k_gemm2<<<dim3(8, 64), 256, 0, stream>>>(YhiB, YloB, WoT, out, 8192, 1024, 1024);
}

// Round 18
// 512.253 us; speedup vs baseline: 1.0496x; 1.0004x over previous
//
#include <hip/hip_runtime.h>

typedef unsigned short u16;
typedef unsigned int u32;
typedef __attribute__((ext_vector_type(8))) __bf16 bf16x8;
typedef __attribute__((ext_vector_type(8))) _Float16 f16x8;
typedef __attribute__((ext_vector_type(4))) _Float16 f16x4;
typedef __attribute__((ext_vector_type(4))) float f32x4;

#define DEV __device__ __forceinline__

DEV u16 f2bf(float f) {
  u32 u = __float_as_uint(f);
  u += 0x7FFFu + ((u >> 16) & 1u);   // RNE
  return (u16)(u >> 16);
}
DEV float bf2f(u16 h) { return __uint_as_float(((u32)h) << 16); }
DEV void splitbf(float f, u16& hi, u16& lo) {
  u16 h = f2bf(f);
  hi = h;
  lo = f2bf(f - bf2f(h));
}
DEV void split4(float4 v, ushort4& hh, ushort4& ll) {
  splitbf(v.x, hh.x, ll.x);
  splitbf(v.y, hh.y, ll.y);
  splitbf(v.z, hh.z, ll.z);
  splitbf(v.w, hh.w, ll.w);
}
// Relaxed barrier: LDS-hazard-only (per-wave lgkmcnt(0) then s_barrier).
// Does NOT drain vmcnt -> global_load_lds prefetch stays in flight across it.
// Full __syncthreads (vmcnt(0)) still used where GLDS targets are consumed.
DEV void lbar() {
  __builtin_amdgcn_sched_barrier(0);
  asm volatile("s_waitcnt lgkmcnt(0)" ::: "memory");
  __builtin_amdgcn_s_barrier();
  __builtin_amdgcn_sched_barrier(0);
}
// T2 XOR swizzle for 64x64 u16 tiles (128B rows): kills the 16-way ds_read_b128 bank conflict.
DEV int SW(int r, int c) { return r * 64 + ((c) ^ ((r & 7) << 3)); }

// GEMM-tile swizzle: [*][32] u16 K-tiles, double-row (128B) units of 8x16B blocks,
// block index XORed with (row>>1)&7 -> fragment reads become 2-way (free).
DEV int SWG(int r, int c) {
  int db = ((r & 1) << 2) | ((c >> 3) & 3);
  int dbp = db ^ ((r >> 1) & 7);
  return ((r >> 1) << 6) | (dbp << 3) | (c & 7);
}
// producer-side: where logical (row, col) lives in the pre-swizzled global
DEV size_t gidx_swz(size_t row, int col, int rowlen) {
  int rr7 = (int)((row >> 1) & 7);
  int db = (int)(((row & 1) << 2) | ((col >> 3) & 3));
  int dbp = db ^ rr7;
  size_t rowp = (row & ~(size_t)1) | (size_t)(dbp >> 2);
  int colp = (col & ~31) | ((dbp & 3) << 3) | (col & 7);
  return rowp * (size_t)rowlen + colp;
}

#define MFMA16(a,b,c) __builtin_amdgcn_mfma_f32_16x16x32_bf16((a),(b),(c),0,0,0)
#define MFMAH(a,b,c)  __builtin_amdgcn_mfma_f32_16x16x32_f16((a),(b),(c),0,0,0)
#define GLDS16(g,l) __builtin_amdgcn_global_load_lds((__attribute__((address_space(1))) void*)(g), (__attribute__((address_space(3))) void*)(l), 16, 0, 0)

DEV f32x4 mm3(bf16x8 ah, bf16x8 al, bf16x8 bh, bf16x8 bl, f32x4 acc) {
  acc = MFMA16(ah, bl, acc);
  acc = MFMA16(al, bh, acc);
  acc = MFMA16(ah, bh, acc);
  return acc;
}

// ---------------- cast f32 -> f16, pre-swizzled for GEMM staging ----------------
__global__ __launch_bounds__(256) void k_cast_h(const float* __restrict__ in, _Float16* __restrict__ out, int n) {
  int idx = (blockIdx.x * 256 + threadIdx.x) * 4;
  if (idx + 3 < n) {
    float4 v = *(const float4*)(in + idx);
    f16x4 o = {(_Float16)v.x, (_Float16)v.y, (_Float16)v.z, (_Float16)v.w};
    const size_t row = (size_t)(idx >> 10);
    const int col = idx & 1023;
    *(f16x4*)(out + gidx_swz(row, col, 1024)) = o;
  }
}

// ---------------- transpose f32 [R][C] -> f16 [C][R], pre-swizzled ----------------
__global__ __launch_bounds__(256) void k_transpose_h(const float* __restrict__ in, _Float16* __restrict__ out, int R, int Cc) {
  __shared__ float tile[64][65];
  int c0 = blockIdx.x * 64, r0 = blockIdx.y * 64;
  int lr = threadIdx.x >> 6, lc = threadIdx.x & 63;
#pragma unroll
  for (int i = 0; i < 16; ++i) {
    int r = lr + i * 4;
    tile[r][lc] = in[(size_t)(r0 + r) * Cc + c0 + lc];
  }
  __syncthreads();
#pragma unroll
  for (int i = 0; i < 16; ++i) {
    int oc = lr + i * 4;
    out[gidx_swz((size_t)(c0 + oc), r0 + lc, R)] = (_Float16)tile[lc][oc];
  }
}

// ---------------- transpose f32 [R][C] -> bf16 [C][R], pre-swizzled ----------------
__global__ __launch_bounds__(256) void k_transpose(const float* __restrict__ in, u16* __restrict__ out, int R, int Cc) {
  __shared__ float tile[64][65];
  int c0 = blockIdx.x * 64, r0 = blockIdx.y * 64;
  int lr = threadIdx.x >> 6, lc = threadIdx.x & 63;
#pragma unroll
  for (int i = 0; i < 16; ++i) {
    int r = lr + i * 4;
    tile[r][lc] = in[(size_t)(r0 + r) * Cc + c0 + lc];
  }
  __syncthreads();
#pragma unroll
  for (int i = 0; i < 16; ++i) {
    int oc = lr + i * 4;
    out[gidx_swz((size_t)(c0 + oc), r0 + lc, R)] = f2bf(tile[lc][oc]);
  }
}

// ---------------- GEMM1 (f16 single): 256x256 tile, 8 waves, dbuf issue-before-compute ----------------
__global__ __launch_bounds__(512, 2) void k_gemm_h(const _Float16* __restrict__ A, const _Float16* __restrict__ Bt,
                                                   u16* __restrict__ Cq, u16* __restrict__ Cz, int M, int N, int K) {
  __shared__ __align__(16) u16 As[2][256 * 32];
  __shared__ __align__(16) u16 Bs[2][256 * 32];
  const int tid = threadIdx.x;
  const int nwg = gridDim.x * gridDim.y;
  int bid = blockIdx.y * gridDim.x + blockIdx.x;
  bid = (bid & 7) * (nwg >> 3) + (bid >> 3);      // bijective (nwg % 8 == 0)
  const int m0 = (bid / gridDim.x) * 256, n0 = (bid % gridDim.x) * 256;
  const int w = tid >> 6, l = tid & 63;
  const int wr = (w >> 1) * 64, wc = (w & 1) * 128;
  const int lrow = l & 15, lk = (l >> 4) * 8, rbase = (l >> 4) * 4;

  f32x4 acc[4][8];
#pragma unroll
  for (int i = 0; i < 4; ++i)
#pragma unroll
    for (int j = 0; j < 8; ++j) acc[i][j] = {0.f, 0.f, 0.f, 0.f};

  const _Float16* aBase = A + (size_t)m0 * K;
  const _Float16* bBase = Bt + (size_t)n0 * K;
  const int srow0 = tid >> 2, scol0 = (tid & 3) * 8;        // staging chunk 0
  const int srow1 = (tid + 512) >> 2;                       // staging chunk 1 (same scol)

  auto STAGE = [&](int buf, int k0) {
    GLDS16(aBase + (size_t)srow0 * K + k0 + scol0, &As[buf][tid * 8]);
    GLDS16(aBase + (size_t)srow1 * K + k0 + scol0, &As[buf][4096 + tid * 8]);
    GLDS16(bBase + (size_t)srow0 * K + k0 + scol0, &Bs[buf][tid * 8]);
    GLDS16(bBase + (size_t)srow1 * K + k0 + scol0, &Bs[buf][4096 + tid * 8]);
  };

  STAGE(0, 0);
  __syncthreads();
  int cur = 0;
  for (int k0 = 0; k0 < K; k0 += 32) {
    if (k0 + 32 < K) STAGE(cur ^ 1, k0 + 32);   // issue next-tile loads (fly under compute)
    f16x8 af[4], bfr[8];
#pragma unroll
    for (int i = 0; i < 4; ++i) af[i] = *(const f16x8*)&As[cur][SWG(wr + i * 16 + lrow, lk)];
#pragma unroll
    for (int j = 0; j < 8; ++j) bfr[j] = *(const f16x8*)&Bs[cur][SWG(wc + j * 16 + lrow, lk)];
#pragma unroll
    for (int i = 0; i < 4; ++i)
#pragma unroll
      for (int j = 0; j < 8; ++j) acc[i][j] = MFMAH(af[i], bfr[j], acc[i][j]);
    __syncthreads();                            // drains next-tile GLDS + this tile's ds_reads
    cur ^= 1;
  }
#pragma unroll
  for (int i = 0; i < 4; ++i)
#pragma unroll
    for (int j = 0; j < 8; ++j)
#pragma unroll
      for (int r = 0; r < 4; ++r) {
        int row = m0 + wr + i * 16 + rbase + r;
        int col = n0 + wc + j * 16 + lrow;
        if (col < 3072) Cq[(size_t)row * 3072 + col] = f2bf(acc[i][j][r]);
        else            Cz[(size_t)row * 1024 + col - 3072] = f2bf(acc[i][j][r]);
      }
}

// ---------------- GEMM2: (Ah+Al) @ Bt^T, f32 out, dbuf issue-before-compute ----------------
__global__ __launch_bounds__(256, 2) void k_gemm2(const u16* __restrict__ Ah, const u16* __restrict__ Al,
                                               const u16* __restrict__ Bt, float* __restrict__ Cf,
                                               int M, int N, int K) {
  __shared__ __align__(16) u16 Ash[2][128 * 32];
  __shared__ __align__(16) u16 Asl[2][128 * 32];
  __shared__ __align__(16) u16 Bs[2][128 * 32];
  const int tid = threadIdx.x;
  const int nwg = gridDim.x * gridDim.y;
  int bid = blockIdx.y * gridDim.x + blockIdx.x;
  bid = (bid & 7) * (nwg >> 3) + (bid >> 3);
  const int m0 = (bid / gridDim.x) * 128, n0 = (bid % gridDim.x) * 128;
  const int w = tid >> 6, l = tid & 63;
  const int wr = (w >> 1) * 64, wc = (w & 1) * 64;
  const int lrow = l & 15, lk = (l >> 4) * 8, rbase = (l >> 4) * 4;
  const int srow = tid >> 2, scol = (tid & 3) * 8;

  f32x4 acc[4][4];
#pragma unroll
  for (int i = 0; i < 4; ++i)
#pragma unroll
    for (int j = 0; j < 4; ++j) acc[i][j] = {0.f, 0.f, 0.f, 0.f};

  const u16* ahBase = Ah + (size_t)m0 * K;
  const u16* alBase = Al + (size_t)m0 * K;
  const u16* bBase  = Bt + (size_t)n0 * K;

  auto STAGE = [&](int buf, int k0) {
    GLDS16(ahBase + (size_t)srow * K + k0 + scol,        &Ash[buf][tid * 8]);
    GLDS16(ahBase + (size_t)(srow + 64) * K + k0 + scol, &Ash[buf][2048 + tid * 8]);
    GLDS16(alBase + (size_t)srow * K + k0 + scol,        &Asl[buf][tid * 8]);
    GLDS16(alBase + (size_t)(srow + 64) * K + k0 + scol, &Asl[buf][2048 + tid * 8]);
    GLDS16(bBase + (size_t)srow * K + k0 + scol,         &Bs[buf][tid * 8]);
    GLDS16(bBase + (size_t)(srow + 64) * K + k0 + scol,  &Bs[buf][2048 + tid * 8]);
  };

  STAGE(0, 0);
  __syncthreads();
  int cur = 0;
  for (int k0 = 0; k0 < K; k0 += 32) {
    if (k0 + 32 < K) STAGE(cur ^ 1, k0 + 32);
    bf16x8 afh[4], afl[4], bfr[4];
#pragma unroll
    for (int i = 0; i < 4; ++i) afh[i] = *(const bf16x8*)&Ash[cur][SWG(wr + i * 16 + lrow, lk)];
#pragma unroll
    for (int i = 0; i < 4; ++i) afl[i] = *(const bf16x8*)&Asl[cur][SWG(wr + i * 16 + lrow, lk)];
#pragma unroll
    for (int j = 0; j < 4; ++j) bfr[j] = *(const bf16x8*)&Bs[cur][SWG(wc + j * 16 + lrow, lk)];
#pragma unroll
    for (int i = 0; i < 4; ++i)
#pragma unroll
      for (int j = 0; j < 4; ++j) {
        acc[i][j] = MFMA16(afl[i], bfr[j], acc[i][j]);
        acc[i][j] = MFMA16(afh[i], bfr[j], acc[i][j]);
      }
    __syncthreads();
    cur ^= 1;
  }
#pragma unroll
  for (int i = 0; i < 4; ++i)
#pragma unroll
    for (int j = 0; j < 4; ++j)
#pragma unroll
      for (int r = 0; r < 4; ++r) {
        int row = m0 + wr + i * 16 + rbase + r;
        int col = n0 + wc + j * 16 + lrow;
        Cf[(size_t)row * N + col] = acc[i][j][r];
      }
}

// ---------------- ba proj + beta/g ----------------
__global__ __launch_bounds__(256) void k_ba(const float* __restrict__ x, const float* __restrict__ Wba,
                                            const float* __restrict__ dt_bias, const float* __restrict__ A_log,
                                            float* __restrict__ betaO, float* __restrict__ gO) {
  __shared__ float xs[4][1024];
  const int wid = threadIdx.x >> 6, lane = threadIdx.x & 63;
  const int m = blockIdx.x * 4 + wid;
#pragma unroll
  for (int i = 0; i < 16; ++i) xs[wid][lane + 64 * i] = x[(size_t)m * 1024 + lane + 64 * i];
  __syncthreads();
  const int n = lane & 31, half = lane >> 5;
  float acc = 0.f;
  const float* wp = Wba + n;
  const int kk0 = half * 512;
#pragma unroll 8
  for (int kk = kk0; kk < kk0 + 512; ++kk) acc += xs[wid][kk] * wp[kk * 32];
  acc += __shfl_xor(acc, 32);
  if (lane < 32) {
    if (n < 16) {
      betaO[(size_t)m * 16 + n] = 1.f / (1.f + expf(-acc));
    } else {
      int h = n - 16;
      float xx = acc + dt_bias[h];
      float sp = (xx > 20.f) ? xx : log1pf(expf(xx));
      gO[(size_t)m * 16 + h] = -expf(fmaxf(A_log[h], -2.3f)) * sp;
    }
  }
}

// ---------------- causal depthwise conv(4) + SiLU + l2norm; outputs per-(b,h) SWIZZLED bf16 hi/lo tiles ----------------
__global__ __launch_bounds__(256) void k_conv(const u16* __restrict__ qkv3, const float* __restrict__ convw,
                                              u16* __restrict__ qhG, u16* __restrict__ qlG,
                                              u16* __restrict__ khG, u16* __restrict__ klG,
                                              u16* __restrict__ vhG, u16* __restrict__ vlG) {
  __shared__ float cs[3072];
  __shared__ float innorm[32];
  const int bt = blockIdx.x;
  const int bb = bt >> 12, tt = bt & 4095;
  const int tid = threadIdx.x;
  const size_t rb = (size_t)bb * 4096;
#pragma unroll
  for (int s = 0; s < 3; ++s) {
    const int c4 = tid * 4 + s * 1024;   // contiguous 1KB segments per step
    float cwa[4][4];
#pragma unroll
    for (int e = 0; e < 4; ++e) {
      float4 t = *(const float4*)&convw[(c4 + e) * 4];
      cwa[e][0] = t.x; cwa[e][1] = t.y; cwa[e][2] = t.z; cwa[e][3] = t.w;
    }
    float acc[4] = {0.f, 0.f, 0.f, 0.f};
#pragma unroll
    for (int j = 0; j < 4; ++j) {
      const int tau = tt - 3 + j;
      if (tau >= 0) {
        ushort4 kv = *(const ushort4*)&qkv3[(rb + tau) * 3072 + c4];
        acc[0] += bf2f(kv.x) * cwa[0][j];
        acc[1] += bf2f(kv.y) * cwa[1][j];
        acc[2] += bf2f(kv.z) * cwa[2][j];
        acc[3] += bf2f(kv.w) * cwa[3][j];
      }
    }
#pragma unroll
    for (int e = 0; e < 4; ++e) cs[c4 + e] = acc[e] / (1.f + expf(-acc[e]));
  }
  __syncthreads();
  {
    const int grp = tid >> 3, off = (tid & 7) * 8;
    const float* p = cs + grp * 64 + off;
    float s = 0.f;
#pragma unroll
    for (int i = 0; i < 8; ++i) s += p[i] * p[i];
    s += __shfl_xor(s, 1); s += __shfl_xor(s, 2); s += __shfl_xor(s, 4);
    if ((tid & 7) == 0) innorm[grp] = rsqrtf(s + 1e-6f);
  }
  __syncthreads();
  // per-(b,h) swizzled tile outputs: elem (tt, d) of tile (bh, tt>>6) -> offset SW(tt&63, d)
  const int h = tid >> 4, d4 = (tid & 15) * 4;
  const size_t ob = ((size_t)(bb * 16 + h) * 64 + (tt >> 6)) * 4096 + SW(tt & 63, d4);
  {
    const int ci = h * 64 + d4;
    const float sc = innorm[h] * 0.125f;
    float4 o = {cs[ci] * sc, cs[ci + 1] * sc, cs[ci + 2] * sc, cs[ci + 3] * sc};
    ushort4 hh, ll;
    split4(o, hh, ll);
    *(ushort4*)&qhG[ob] = hh;
    *(ushort4*)&qlG[ob] = ll;
  }
  {
    const int ci = 1024 + h * 64 + d4;
    const float sc = innorm[16 + h];
    float4 o = {cs[ci] * sc, cs[ci + 1] * sc, cs[ci + 2] * sc, cs[ci + 3] * sc};
    ushort4 hh, ll;
    split4(o, hh, ll);
    *(ushort4*)&khG[ob] = hh;
    *(ushort4*)&klG[ob] = ll;
  }
  {
    const int ci = 2048 + h * 64 + d4;
    float4 o = {cs[ci], cs[ci + 1], cs[ci + 2], cs[ci + 3]};
    ushort4 hh, ll;
    split4(o, hh, ll);
    *(ushort4*)&vhG[ob] = hh;
    *(ushort4*)&vlG[ob] = ll;
  }
}

// ---------------- per-chunk precompute: gc cumsum + T=(I+A)^{-1} ----------------
__global__ __launch_bounds__(64) void k_prep(const u16* __restrict__ khG, const u16* __restrict__ klG,
                                             const float* __restrict__ gG, const float* __restrict__ betaG,
                                             float* __restrict__ gcG, u16* __restrict__ Tgh, u16* __restrict__ Tgl) {
  __shared__ __align__(16) char pmem[16384];
  u16* Kbh = (u16*)pmem;                 // 8KB
  u16* Kbl = (u16*)(pmem + 8192);        // 8KB
  float* Af = (float*)pmem;              // 16KB, aliases Kb after MFMA phase
  __shared__ float gcs[64], bs[64];
  const int bhc = blockIdx.x;              // b*1024 + h*64 + c
  const int c = bhc & 63, h = (bhc >> 6) & 15, bb = bhc >> 10;
  const int lane = threadIdx.x;
  const int t0 = c * 64;
  const size_t rowbase = (size_t)bb * 4096;
  const size_t ktile = (size_t)bhc * 4096;   // swizzled tile in global
#pragma unroll
  for (int i = 0; i < 8; ++i) {
    const int idx = lane + 64 * i;
    GLDS16(khG + ktile + idx * 8, &Kbh[idx * 8]);
    GLDS16(klG + ktile + idx * 8, &Kbl[idx * 8]);
  }
  {
    float gv = gG[(rowbase + t0 + lane) * 16 + h];
    float sc = gv;
#pragma unroll
    for (int off = 1; off < 64; off <<= 1) {
      float o = __shfl_up(sc, off);
      if (lane >= off) sc += o;
    }
    gcs[lane] = sc;
    bs[lane] = betaG[(rowbase + t0 + lane) * 16 + h];
    gcG[(size_t)bhc * 64 + lane] = sc;
  }
  __syncthreads();
  const int lrow = lane & 15, lk8 = (lane >> 4) * 8, rbase = (lane >> 4) * 4;
  f32x4 acc[4][4];
#pragma unroll
  for (int i = 0; i < 4; ++i)
#pragma unroll
    for (int j = 0; j < 4; ++j) acc[i][j] = {0.f, 0.f, 0.f, 0.f};
#pragma unroll
  for (int ks = 0; ks < 2; ++ks) {
    bf16x8 afh[4], afl[4], bfh[4], bfl[4];
#pragma unroll
    for (int i = 0; i < 4; ++i) {
      afh[i] = *(const bf16x8*)&Kbh[SW(i * 16 + lrow, ks * 32 + lk8)];
      afl[i] = *(const bf16x8*)&Kbl[SW(i * 16 + lrow, ks * 32 + lk8)];
    }
#pragma unroll
    for (int j = 0; j < 4; ++j) {
      bfh[j] = *(const bf16x8*)&Kbh[SW(j * 16 + lrow, ks * 32 + lk8)];
      bfl[j] = *(const bf16x8*)&Kbl[SW(j * 16 + lrow, ks * 32 + lk8)];
    }
#pragma unroll
    for (int i = 0; i < 4; ++i)
#pragma unroll
      for (int j = 0; j < 4; ++j) acc[i][j] = mm3(afh[i], afl[i], bfh[j], bfl[j], acc[i][j]);
  }
  __syncthreads();   // Kb reads complete before Af overwrites same LDS
#pragma unroll
  for (int i = 0; i < 4; ++i)
#pragma unroll
    for (int j = 0; j < 4; ++j)
#pragma unroll
      for (int r = 0; r < 4; ++r) {
        int t = i * 16 + rbase + r, s = j * 16 + lrow;
        Af[t * 64 + s] = (s < t) ? bs[t] * expf(gcs[t] - gcs[s]) * acc[i][j][r] : 0.f;
      }
  __syncthreads();
  // forward substitution: lane = column; X fully in registers (static unroll)
  float x[64];
#pragma unroll
  for (int t = 0; t < 64; ++t) {
    float sum = 0.f;
#pragma unroll
    for (int s4 = 0; s4 + 4 <= t; s4 += 4) {
      float4 a4 = *(const float4*)&Af[t * 64 + s4];
      sum += a4.x * x[s4] + a4.y * x[s4 + 1] + a4.z * x[s4 + 2] + a4.w * x[s4 + 3];
    }
#pragma unroll
    for (int s = (t & ~3); s < t; ++s) sum += Af[t * 64 + s] * x[s];
    x[t] = ((t == lane) ? 1.f : 0.f) - sum;
  }
#pragma unroll
  for (int t = 0; t < 64; ++t) {
    u16 hi, lo;
    splitbf(x[t], hi, lo);
    Tgh[(size_t)bhc * 4096 + SW(t, lane)] = hi;   // global T stored swizzled
    Tgl[(size_t)bhc * 4096 + SW(t, lane)] = lo;
  }
}

// ---------------- k_mn: per-chunk affine map (swizzled tiles; M,N global swizzled) ----------------
__global__ __launch_bounds__(256) void k_mn(const u16* __restrict__ khG, const u16* __restrict__ klG,
                                            const u16* __restrict__ vhG, const u16* __restrict__ vlG,
                                            const u16* __restrict__ Tgh, const u16* __restrict__ Tgl,
                                            const float* __restrict__ gcG, const float* __restrict__ betaG,
                                            u16* __restrict__ Mh, u16* __restrict__ Ml,
                                            u16* __restrict__ Nh, u16* __restrict__ Nl) {
  extern __shared__ __align__(16) char smem[];
  u16* base = (u16*)smem;
  u16* Tbh  = base + 0 * 4096;
  u16* Tbl  = base + 1 * 4096;
  u16* X1h  = base + 2 * 4096;
  u16* X1l  = base + 3 * 4096;
  u16* KdTh = base + 4 * 4096;
  u16* KdTl = base + 5 * 4096;
  u16* X2h  = base + 6 * 4096;
  u16* X2l  = base + 7 * 4096;
  float* gcs = (float*)(base + 8 * 4096);
  float* bs  = gcs + 64;

  const int bhc = blockIdx.x;
  const int c = bhc & 63, h = (bhc >> 6) & 15, bb = bhc >> 10;
  const int tid = threadIdx.x, w = tid >> 6, l = tid & 63;
  const int lrow = l & 15, lk8 = (l >> 4) * 8, rbase = (l >> 4) * 4;
  const int t0 = c * 64;
  const size_t rowbase = (size_t)bb * 4096;
  const size_t ktile = (size_t)bhc * 4096;

  if (tid < 64) {
    gcs[tid] = gcG[(size_t)bhc * 64 + tid];
    bs[tid] = betaG[(rowbase + t0 + tid) * 16 + h];
  }
#pragma unroll
  for (int i = 0; i < 2; ++i) {   // T global is swizzled: linear copy keeps tile swizzled
    const int idx = tid + 256 * i;
    const int off = idx * 8;
    *(float4*)&Tbh[off] = *(const float4*)&Tgh[(size_t)bhc * 4096 + off];
    *(float4*)&Tbl[off] = *(const float4*)&Tgl[(size_t)bhc * 4096 + off];
  }
  __syncthreads();
  const float gc63 = gcs[63];
#pragma unroll
  for (int i = 0; i < 16; ++i) {
    const int flat = tid + 256 * i;
    const int s = flat >> 6, d = flat & 63;
    const int sws = SW(s, d);
    const float kf = bf2f(khG[ktile + sws]) + bf2f(klG[ktile + sws]);
    const float gv = gcs[s], bv = bs[s];
    u16 hh, ll;
    splitbf(bv * expf(gv) * kf, hh, ll);
    X1h[SW(d, s)] = hh; X1l[SW(d, s)] = ll;
    splitbf(expf(gc63 - gv) * kf, hh, ll);
    KdTh[SW(d, s)] = hh; KdTl[SW(d, s)] = ll;
    const float vv = bf2f(vhG[ktile + sws]) + bf2f(vlG[ktile + sws]);
    splitbf(bv * vv, hh, ll);
    X2h[SW(d, s)] = hh; X2l[SW(d, s)] = ll;
  }
  __syncthreads();

  f32x4 aW[4], aU[4];
#pragma unroll
  for (int j = 0; j < 4; ++j) { aW[j] = {0.f,0.f,0.f,0.f}; aU[j] = {0.f,0.f,0.f,0.f}; }
#pragma unroll
  for (int ks = 0; ks < 2; ++ks) {
    const int ao = SW(w * 16 + lrow, ks * 32 + lk8);
    bf16x8 aTh = *(const bf16x8*)&Tbh[ao];
    bf16x8 aTl = *(const bf16x8*)&Tbl[ao];
#pragma unroll
    for (int j = 0; j < 4; ++j) {
      const int bo = SW(j * 16 + lrow, ks * 32 + lk8);
      aW[j] = mm3(aTh, aTl, *(const bf16x8*)&X1h[bo], *(const bf16x8*)&X1l[bo], aW[j]);
      aU[j] = mm3(aTh, aTl, *(const bf16x8*)&X2h[bo], *(const bf16x8*)&X2l[bo], aU[j]);
    }
  }
  __syncthreads();
#pragma unroll
  for (int j = 0; j < 4; ++j)
#pragma unroll
    for (int r = 0; r < 4; ++r) {
      const int t = w * 16 + rbase + r, dcol = j * 16 + lrow;
      u16 hh, ll;
      splitbf(aW[j][r], hh, ll);
      X1h[SW(dcol, t)] = hh; X1l[SW(dcol, t)] = ll;
      splitbf(aU[j][r], hh, ll);
      X2h[SW(dcol, t)] = hh; X2l[SW(dcol, t)] = ll;
    }
  __syncthreads();

  f32x4 aM[4], aN[4];
#pragma unroll
  for (int j = 0; j < 4; ++j) { aM[j] = {0.f,0.f,0.f,0.f}; aN[j] = {0.f,0.f,0.f,0.f}; }
#pragma unroll
  for (int ks = 0; ks < 2; ++ks) {
    const int ao = SW(w * 16 + lrow, ks * 32 + lk8);
    bf16x8 aKh = *(const bf16x8*)&KdTh[ao];
    bf16x8 aKl = *(const bf16x8*)&KdTl[ao];
#pragma unroll
    for (int j = 0; j < 4; ++j) {
      const int bo = SW(j * 16 + lrow, ks * 32 + lk8);
      aM[j] = mm3(aKh, aKl, *(const bf16x8*)&X1h[bo], *(const bf16x8*)&X1l[bo], aM[j]);
      aN[j] = mm3(aKh, aKl, *(const bf16x8*)&X2h[bo], *(const bf16x8*)&X2l[bo], aN[j]);
    }
  }
  __syncthreads();
  const float decC = expf(gc63);
#pragma unroll
  for (int j = 0; j < 4; ++j)
#pragma unroll
    for (int r = 0; r < 4; ++r) {
      const int d = w * 16 + rbase + r, d2 = j * 16 + lrow;
      u16 hh, ll;
      splitbf(((d == d2) ? decC : 0.f) - aM[j][r], hh, ll);
      X1h[SW(d, d2)] = hh; X1l[SW(d, d2)] = ll;
      splitbf(aN[j][r], hh, ll);
      X2h[SW(d, d2)] = hh; X2l[SW(d, d2)] = ll;
    }
  __syncthreads();
#pragma unroll
  for (int i = 0; i < 2; ++i) {   // linear copy out -> globals hold swizzled tiles
    const int idx = tid + 256 * i;
    const int off = idx * 8;
    *(float4*)&Mh[(size_t)bhc * 4096 + off] = *(const float4*)&X1h[off];
    *(float4*)&Ml[(size_t)bhc * 4096 + off] = *(const float4*)&X1l[off];
    *(float4*)&Nh[(size_t)bhc * 4096 + off] = *(const float4*)&X2h[off];
    *(float4*)&Nl[(size_t)bhc * 4096 + off] = *(const float4*)&X2l[off];
  }
}

// ---------------- k_seg: compose 8 chunks (swizzled tiles throughout) ----------------
__global__ __launch_bounds__(256) void k_seg(const u16* __restrict__ Mh, const u16* __restrict__ Ml,
                                             const u16* __restrict__ Nh, const u16* __restrict__ Nl,
                                             u16* __restrict__ Msegh, u16* __restrict__ Msegl,
                                             u16* __restrict__ Nsegh, u16* __restrict__ Nsegl) {
  extern __shared__ __align__(16) char smem[];
  u16* base = (u16*)smem;
  u16* MaTh = base + 0 * 4096;
  u16* MaTl = base + 1 * 4096;
  u16* NaTh = base + 2 * 4096;
  u16* NaTl = base + 3 * 4096;
  u16* sMh  = base + 4 * 4096;
  u16* sMl  = base + 5 * 4096;
  u16* sNh  = base + 6 * 4096;
  u16* sNl  = base + 7 * 4096;

  const int blk = blockIdx.x;                       // bh*8 + seg
  const size_t cbase = (size_t)(blk >> 3) * 64 + (blk & 7) * 8;
  const int tid = threadIdx.x, w = tid >> 6, l = tid & 63;
  const int lrow = l & 15, lk8 = (l >> 4) * 8, rbase = (l >> 4) * 4;

#pragma unroll
  for (int i = 0; i < 2; ++i) {
    const int off = (tid + 256 * i) * 8;
    *(float4*)&sMh[off] = *(const float4*)&Mh[cbase * 4096 + off];
    *(float4*)&sMl[off] = *(const float4*)&Ml[cbase * 4096 + off];
    *(float4*)&sNh[off] = *(const float4*)&Nh[cbase * 4096 + off];
    *(float4*)&sNl[off] = *(const float4*)&Nl[cbase * 4096 + off];
  }
  __syncthreads();
#pragma unroll
  for (int i = 0; i < 16; ++i) {       // transpose into accumulators
    const int flat = tid + 256 * i;
    const int a = flat >> 6, b = flat & 63;
    MaTh[SW(a, b)] = sMh[SW(b, a)];
    MaTl[SW(a, b)] = sMl[SW(b, a)];
    NaTh[SW(a, b)] = sNh[SW(b, a)];
    NaTl[SW(a, b)] = sNl[SW(b, a)];
  }
  __syncthreads();

  for (int j = 1; j < 8; ++j) {
#pragma unroll
    for (int i = 0; i < 2; ++i) {
      const int off = (tid + 256 * i) * 8;
      *(float4*)&sMh[off] = *(const float4*)&Mh[(cbase + j) * 4096 + off];
      *(float4*)&sMl[off] = *(const float4*)&Ml[(cbase + j) * 4096 + off];
      *(float4*)&sNh[off] = *(const float4*)&Nh[(cbase + j) * 4096 + off];
      *(float4*)&sNl[off] = *(const float4*)&Nl[(cbase + j) * 4096 + off];
    }
    __syncthreads();
    f32x4 aM2[4], aN2[4];
#pragma unroll
    for (int jj = 0; jj < 4; ++jj) { aM2[jj] = {0.f,0.f,0.f,0.f}; aN2[jj] = {0.f,0.f,0.f,0.f}; }
#pragma unroll
    for (int ks = 0; ks < 2; ++ks) {
      const int ao = SW(w * 16 + lrow, ks * 32 + lk8);
      bf16x8 aCh = *(const bf16x8*)&sMh[ao];
      bf16x8 aCl = *(const bf16x8*)&sMl[ao];
#pragma unroll
      for (int jj = 0; jj < 4; ++jj) {
        const int bo = SW(jj * 16 + lrow, ks * 32 + lk8);
        aM2[jj] = mm3(aCh, aCl, *(const bf16x8*)&MaTh[bo], *(const bf16x8*)&MaTl[bo], aM2[jj]);
        aN2[jj] = mm3(aCh, aCl, *(const bf16x8*)&NaTh[bo], *(const bf16x8*)&NaTl[bo], aN2[jj]);
      }
    }
    __syncthreads();
#pragma unroll
    for (int jj = 0; jj < 4; ++jj)
#pragma unroll
      for (int r = 0; r < 4; ++r) {
        const int t = w * 16 + rbase + r, col = jj * 16 + lrow;
        u16 hh, ll;
        splitbf(aM2[jj][r], hh, ll);
        MaTh[SW(col, t)] = hh; MaTl[SW(col, t)] = ll;
        const float nv = aN2[jj][r] + bf2f(sNh[SW(t, col)]) + bf2f(sNl[SW(t, col)]);
        splitbf(nv, hh, ll);
        NaTh[SW(col, t)] = hh; NaTl[SW(col, t)] = ll;
      }
    __syncthreads();
  }
#pragma unroll
  for (int i = 0; i < 16; ++i) {       // un-transpose; globals swizzled
    const int flat = tid + 256 * i;
    const int t = flat >> 6, s = flat & 63;
    Msegh[(size_t)blk * 4096 + SW(t, s)] = MaTh[SW(s, t)];
    Msegl[(size_t)blk * 4096 + SW(t, s)] = MaTl[SW(s, t)];
    Nsegh[(size_t)blk * 4096 + SW(t, s)] = NaTh[SW(s, t)];
    Nsegl[(size_t)blk * 4096 + SW(t, s)] = NaTl[SW(s, t)];
  }
}

// ---------------- k_bound: sequential 8-step prefix (S^T tiles, swizzled; Sseg global swizzled) ----------------
__global__ __launch_bounds__(256) void k_bound(const u16* __restrict__ Msegh, const u16* __restrict__ Msegl,
                                               const u16* __restrict__ Nsegh, const u16* __restrict__ Nsegl,
                                               u16* __restrict__ Ssegh, u16* __restrict__ Ssegl) {
  __shared__ __align__(16) u16 STh[4096], STl[4096];
  __shared__ __align__(16) u16 sMh[4096], sMl[4096], sNh[4096], sNl[4096];
  const int bh = blockIdx.x;
  const int tid = threadIdx.x, w = tid >> 6, l = tid & 63;
  const int lrow = l & 15, lk8 = (l >> 4) * 8, rbase = (l >> 4) * 4;
  for (int i = tid; i < 4096; i += 256) { STh[i] = (u16)0; STl[i] = (u16)0; }
  __syncthreads();
  for (int j = 0; j < 8; ++j) {
    const size_t sb = (size_t)(bh * 8 + j) * 4096;
#pragma unroll
    for (int i = 0; i < 2; ++i) {
      const int off = (tid + 256 * i) * 8;
      *(float4*)&Ssegh[sb + off] = *(const float4*)&STh[off];   // linear copies (all swizzled)
      *(float4*)&Ssegl[sb + off] = *(const float4*)&STl[off];
      *(float4*)&sMh[off] = *(const float4*)&Msegh[sb + off];
      *(float4*)&sMl[off] = *(const float4*)&Msegl[sb + off];
      *(float4*)&sNh[off] = *(const float4*)&Nsegh[sb + off];
      *(float4*)&sNl[off] = *(const float4*)&Nsegl[sb + off];
    }
    __syncthreads();
    f32x4 acc[4];
#pragma unroll
    for (int jj = 0; jj < 4; ++jj) acc[jj] = {0.f, 0.f, 0.f, 0.f};
#pragma unroll
    for (int ks = 0; ks < 2; ++ks) {
      const int ao = SW(w * 16 + lrow, ks * 32 + lk8);
      bf16x8 aSh = *(const bf16x8*)&STh[ao];
      bf16x8 aSl = *(const bf16x8*)&STl[ao];
#pragma unroll
      for (int jj = 0; jj < 4; ++jj) {
        const int bo = SW(jj * 16 + lrow, ks * 32 + lk8);
        acc[jj] = mm3(aSh, aSl, *(const bf16x8*)&sMh[bo], *(const bf16x8*)&sMl[bo], acc[jj]);
      }
    }
    __syncthreads();
#pragma unroll
    for (int jj = 0; jj < 4; ++jj)
#pragma unroll
      for (int r = 0; r < 4; ++r) {
        const int v = w * 16 + rbase + r, t = jj * 16 + lrow;
        const float sv = acc[jj][r] + bf2f(sNh[SW(t, v)]) + bf2f(sNl[SW(t, v)]);
        u16 hh, ll;
        splitbf(sv, hh, ll);
        STh[SW(v, t)] = hh; STl[SW(v, t)] = ll;
      }
    __syncthreads();
  }
}

// ---------------- k_scan2: 8-chunk scan per (bh,seg); 8 waves, GLDS pipeline, relaxed barriers ----------------
__global__ __launch_bounds__(512, 2) void k_scan2(const u16* __restrict__ qhG, const u16* __restrict__ qlG,
                                               const u16* __restrict__ khG, const u16* __restrict__ klG,
                                               const u16* __restrict__ vhG, const u16* __restrict__ vlG,
                                               const u16* __restrict__ zb,
                                               const u16* __restrict__ Tgh, const u16* __restrict__ Tgl,
                                               const float* __restrict__ gcG,
                                               const float* __restrict__ betaG, const float* __restrict__ norm_w,
                                               const u16* __restrict__ Ssegh, const u16* __restrict__ Ssegl,
                                               u16* __restrict__ Yhi, u16* __restrict__ Ylo) {
  extern __shared__ __align__(16) char smem[];
  u16* base = (u16*)smem;
  u16* Kbh  = base + 0 * 4096;
  u16* Kbl  = base + 1 * 4096;
  u16* Qbh  = base + 2 * 4096;
  u16* Qbl  = base + 3 * 4096;
  u16* Vbh  = base + 4 * 4096;
  u16* Vbl  = base + 5 * 4096;
  u16* Zb   = base + 6 * 4096;
  u16* Tbh  = base + 7 * 4096;
  u16* Tbl  = base + 8 * 4096;
  u16* SbTh = base + 9 * 4096;
  u16* SbTl = base + 10 * 4096;
  u16* Mqh  = base + 11 * 4096;
  u16* Mql  = base + 12 * 4096;
  u16* KdTh = base + 13 * 4096;
  u16* KdTl = base + 14 * 4096;
  u16* RTh  = base + 15 * 4096;
  u16* RTl  = base + 16 * 4096;
  u16* UTh  = base + 17 * 4096;
  u16* UTl  = base + 18 * 4096;
  u16* Ybh  = RTh;   // RT dead after phase B
  u16* Ybl  = RTl;
  float* gcs = (float*)(base + 19 * 4096);
  float* bs  = gcs + 64;
  float* nws = gcs + 128;
  float* esF = gcs + 192;   // exp(gc63 - gcs[s])
  float* etF = gcs + 256;   // exp(gcs[t])
  float* ssP = gcs + 320;   // [2][64] RMS partials

  const int blk = blockIdx.x;             // bh*8 + seg
  const int bh = blk >> 3, seg = blk & 7;
  const int bb = bh >> 4, h = bh & 15;
  const int tid = threadIdx.x, w = tid >> 6, l = tid & 63;
  const int wrow = w >> 1, jh = w & 1;            // row quadrant, j-half
  const int lrow = l & 15, lk8 = (l >> 4) * 8, rbase = (l >> 4) * 4;
  const size_t rowbase = (size_t)bb * 4096;
  const size_t bhTile = (size_t)bh * 64;
  const int o8 = tid * 8;
  const int zr = tid >> 3, zc8 = (tid & 7) << 3;  // 512-thread float4 tile mapping

  // ---- prologue: GLDS stage everything for chunk seg*8 ----
  {
    const int c = seg * 8, t0 = c * 64;
    const size_t gt = (bhTile + c) * 4096;
    GLDS16(qhG + gt + o8, &Qbh[o8]);
    GLDS16(qlG + gt + o8, &Qbl[o8]);
    GLDS16(khG + gt + o8, &Kbh[o8]);
    GLDS16(klG + gt + o8, &Kbl[o8]);
    GLDS16(vhG + gt + o8, &Vbh[o8]);
    GLDS16(vlG + gt + o8, &Vbl[o8]);
    GLDS16(Tgh + (size_t)(bh * 64 + c) * 4096 + o8, &Tbh[o8]);
    GLDS16(Tgl + (size_t)(bh * 64 + c) * 4096 + o8, &Tbl[o8]);
    GLDS16(Ssegh + (size_t)blk * 4096 + o8, &SbTh[o8]);
    GLDS16(Ssegl + (size_t)blk * 4096 + o8, &SbTl[o8]);
    *(float4*)&Zb[SW(zr, zc8)] = *(const float4*)&zb[(rowbase + t0 + zr) * 1024 + h * 64 + zc8];
    if (tid < 64) {
      nws[tid] = norm_w[tid];
      float g0 = gcG[((size_t)bh * 64 + c) * 64 + tid];
      float b0 = betaG[(rowbase + t0 + tid) * 16 + h];
      float g63 = __shfl(g0, 63);
      gcs[tid] = g0; bs[tid] = b0;
      esF[tid] = expf(g63 - g0);
      etF[tid] = expf(g0);
    }
  }
  __syncthreads();   // full: drains prologue GLDS (phase A reads K/Q/V/T/S)

  for (int cc = 0; cc < 8; ++cc) {
    const int c = seg * 8 + cc;
    const int t0 = c * 64;
    const bool pf = (cc < 7);
    const size_t gt1 = (bhTile + c + 1) * 4096;

    // ---- tiny register prefetch: z, gc, bs for chunk c+1 ----
    float4 pz;
    float pgc = 0.f, pbs = 0.f;
    if (pf) {
      const int t1 = t0 + 64;
      pz = *(const float4*)&zb[(rowbase + t1 + zr) * 1024 + h * 64 + zc8];
      if (tid < 64) {
        pgc = gcG[((size_t)bh * 64 + (c + 1)) * 64 + tid];
        pbs = betaG[(rowbase + t1 + tid) * 16 + h];
      }
    }

    // ---- phase A: KdT build (no expf: esF) ----
#pragma unroll
    for (int i = 0; i < 8; ++i) {
      const int flat = tid * 8 + i;
      const int d = flat >> 6, s = flat & 63;
      const float kv = bf2f(Kbh[SW(s, d)]) + bf2f(Kbl[SW(s, d)]);
      u16 hh, ll;
      splitbf(esF[s] * kv, hh, ll);
      KdTh[SW(d, s)] = hh;
      KdTl[SW(d, s)] = ll;
    }
    f32x4 aqk[2], ap[2], aqs[2];
#pragma unroll
    for (int j = 0; j < 2; ++j) { aqk[j] = {0.f,0.f,0.f,0.f}; ap[j] = {0.f,0.f,0.f,0.f}; aqs[j] = {0.f,0.f,0.f,0.f}; }
#pragma unroll
    for (int ks = 0; ks < 2; ++ks) {
      const int ao = SW(wrow * 16 + lrow, ks * 32 + lk8);
      bf16x8 aKh = *(const bf16x8*)&Kbh[ao];
      bf16x8 aKl = *(const bf16x8*)&Kbl[ao];
      bf16x8 aQh = *(const bf16x8*)&Qbh[ao];
      bf16x8 aQl = *(const bf16x8*)&Qbl[ao];
#pragma unroll
      for (int j = 0; j < 2; ++j) {
        const int jj = jh * 2 + j;
        const int bo = SW(jj * 16 + lrow, ks * 32 + lk8);
        bf16x8 bKh = *(const bf16x8*)&Kbh[bo];
        bf16x8 bKl = *(const bf16x8*)&Kbl[bo];
        bf16x8 bSh = *(const bf16x8*)&SbTh[bo];
        bf16x8 bSl = *(const bf16x8*)&SbTl[bo];
        aqk[j] = mm3(aQh, aQl, bKh, bKl, aqk[j]);
        ap[j]  = mm3(aKh, aKl, bSh, bSl, ap[j]);
        aqs[j] = mm3(aQh, aQl, bSh, bSl, aqs[j]);
      }
    }
#pragma unroll
    for (int j = 0; j < 2; ++j)
#pragma unroll
      for (int r = 0; r < 4; ++r) {
        const int t = wrow * 16 + rbase + r;
        const int s = (jh * 2 + j) * 16 + lrow;
        u16 mh, ml;
        splitbf((s <= t) ? expf(gcs[t] - gcs[s]) * aqk[j][r] : 0.f, mh, ml);
        Mqh[SW(t, s)] = mh;
        Mql[SW(t, s)] = ml;
        const float vv = bf2f(Vbh[SW(t, s)]) + bf2f(Vbl[SW(t, s)]);
        const float rhs = bs[t] * (vv - etF[t] * ap[j][r]);
        u16 rh, rl;
        splitbf(rhs, rh, rl);
        RTh[SW(s, t)] = rh;
        RTl[SW(s, t)] = rl;
      }
    lbar();                                 // barrier A (LDS only; K/Q/V reads done per-wave)

    // ---- Q/K/V dead: async GLDS chunk c+1 Q/K/V (drains only at barrier D) ----
    if (pf) {
      GLDS16(qhG + gt1 + o8, &Qbh[o8]);
      GLDS16(qlG + gt1 + o8, &Qbl[o8]);
      GLDS16(khG + gt1 + o8, &Kbh[o8]);
      GLDS16(klG + gt1 + o8, &Kbl[o8]);
      GLDS16(vhG + gt1 + o8, &Vbh[o8]);
      GLDS16(vlG + gt1 + o8, &Vbl[o8]);
    }

    // ---- phase B: U = T @ RHS ----
    f32x4 au[2];
#pragma unroll
    for (int j = 0; j < 2; ++j) au[j] = {0.f, 0.f, 0.f, 0.f};
#pragma unroll
    for (int ks = 0; ks < 2; ++ks) {
      const int ao = SW(wrow * 16 + lrow, ks * 32 + lk8);
      bf16x8 aTh = *(const bf16x8*)&Tbh[ao];
      bf16x8 aTl = *(const bf16x8*)&Tbl[ao];
#pragma unroll
      for (int j = 0; j < 2; ++j) {
        const int bo = SW((jh * 2 + j) * 16 + lrow, ks * 32 + lk8);
        au[j] = mm3(aTh, aTl, *(const bf16x8*)&RTh[bo], *(const bf16x8*)&RTl[bo], au[j]);
      }
    }
#pragma unroll
    for (int j = 0; j < 2; ++j)
#pragma unroll
      for (int r = 0; r < 4; ++r) {
        u16 uh, ul;
        splitbf(au[j][r], uh, ul);
        const int o = SW((jh * 2 + j) * 16 + lrow, wrow * 16 + rbase + r);
        UTh[o] = uh;
        UTl[o] = ul;
      }
    lbar();                                 // barrier B (LDS only; QKV GLDS stays in flight)

    // ---- T dead: async GLDS chunk c+1 T (drains only at barrier D) ----
    if (pf) {
      GLDS16(Tgh + (size_t)(bh * 64 + (c + 1)) * 4096 + o8, &Tbh[o8]);
      GLDS16(Tgl + (size_t)(bh * 64 + (c + 1)) * 4096 + o8, &Tbl[o8]);
    }

    // ---- phase C ----
    f32x4 amu[2], as_[2];
#pragma unroll
    for (int j = 0; j < 2; ++j) { amu[j] = {0.f,0.f,0.f,0.f}; as_[j] = {0.f,0.f,0.f,0.f}; }
#pragma unroll
    for (int ks = 0; ks < 2; ++ks) {
      const int ao = SW(wrow * 16 + lrow, ks * 32 + lk8);
      bf16x8 aMh = *(const bf16x8*)&Mqh[ao];
      bf16x8 aMl = *(const bf16x8*)&Mql[ao];
      bf16x8 aKdh = *(const bf16x8*)&KdTh[ao];
      bf16x8 aKdl = *(const bf16x8*)&KdTl[ao];
#pragma unroll
      for (int j = 0; j < 2; ++j) {
        const int bo = SW((jh * 2 + j) * 16 + lrow, ks * 32 + lk8);
        bf16x8 bUh = *(const bf16x8*)&UTh[bo];
        bf16x8 bUl = *(const bf16x8*)&UTl[bo];
        amu[j] = mm3(aMh, aMl, bUh, bUl, amu[j]);
        as_[j] = mm3(aKdh, aKdl, bUh, bUl, as_[j]);
      }
    }
    // y values + cross-wave RMS partials
    float yv_[4][2];
#pragma unroll
    for (int r = 0; r < 4; ++r) {
      const int t = wrow * 16 + rbase + r;
      const float gt = etF[t];
      float ss = 0.f;
#pragma unroll
      for (int j = 0; j < 2; ++j) {
        yv_[r][j] = gt * aqs[j][r] + amu[j][r];
        ss += yv_[r][j] * yv_[r][j];
      }
      ss += __shfl_xor(ss, 1); ss += __shfl_xor(ss, 2); ss += __shfl_xor(ss, 4); ss += __shfl_xor(ss, 8);
      if (lrow == 0) ssP[jh * 64 + t] = ss;
    }
    lbar();                                 // publish RMS partials (LDS only)
#pragma unroll
    for (int r = 0; r < 4; ++r) {
      const int t = wrow * 16 + rbase + r;
      const float rstd = rsqrtf((ssP[t] + ssP[64 + t]) * (1.f / 64.f) + 1e-6f);
#pragma unroll
      for (int j = 0; j < 2; ++j) {
        const int col = (jh * 2 + j) * 16 + lrow;
        const float zz = bf2f(Zb[SW(t, col)]);
        const float yv = yv_[r][j] * rstd * nws[col] * (zz / (1.f + expf(-zz)));
        u16 yh, yl;
        splitbf(yv, yh, yl);
        Ybh[SW(t, col)] = yh;
        Ybl[SW(t, col)] = yl;
      }
    }
    {
      const float decC = etF[63];
#pragma unroll
      for (int j = 0; j < 2; ++j)
#pragma unroll
        for (int r = 0; r < 4; ++r) {
          const int d = wrow * 16 + rbase + r, col = (jh * 2 + j) * 16 + lrow;
          const int o = SW(col, d);
          const float s0 = bf2f(SbTh[o]) + bf2f(SbTl[o]);
          const float sv = decC * s0 + as_[j][r];
          u16 sh, sl;
          splitbf(sv, sh, sl);
          SbTh[o] = sh;
          SbTl[o] = sl;
        }
    }
    lbar();                                 // barrier C (LDS only; GLDS still in flight)

    // ---- store Y (pre-swizzled for GEMM2); write prefetched z; update gcs/bs/esF/etF ----
    {
      const size_t gsw = gidx_swz(rowbase + t0 + zr, h * 64 + zc8, 1024);
      *(float4*)&Yhi[gsw] = *(const float4*)&Ybh[SW(zr, zc8)];
      *(float4*)&Ylo[gsw] = *(const float4*)&Ybl[SW(zr, zc8)];
    }
    if (pf) {
      *(float4*)&Zb[SW(zr, zc8)] = pz;
      if (tid < 64) {
        float g63 = __shfl(pgc, 63);
        gcs[tid] = pgc; bs[tid] = pbs;
        esF[tid] = expf(g63 - pgc);
        etF[tid] = expf(pgc);
      }
    }
    __syncthreads();   // barrier D (FULL: drains Q/K/V/T GLDS before next phase A reads)
  }
}

extern "C" void kernel_launch(void* const* d_in, const int* in_sizes, int n_in,
                              void* d_out, int out_size, void* d_ws, size_t ws_size,
                              hipStream_t stream) {
  (void)in_sizes; (void)n_in; (void)out_size; (void)ws_size;
  const float* x       = (const float*)d_in[0];
  const float* W_in    = (const float*)d_in[1];
  const float* W_ba    = (const float*)d_in[2];
  const float* conv_w  = (const float*)d_in[3];
  const float* dt_bias = (const float*)d_in[4];
  const float* A_log   = (const float*)d_in[5];
  const float* norm_w  = (const float*)d_in[6];
  const float* W_o     = (const float*)d_in[7];
  float* out = (float*)d_out;
  char* ws = (char*)d_ws;
  const size_t MB = 1048576;

  _Float16* xh = (_Float16*)(ws + 0);     // 16 MB f16 x (pre-swizzled) -> Mh -> Yhi
  u16* MhB   = (u16*)(ws + 0);
  u16* YhiB  = (u16*)(ws + 0);
  u16* MlB   = (u16*)(ws + 16 * MB);      // 16 MB Ml -> Ylo
  u16* YloB  = (u16*)(ws + 16 * MB);
  _Float16* WinT = (_Float16*)(ws + 32 * MB);  // 8 MB f16 (pre-swizzled, dead post-GEMM1)
  float* gB  = (float*)(ws + 32 * MB);             // 0.5 MB (post-GEMM1)
  float* bB  = (float*)(ws + 32 * MB + 524288);    // 0.5 MB
  float* gcB = (float*)(ws + 33 * MB);             // 0.5 MB
  u16* Ssegh = (u16*)(ws + 34 * MB);      // 2 MB
  u16* Ssegl = (u16*)(ws + 36 * MB);      // 2 MB
  u16* Msegh = (u16*)(ws + 38 * MB);      // 2 MB
  u16* Msegl = (u16*)(ws + 40 * MB);      // 2 MB
  u16* Nsegh = (u16*)(ws + 42 * MB);      // 2 MB
  u16* Nsegl = (u16*)(ws + 44 * MB);      // 2 MB
  u16* WoT   = (u16*)(ws + 48 * MB);      // 2 MB (pre-swizzled)
  u16* qkv3  = (u16*)(ws + 50 * MB);      // 48 MB (dead post-conv)
  u16* NhB   = (u16*)(ws + 50 * MB);      // 16 MB
  u16* NlB   = (u16*)(ws + 66 * MB);      // 16 MB
  u16* zbB   = (u16*)(ws + 98 * MB);      // 16 MB (GEMM-major)
  u16* qhG   = (u16*)(ws + 114 * MB);     // 16 MB (per-(b,h) swizzled tiles)
  u16* qlG   = (u16*)(ws + 130 * MB);     // 16 MB
  u16* khG   = (u16*)(ws + 146 * MB);     // 16 MB
  u16* klG   = (u16*)(ws + 162 * MB);     // 16 MB
  u16* vhG   = (u16*)(ws + 178 * MB);     // 16 MB
  u16* vlG   = (u16*)(ws + 194 * MB);     // 16 MB
  u16* TghB  = (u16*)(ws + 210 * MB);     // 16 MB
  u16* TglB  = (u16*)(ws + 226 * MB);     // 16 MB  (end 242 MB)

  const int SCAN_LDS = 19 * 8192 + 448 * 4;   // 157440 B
  const int MN_LDS   = 8 * 8192 + 512;        // 66048 B
  const int SEG_LDS  = 8 * 8192;              // 65536 B

  k_cast_h<<<8192, 256, 0, stream>>>(x, xh, 8388608);
  k_transpose_h<<<dim3(64, 16), 256, 0, stream>>>(W_in, WinT, 1024, 4096);
  k_transpose<<<dim3(16, 16), 256, 0, stream>>>(W_o, WoT, 1024, 1024);
  k_gemm_h<<<dim3(16, 32), 512, 0, stream>>>(xh, WinT, qkv3, zbB, 8192, 4096, 1024);
  k_ba<<<2048, 256, 0, stream>>>(x, W_ba, dt_bias, A_log, bB, gB);
  k_conv<<<8192, 256, 0, stream>>>(qkv3, conv_w, qhG, qlG, khG, klG, vhG, vlG);
  k_prep<<<2048, 64, 0, stream>>>(khG, klG, gB, bB, gcB, TghB, TglB);
  hipFuncSetAttribute((const void*)k_mn, hipFuncAttributeMaxDynamicSharedMemorySize, MN_LDS);
  k_mn<<<2048, 256, MN_LDS, stream>>>(khG, klG, vhG, vlG, TghB, TglB, gcB, bB, MhB, MlB, NhB, NlB);
  hipFuncSetAttribute((const void*)k_seg, hipFuncAttributeMaxDynamicSharedMemorySize, SEG_LDS);
  k_seg<<<256, 256, SEG_LDS, stream>>>(MhB, MlB, NhB, NlB, Msegh, Msegl, Nsegh, Nsegl);
  k_bound<<<32, 256, 0, stream>>>(Msegh, Msegl, Nsegh, Nsegl, Ssegh, Ssegl);
  hipFuncSetAttribute((const void*)k_scan2, hipFuncAttributeMaxDynamicSharedMemorySize, SCAN_LDS);
  k_scan2<<<256, 512, SCAN_LDS, stream>>>(qhG, qlG, khG, klG, vhG, vlG, zbB, TghB, TglB, gcB, bB, norm_w,
                                          Ssegh, Ssegl, YhiB, YloB);
  k_gemm2<<<dim3(8, 64), 256, 0, stream>>>(YhiB, YloB, WoT, out, 8192, 1024, 1024);
}